// Round 1
// baseline (498.482 us; speedup 1.0000x reference)
//
#include <hip/hip_runtime.h>
#include <math.h>

#define NEG_V (-1e30f)
#define SLOPE_V 0.01f
#define EPS_V 1e-5f

typedef __attribute__((ext_vector_type(8))) short bs8;    // 8 bf16 (4 VGPRs)
typedef __attribute__((ext_vector_type(4))) float f32x4;  // mfma acc

// ---------------------------------------------------------------------------
// Round: single persistent mega-kernel. All 8 former launches become phases
// separated by a sense-reversing grid barrier. Phase math is VERBATIM from
// the validated multi-kernel version; only job-index mapping changed.
// Grid 256 blocks x 256 thr, 41KB LDS -> LDS cap 3 blk/CU => capacity 768
// >= 256, all blocks resident regardless of packing: no deadlock.
// Barrier state in zero-init __device__ globals; 8 barriers/launch (even)
// returns sense to 0 => invariant across graph replays.
// ---------------------------------------------------------------------------

__device__ unsigned g_cnt = 0;
__device__ unsigned g_sense = 0;

__device__ __forceinline__ void gridbar(unsigned& lsense) {
    __syncthreads();                 // all waves' stores drained to L2 here
    if (threadIdx.x == 0) {
        unsigned my = lsense ^ 1u;
        __threadfence();             // device-scope release (cross-XCD)
        unsigned v = __hip_atomic_fetch_add(&g_cnt, 1u, __ATOMIC_ACQ_REL,
                                            __HIP_MEMORY_SCOPE_AGENT);
        if (v == 255u) {
            __hip_atomic_store(&g_cnt, 0u, __ATOMIC_RELAXED, __HIP_MEMORY_SCOPE_AGENT);
            __hip_atomic_store(&g_sense, my, __ATOMIC_RELEASE, __HIP_MEMORY_SCOPE_AGENT);
        } else {
            while (__hip_atomic_load(&g_sense, __ATOMIC_ACQUIRE,
                                     __HIP_MEMORY_SCOPE_AGENT) != my)
                __builtin_amdgcn_s_sleep(2);
        }
        __threadfence();             // device-scope acquire
    }
    __syncthreads();
    lsense ^= 1u;
}

// Split fp32 x into bf16 hi + bf16 lo (RNE both). x ≈ hi + lo, rel err ~2^-17.
__device__ __forceinline__ void split2(float x, unsigned short& hi, unsigned short& lo) {
    unsigned u = __float_as_uint(x);
    unsigned h = (u + 0x7FFFu + ((u >> 16) & 1u)) >> 16;
    hi = (unsigned short)h;
    float hf = __uint_as_float(h << 16);
    float l = x - hf;
    unsigned ul = __float_as_uint(l);
    lo = (unsigned short)((ul + 0x7FFFu + ((ul >> 16) & 1u)) >> 16);
}

// ---------------------------------------------------------------------------
// Software-pipelined split-bf16 MFMA mainloop (validated; unchanged):
//  - double-buffered LDS stages (buf[2][4][64][40], 40 KB): ONE barrier/iter
//  - register prefetch of iter k+1's global b128 loads.
// Caller must __syncthreads() before reusing the LDS for an epilogue.
// ---------------------------------------------------------------------------
__device__ __forceinline__ void mfma_loop(
    const unsigned short* __restrict__ Ahg, const unsigned short* __restrict__ Alg,
    int lda,
    const unsigned short* __restrict__ Bhg, const unsigned short* __restrict__ Blg,
    int ldb, int K, int row0, int col0,
    f32x4 (&acc)[2][2],
    unsigned short (*buf)[64][40])   // buf[8]: stage*4 + {Ah,Al,Bh,Bl}
{
    const int tid = threadIdx.x;
    const int lane = tid & 63, wid = tid >> 6;
    const int wm0 = (wid >> 1) * 32, wn0 = (wid & 1) * 32;
    const int lm = lane & 15, q = lane >> 4;
    const int sr = tid >> 2, sc = (tid & 3) * 8;

    const unsigned short* pAh = Ahg + (size_t)(row0 + sr) * lda + sc;
    const unsigned short* pAl = Alg + (size_t)(row0 + sr) * lda + sc;
    const unsigned short* pBh = Bhg + (size_t)(col0 + sr) * ldb + sc;
    const unsigned short* pBl = Blg + (size_t)(col0 + sr) * ldb + sc;

    bs8 rAh = *(const bs8*)(pAh);
    bs8 rAl = *(const bs8*)(pAl);
    bs8 rBh = *(const bs8*)(pBh);
    bs8 rBl = *(const bs8*)(pBl);

    int st = 0;
    for (int k0 = 0; k0 < K; k0 += 32) {
        unsigned short (*Ah)[40] = buf[st * 4 + 0];
        unsigned short (*Al)[40] = buf[st * 4 + 1];
        unsigned short (*Bh)[40] = buf[st * 4 + 2];
        unsigned short (*Bl)[40] = buf[st * 4 + 3];
        *(bs8*)&Ah[sr][sc] = rAh;
        *(bs8*)&Al[sr][sc] = rAl;
        *(bs8*)&Bh[sr][sc] = rBh;
        *(bs8*)&Bl[sr][sc] = rBl;
        __syncthreads();
        if (k0 + 32 < K) {
            rAh = *(const bs8*)(pAh + k0 + 32);
            rAl = *(const bs8*)(pAl + k0 + 32);
            rBh = *(const bs8*)(pBh + k0 + 32);
            rBl = *(const bs8*)(pBl + k0 + 32);
        }
        bs8 a_h[2], a_l[2], b_h[2], b_l[2];
#pragma unroll
        for (int t = 0; t < 2; t++) {
            a_h[t] = *(bs8*)&Ah[wm0 + t * 16 + lm][q * 8];
            a_l[t] = *(bs8*)&Al[wm0 + t * 16 + lm][q * 8];
            b_h[t] = *(bs8*)&Bh[wn0 + t * 16 + lm][q * 8];
            b_l[t] = *(bs8*)&Bl[wn0 + t * 16 + lm][q * 8];
        }
#pragma unroll
        for (int mt = 0; mt < 2; mt++)
#pragma unroll
            for (int nt = 0; nt < 2; nt++) {
                acc[mt][nt] = __builtin_amdgcn_mfma_f32_16x16x32_bf16(a_h[mt], b_h[nt], acc[mt][nt], 0, 0, 0);
                acc[mt][nt] = __builtin_amdgcn_mfma_f32_16x16x32_bf16(a_h[mt], b_l[nt], acc[mt][nt], 0, 0, 0);
                acc[mt][nt] = __builtin_amdgcn_mfma_f32_16x16x32_bf16(a_l[mt], b_h[nt], acc[mt][nt], 0, 0, 0);
            }
        st ^= 1;
        // no second barrier: next iteration writes the OTHER stage.
    }
}

// 64x64 fp32 tile -> transposed bf16 hi/lo (dst[n][k] = src[k][n]).
__device__ __forceinline__ void transpose_split_tile(
    const float* __restrict__ src, int src_ld,
    unsigned short* __restrict__ dh, unsigned short* __restrict__ dl, int dst_ld,
    unsigned short (*Th)[72], unsigned short (*Tl)[72])
{
    int tid = threadIdx.x;
    int r = tid >> 2;
    int cb = (tid & 3) * 16;
#pragma unroll
    for (int cc = 0; cc < 16; cc += 4) {
        float4 v = *(const float4*)(src + (size_t)r * src_ld + cb + cc);
        unsigned short hh, ll;
        split2(v.x, hh, ll); Th[cb + cc + 0][r] = hh; Tl[cb + cc + 0][r] = ll;
        split2(v.y, hh, ll); Th[cb + cc + 1][r] = hh; Tl[cb + cc + 1][r] = ll;
        split2(v.z, hh, ll); Th[cb + cc + 2][r] = hh; Tl[cb + cc + 2][r] = ll;
        split2(v.w, hh, ll); Th[cb + cc + 3][r] = hh; Tl[cb + cc + 3][r] = ll;
    }
    __syncthreads();
    int n = tid >> 2, ch = (tid & 3) * 8;
    *(bs8*)(dh + (size_t)n * dst_ld + ch)      = *(bs8*)&Th[n][ch];
    *(bs8*)(dh + (size_t)n * dst_ld + ch + 32) = *(bs8*)&Th[n][ch + 32];
    *(bs8*)(dl + (size_t)n * dst_ld + ch)      = *(bs8*)&Tl[n][ch];
    *(bs8*)(dl + (size_t)n * dst_ld + ch + 32) = *(bs8*)&Tl[n][ch + 32];
}

// flat fp32 -> split bf16 hi/lo, 4096 elems/job, 16/thread.
__device__ __forceinline__ void flat_split_job(
    const float* __restrict__ src, unsigned short* __restrict__ dh,
    unsigned short* __restrict__ dl, size_t base)
{
    unsigned short hh, ll;
#pragma unroll
    for (int g = 0; g < 2; g++) {
        bs8 sh, sl;
#pragma unroll
        for (int cc = 0; cc < 8; cc += 4) {
            float4 v = *(const float4*)(src + base + g * 8 + cc);
            split2(v.x, hh, ll); sh[cc + 0] = (short)hh; sl[cc + 0] = (short)ll;
            split2(v.y, hh, ll); sh[cc + 1] = (short)hh; sl[cc + 1] = (short)ll;
            split2(v.z, hh, ll); sh[cc + 2] = (short)hh; sl[cc + 2] = (short)ll;
            split2(v.w, hh, ll); sh[cc + 3] = (short)hh; sl[cc + 3] = (short)ll;
        }
        *(bs8*)(dh + base + g * 8) = sh;
        *(bs8*)(dl + base + g * 8) = sl;
    }
}

struct MegaArgs {
    const float* feature; const int* adj;
    const float* W0; const float* b0; const float* W1; const float* b1;
    const float* A1; const float* ab1; const float* A2; const float* ab2;
    const float* gamma; const float* beta;
    float* s; float* psum; float* bA; float* g_ws;
    unsigned short* Wt0h; unsigned short* Wt0l;
    unsigned short* Wt1h; unsigned short* Wt1l;
    unsigned short* WAth; unsigned short* WAtl;
    unsigned short* fh;  unsigned short* fl;
    unsigned short* hth; unsigned short* htl;
    unsigned short* ndh; unsigned short* ndl;
    unsigned short* ph;  unsigned short* pl;
    float* out_graph; float* out_node;
};

__global__ __launch_bounds__(256) void mega_k(MegaArgs A) {
    __shared__ __align__(16) char SM[41216];
    const int bid = blockIdx.x;
    const int tid = threadIdx.x;
    unsigned lsense = 0;

    // ==================== phase 0: prep (530 jobs) ====================
    if (bid < 48) {
        // --- WA MFMA job, self-splitting operands (heavy -> dedicated block) ---
        int j = bid;
        int rt = j % 12, ct = (j / 12) & 1, lay = j / 24;
        const float* W = lay ? A.W1 : A.W0;
        const int r0 = rt * 64;
        unsigned short (*Ah)[40] = (unsigned short(*)[40])(SM);
        unsigned short (*Al)[40] = (unsigned short(*)[40])(SM + 5120);
        unsigned short (*Bh)[40] = (unsigned short(*)[40])(SM + 10240);
        unsigned short (*Bl)[40] = (unsigned short(*)[40])(SM + 15360);
        const int lane = tid & 63, wid = tid >> 6;
        const int wm0 = (wid >> 1) * 32, wn0 = (wid & 1) * 32;
        const int lm = lane & 15, q = lane >> 4;
        const int akk = tid & 31, acs = (tid >> 5) * 8;   // A: k-row, c-seg
        const int br = tid >> 2, bks = (tid & 3) * 8;     // B: r-row, k-seg
        f32x4 acc[2][2] = {};
        for (int k0 = 0; k0 < 768; k0 += 32) {
            {   // A-operand: Ah[c][k] = A1[(ct*768 + k0+kk)][c] (transpose-split)
                const float* ap = A.A1 + (size_t)(ct * 768 + k0 + akk) * 64 + acs;
                float4 v0 = *(const float4*)ap;
                float4 v1 = *(const float4*)(ap + 4);
                unsigned short hv, lv;
                split2(v0.x, hv, lv); Ah[acs + 0][akk] = hv; Al[acs + 0][akk] = lv;
                split2(v0.y, hv, lv); Ah[acs + 1][akk] = hv; Al[acs + 1][akk] = lv;
                split2(v0.z, hv, lv); Ah[acs + 2][akk] = hv; Al[acs + 2][akk] = lv;
                split2(v0.w, hv, lv); Ah[acs + 3][akk] = hv; Al[acs + 3][akk] = lv;
                split2(v1.x, hv, lv); Ah[acs + 4][akk] = hv; Al[acs + 4][akk] = lv;
                split2(v1.y, hv, lv); Ah[acs + 5][akk] = hv; Al[acs + 5][akk] = lv;
                split2(v1.z, hv, lv); Ah[acs + 6][akk] = hv; Al[acs + 6][akk] = lv;
                split2(v1.w, hv, lv); Ah[acs + 7][akk] = hv; Al[acs + 7][akk] = lv;
            }
            {   // B-operand: Bh[r][k] = W[r0+r][k0+k] (row-major split)
                const float* wp = W + (size_t)(r0 + br) * 768 + k0 + bks;
                float4 v0 = *(const float4*)wp;
                float4 v1 = *(const float4*)(wp + 4);
                bs8 sh, sl; unsigned short hv, lv;
                split2(v0.x, hv, lv); sh[0] = (short)hv; sl[0] = (short)lv;
                split2(v0.y, hv, lv); sh[1] = (short)hv; sl[1] = (short)lv;
                split2(v0.z, hv, lv); sh[2] = (short)hv; sl[2] = (short)lv;
                split2(v0.w, hv, lv); sh[3] = (short)hv; sl[3] = (short)lv;
                split2(v1.x, hv, lv); sh[4] = (short)hv; sl[4] = (short)lv;
                split2(v1.y, hv, lv); sh[5] = (short)hv; sl[5] = (short)lv;
                split2(v1.z, hv, lv); sh[6] = (short)hv; sl[6] = (short)lv;
                split2(v1.w, hv, lv); sh[7] = (short)hv; sl[7] = (short)lv;
                *(bs8*)&Bh[br][bks] = sh;
                *(bs8*)&Bl[br][bks] = sl;
            }
            __syncthreads();
            bs8 a_h[2], a_l[2], b_h[2], b_l[2];
#pragma unroll
            for (int t = 0; t < 2; t++) {
                a_h[t] = *(bs8*)&Ah[wm0 + t * 16 + lm][q * 8];
                a_l[t] = *(bs8*)&Al[wm0 + t * 16 + lm][q * 8];
                b_h[t] = *(bs8*)&Bh[wn0 + t * 16 + lm][q * 8];
                b_l[t] = *(bs8*)&Bl[wn0 + t * 16 + lm][q * 8];
            }
#pragma unroll
            for (int mt = 0; mt < 2; mt++)
#pragma unroll
                for (int nt = 0; nt < 2; nt++) {
                    acc[mt][nt] = __builtin_amdgcn_mfma_f32_16x16x32_bf16(a_h[mt], b_h[nt], acc[mt][nt], 0, 0, 0);
                    acc[mt][nt] = __builtin_amdgcn_mfma_f32_16x16x32_bf16(a_h[mt], b_l[nt], acc[mt][nt], 0, 0, 0);
                    acc[mt][nt] = __builtin_amdgcn_mfma_f32_16x16x32_bf16(a_l[mt], b_h[nt], acc[mt][nt], 0, 0, 0);
                }
            __syncthreads();
        }
        const int c0 = ct * 64;
        size_t base = (size_t)lay * 98304;
#pragma unroll
        for (int mt = 0; mt < 2; mt++)
#pragma unroll
            for (int nt = 0; nt < 2; nt++) {
                int n = r0 + wn0 + nt * 16 + lm;
#pragma unroll
                for (int i = 0; i < 4; i++) {
                    int m = c0 + wm0 + mt * 16 + q * 4 + i;
                    unsigned short hv, lv;
                    split2(acc[mt][nt][i], hv, lv);
                    A.WAth[base + (size_t)m * 768 + n] = hv;
                    A.WAtl[base + (size_t)m * 768 + n] = lv;
                }
            }
    } else if (bid < 50) {
        // --- bA[layer][c] = sum_k b[k] * A1x[k][c] ---
        float* redb = (float*)(SM);
        int lay = bid - 48;
        const float* bv = lay ? A.b1 : A.b0;
        int c = tid & 127, half = tid >> 7;
        float acc = 0.f;
        for (int kk = 0; kk < 384; kk++) {
            int k = half * 384 + kk;
            int row = (c < 64 ? k : 768 + k);
            acc += bv[k] * A.A1[(size_t)row * 64 + (c & 63)];
        }
        redb[tid] = acc;
        __syncthreads();
        if (tid < 128) A.bA[lay * 128 + tid] = redb[tid] + redb[tid + 128];
    } else {
        // --- light jobs 0..479: W transposes + feature split (2-3 per block) ---
        for (int id = bid - 50; id < 480; id += 206) {
            if (id < 288) {
                __syncthreads();   // protect previous job's LDS reads
                unsigned short (*Th)[72] = (unsigned short(*)[72])(SM);
                unsigned short (*Tl)[72] = (unsigned short(*)[72])(SM + 9216);
                if (id < 144) {
                    int kt = id / 12, nt = id % 12;
                    transpose_split_tile(A.W0 + (size_t)(kt * 64) * 768 + nt * 64, 768,
                                         A.Wt0h + (size_t)(nt * 64) * 768 + kt * 64,
                                         A.Wt0l + (size_t)(nt * 64) * 768 + kt * 64, 768, Th, Tl);
                } else {
                    int r = id - 144, kt = r / 12, nt = r % 12;
                    transpose_split_tile(A.W1 + (size_t)(kt * 64) * 768 + nt * 64, 768,
                                         A.Wt1h + (size_t)(nt * 64) * 768 + kt * 64,
                                         A.Wt1l + (size_t)(nt * 64) * 768 + kt * 64, 768, Th, Tl);
                }
            } else {
                flat_split_job(A.feature, A.fh, A.fl, (size_t)(id - 288) * 4096 + tid * 16);
            }
        }
    }
    gridbar(lsense);   // barrier 1

    for (int layer = 0; layer < 2; layer++) {
        const unsigned short* Wth = layer ? A.Wt1h : A.Wt0h;
        const unsigned short* Wtl = layer ? A.Wt1l : A.Wt0l;
        const float* bb = layer ? A.b1 : A.b0;
        const unsigned short* Ahg = layer ? A.ndh : A.fh;
        const unsigned short* Alg = layer ? A.ndl : A.fl;
        const unsigned short* WAthL = A.WAth + (size_t)layer * 98304;
        const unsigned short* WAtlL = A.WAtl + (size_t)layer * 98304;
        const float* bAl = A.bA + layer * 128;

        // ==================== gemm_fused (224 jobs) ====================
        if (bid < 224) {
            unsigned short (*buf)[64][40] = (unsigned short(*)[64][40])SM;
            int bx = bid % 14, row0 = (bid / 14) * 64;
            const unsigned short* Bh;
            const unsigned short* Bl;
            int col0;
            if (bx < 12) { Bh = Wth;   Bl = Wtl;   col0 = bx * 64; }
            else         { Bh = WAthL; Bl = WAtlL; col0 = (bx - 12) * 64; }
            f32x4 acc[2][2] = {};
            mfma_loop(Ahg, Alg, 768, Bh, Bl, 768, 768, row0, col0, acc, buf);
            int lane = tid & 63, wid = tid >> 6;
            int wm0 = (wid >> 1) * 32, wn0 = (wid & 1) * 32;
            int lm = lane & 15, q = lane >> 4;
            if (bx >= 12) {
#pragma unroll
                for (int mt = 0; mt < 2; mt++)
#pragma unroll
                    for (int nt = 0; nt < 2; nt++) {
                        int c = col0 + wn0 + nt * 16 + lm;
#pragma unroll
                        for (int i = 0; i < 4; i++) {
                            int r = row0 + wm0 + mt * 16 + q * 4 + i;
                            A.s[(size_t)r * 128 + c] = acc[mt][nt][i];
                        }
                    }
            } else {
                __syncthreads();   // drain last-stage LDS reads before reuse
                unsigned short* flat = (unsigned short*)SM;
                unsigned short (*Hi)[69] = (unsigned short(*)[69])flat;
                unsigned short (*Lo)[69] = (unsigned short(*)[69])(flat + 4416);
#pragma unroll
                for (int mt = 0; mt < 2; mt++)
#pragma unroll
                    for (int nt = 0; nt < 2; nt++) {
                        int c = wn0 + nt * 16 + lm;
                        float bv = bb[col0 + c];
#pragma unroll
                        for (int i = 0; i < 4; i++) {
                            int r = wm0 + mt * 16 + q * 4 + i;
                            unsigned short hv, lv;
                            split2(acc[mt][nt][i] + bv, hv, lv);
                            Hi[r][c] = hv; Lo[r][c] = lv;
                        }
                    }
                __syncthreads();
                int d = tid >> 2, kq = (tid & 3) * 16;
                int bN = row0 >> 7, kb = row0 & 127;
                bs8 th0, th1, tl0, tl1;
#pragma unroll
                for (int e = 0; e < 8; e++) {
                    th0[e] = Hi[kq + e][d];     th1[e] = Hi[kq + 8 + e][d];
                    tl0[e] = Lo[kq + e][d];     tl1[e] = Lo[kq + 8 + e][d];
                }
                size_t to = ((size_t)bN * 768 + col0 + d) * 128 + kb + kq;
                *(bs8*)(A.hth + to) = th0; *(bs8*)(A.hth + to + 8) = th1;
                *(bs8*)(A.htl + to) = tl0; *(bs8*)(A.htl + to + 8) = tl1;
            }
        }
        gridbar(lsense);   // barrier 2 / 5

        // ==================== score (256 jobs, all blocks) ====================
        {
            float (*st)[65] = (float(*)[65])SM;
            float (*ss)[65] = (float(*)[65])(SM + 33280);
            float* a2s = (float*)(SM + 34320);
            float* warr = (float*)(SM + 34576);
            int bx = bid & 31, b = bid >> 5;
            int i0 = bx * 4;
#pragma unroll
            for (int g = 0; g < 8; g++) {     // float4-vectorized st load
                int idx4 = tid + g * 256;
                int j = idx4 >> 4;
                int h2 = (idx4 & 15) * 4;
                float4 v = *(const float4*)&A.s[(size_t)(b * 128 + j) * 128 + 64 + h2];
                float4 bv = *(const float4*)&bAl[64 + h2];
                st[j][h2 + 0] = v.x + bv.x;
                st[j][h2 + 1] = v.y + bv.y;
                st[j][h2 + 2] = v.z + bv.z;
                st[j][h2 + 3] = v.w + bv.w;
            }
            {
                int i = tid >> 6, h2 = tid & 63;
                ss[i][h2] = A.s[(size_t)(b * 128 + i0 + i) * 128 + h2] + bAl[h2] + A.ab1[h2];
            }
            if (tid < 64) a2s[tid] = A.A2[tid];
            __syncthreads();
            const float ab2v = A.ab2[0];
            const int rr = tid >> 7;
            const int j = tid & 127;
            const int r0 = rr * 2, r1 = rr * 2 + 1;
            float acc0 = 0.f, acc1 = 0.f;
#pragma unroll 4
            for (int h2 = 0; h2 < 64; h2++) {
                float bbv = st[j][h2];
                float cv = a2s[h2];
                acc0 = fmaf(fmaxf(ss[r0][h2] + bbv, 0.f), cv, acc0);
                acc1 = fmaf(fmaxf(ss[r1][h2] + bbv, 0.f), cv, acc1);
            }
            float e0 = acc0 + ab2v; e0 = (e0 > 0.f) ? e0 : SLOPE_V * e0;
            float e1 = acc1 + ab2v; e1 = (e1 > 0.f) ? e1 : SLOPE_V * e1;
            size_t o0 = (size_t)b * 16384 + (size_t)(i0 + r0) * 128 + j;
            size_t o1 = (size_t)b * 16384 + (size_t)(i0 + r1) * 128 + j;
            float v0 = A.adj[o0] ? expf(e0) : 0.f;
            float v1 = A.adj[o1] ? expf(e1) : 0.f;
            unsigned short hv, lv;
            split2(v0, hv, lv); A.ph[o0] = hv; A.pl[o0] = lv;
            split2(v1, hv, lv); A.ph[o1] = hv; A.pl[o1] = lv;
            float vs = v0 + v1;
#pragma unroll
            for (int o = 32; o > 0; o >>= 1) vs += __shfl_down(vs, o);
            if ((tid & 63) == 0) warr[tid >> 6] = vs;
            __syncthreads();
            if (tid == 0) A.psum[b * 32 + bx] = warr[0] + warr[1] + warr[2] + warr[3];
        }
        gridbar(lsense);   // barrier 3 / 6

        // ==================== attn (192 jobs) ====================
        if (bid < 192) {
            unsigned short (*buf)[64][40] = (unsigned short(*)[64][40])SM;
            float* sred = (float*)(SM + 40960);
            int cx = bid % 12, ry = (bid / 12) & 1, b = bid / 24;
            int row0 = ry * 64, col0 = cx * 64;
            if (tid < 32) sred[tid] = A.psum[b * 32 + tid];
            __syncthreads();
            if (tid == 0) {
                float t = 0.f;
#pragma unroll
                for (int i = 0; i < 32; i++) t += sred[i];
                sred[32] = 1.0f / t;
            }
            __syncthreads();
            float alpha = sred[32];
            f32x4 acc[2][2] = {};
            mfma_loop(A.ph + (size_t)b * 16384, A.pl + (size_t)b * 16384, 128,
                      A.hth + (size_t)b * 98304, A.htl + (size_t)b * 98304, 128, 128,
                      row0, col0, acc, buf);
            __syncthreads();   // drain last-stage LDS reads before reuse
            float* C = A.out_node + (size_t)b * 98304;
            unsigned short* flat = (unsigned short*)SM;
            unsigned short (*Hi)[69] = (unsigned short(*)[69])flat;
            unsigned short (*Lo)[69] = (unsigned short(*)[69])(flat + 4416);
            int lane = tid & 63, wid = tid >> 6;
            int wm0 = (wid >> 1) * 32, wn0 = (wid & 1) * 32;
            int lm = lane & 15, q = lane >> 4;
#pragma unroll
            for (int mt = 0; mt < 2; mt++)
#pragma unroll
                for (int nt = 0; nt < 2; nt++) {
                    int c = wn0 + nt * 16 + lm;
#pragma unroll
                    for (int i = 0; i < 4; i++) {
                        int r = wm0 + mt * 16 + q * 4 + i;
                        float v = acc[mt][nt][i] * alpha;
                        C[(size_t)(row0 + r) * 768 + col0 + c] = v;
                        unsigned short hv, lv;
                        split2(v, hv, lv);
                        Hi[r][c] = hv; Lo[r][c] = lv;
                    }
                }
            __syncthreads();
            int r = tid >> 2, cq = (tid & 3) * 16;
            bs8 vh0, vh1, vl0, vl1;
#pragma unroll
            for (int e = 0; e < 8; e++) {
                vh0[e] = Hi[r][cq + e];     vh1[e] = Hi[r][cq + 8 + e];
                vl0[e] = Lo[r][cq + e];     vl1[e] = Lo[r][cq + 8 + e];
            }
            size_t ro = (size_t)(b * 128 + row0 + r) * 768 + col0 + cq;
            *(bs8*)(A.ndh + ro) = vh0; *(bs8*)(A.ndh + ro + 8) = vh1;
            *(bs8*)(A.ndl + ro) = vl0; *(bs8*)(A.ndl + ro + 8) = vl1;
        }
        gridbar(lsense);   // barrier 4 / 7
    }

    // ==================== gsum part 1: g[b][d] (96 jobs) ====================
    if (bid < 96) {
        float (*gbuf)[64] = (float(*)[64])SM;
        int b = bid / 12, dt = bid % 12;
        int dl = tid & 63, rg = tid >> 6;
        const float* np = A.out_node + (size_t)(b * 128 + rg * 32) * 768 + dt * 64 + dl;
        float v = 0.f;
        for (int i = 0; i < 32; i++) v += np[(size_t)i * 768];
        gbuf[rg][dl] = v;
        __syncthreads();
        if (tid < 64)
            A.g_ws[b * 768 + dt * 64 + tid] =
                gbuf[0][tid] + gbuf[1][tid] + gbuf[2][tid] + gbuf[3][tid];
    }
    gridbar(lsense);   // barrier 8

    // ==================== gsum part 2: batch-norm (12 jobs) ====================
    if (bid < 12 && tid < 64) {
        int d = bid * 64 + tid;
        float vals[8]; float m = 0.f;
#pragma unroll
        for (int b = 0; b < 8; b++) { vals[b] = A.g_ws[b * 768 + d]; m += vals[b]; }
        m *= 0.125f;
        float var = 0.f;
#pragma unroll
        for (int b = 0; b < 8; b++) { float t = vals[b] - m; var += t * t; }
        var *= 0.125f;
        float inv = 1.0f / sqrtf(var + EPS_V);
        float gm = A.gamma[d], bt = A.beta[d];
#pragma unroll
        for (int b = 0; b < 8; b++)
            A.out_graph[b * 768 + d] = gm * (vals[b] - m) * inv + bt;
    }
}

// ---------------------------------------------------------------------------
extern "C" void kernel_launch(void* const* d_in, const int* in_sizes, int n_in,
                              void* d_out, int out_size, void* d_ws, size_t ws_size,
                              hipStream_t stream)
{
    float* ws = (float*)d_ws;
    MegaArgs M;
    M.feature = (const float*)d_in[0];
    // d_in[1] = aspect: unused by the reference
    M.adj     = (const int*)d_in[2];
    M.W0      = (const float*)d_in[3];
    M.b0      = (const float*)d_in[4];
    M.W1      = (const float*)d_in[5];
    M.b1      = (const float*)d_in[6];
    M.A1      = (const float*)d_in[7];
    M.ab1     = (const float*)d_in[8];
    M.A2      = (const float*)d_in[9];
    M.ab2     = (const float*)d_in[10];
    M.gamma   = (const float*)d_in[11];
    M.beta    = (const float*)d_in[12];

    M.s    = ws;                 // 131072 f
    M.psum = ws + 131072;        // 256 f
    M.bA   = ws + 131328;        // 256 f
    M.g_ws = ws + 131584;        // 6144 f
    unsigned short* u = (unsigned short*)(ws + 137728);  // 16B-aligned
    M.Wt0h = u;                          // 589824 each
    M.Wt0l = M.Wt0h + 589824;
    M.Wt1h = M.Wt0l + 589824;
    M.Wt1l = M.Wt1h + 589824;
    M.WAth = M.Wt1l + 589824;            // 196608 each (2 layers)
    M.WAtl = M.WAth + 196608;
    M.fh   = M.WAtl + 196608;            // 786432 each from here
    M.fl   = M.fh + 786432;
    M.hth  = M.fl + 786432;
    M.htl  = M.hth + 786432;
    M.ndh  = M.htl + 786432;
    M.ndl  = M.ndh + 786432;
    M.ph   = M.ndl + 786432;             // 131072 each
    M.pl   = M.ph + 131072;

    float* out  = (float*)d_out;
    M.out_graph = out;           // (8,768)
    M.out_node  = out + 6144;    // (8,128,768)

    mega_k<<<256, 256, 0, stream>>>(M);
}

// Round 2
// 295.490 us; speedup vs baseline: 1.6870x; 1.6870x over previous
//
#include <hip/hip_runtime.h>
#include <math.h>

#define NEG_V (-1e30f)
#define SLOPE_V 0.01f
#define EPS_V 1e-5f

typedef __attribute__((ext_vector_type(8))) short bs8;    // 8 bf16 (4 VGPRs)
typedef __attribute__((ext_vector_type(4))) float f32x4;  // mfma acc

// ---------------------------------------------------------------------------
// Persistent mega-kernel, round 2: SAME phase structure as round 1; only the
// grid barrier changed. Round-1 post-mortem: ACQUIRE atomic poll at agent
// scope emits a cache-invalidate PER SPIN ITERATION -> invalidation storm,
// ~50us/barrier (429us total, MfmaUtil 0.97%). Fix: RELAXED polls (cache-
// bypass, no maintenance ops) + ONE release fence on entry and ONE acquire
// fence on exit. g_sense store is RELEASE so the g_cnt reset can't reorder
// past it (would lose an increment at the next barrier -> deadlock).
// Grid 256 x 256thr, 41KB LDS -> LDS cap 3 blk/CU => all 256 resident.
// 8 barriers/launch (even) -> g_sense returns to 0: replay-invariant.
// ---------------------------------------------------------------------------

__device__ unsigned g_cnt = 0;
__device__ unsigned g_sense = 0;

__device__ __forceinline__ void gridbar(unsigned& lsense) {
    __syncthreads();                 // block-local: all waves arrived
    if (threadIdx.x == 0) {
        unsigned my = lsense ^ 1u;
        // release once: write back this block's data to the coherence point
        __builtin_amdgcn_fence(__ATOMIC_RELEASE, "agent");
        unsigned v = __hip_atomic_fetch_add(&g_cnt, 1u, __ATOMIC_RELAXED,
                                            __HIP_MEMORY_SCOPE_AGENT);
        if (v == 255u) {
            __hip_atomic_store(&g_cnt, 0u, __ATOMIC_RELAXED, __HIP_MEMORY_SCOPE_AGENT);
            // RELEASE: orders the cnt reset before the sense flip
            __hip_atomic_store(&g_sense, my, __ATOMIC_RELEASE, __HIP_MEMORY_SCOPE_AGENT);
        } else {
            // RELAXED poll: reads the coherence point, NO cache-inv per iter
            while (__hip_atomic_load(&g_sense, __ATOMIC_RELAXED,
                                     __HIP_MEMORY_SCOPE_AGENT) != my)
                __builtin_amdgcn_s_sleep(16);
        }
        // acquire once: invalidate stale L1/L2 before reading others' data
        __builtin_amdgcn_fence(__ATOMIC_ACQUIRE, "agent");
    }
    __syncthreads();
    lsense ^= 1u;
}

// Split fp32 x into bf16 hi + bf16 lo (RNE both). x ≈ hi + lo, rel err ~2^-17.
__device__ __forceinline__ void split2(float x, unsigned short& hi, unsigned short& lo) {
    unsigned u = __float_as_uint(x);
    unsigned h = (u + 0x7FFFu + ((u >> 16) & 1u)) >> 16;
    hi = (unsigned short)h;
    float hf = __uint_as_float(h << 16);
    float l = x - hf;
    unsigned ul = __float_as_uint(l);
    lo = (unsigned short)((ul + 0x7FFFu + ((ul >> 16) & 1u)) >> 16);
}

// ---------------------------------------------------------------------------
// Software-pipelined split-bf16 MFMA mainloop (validated; unchanged):
//  - double-buffered LDS stages (buf[2][4][64][40], 40 KB): ONE barrier/iter
//  - register prefetch of iter k+1's global b128 loads.
// Caller must __syncthreads() before reusing the LDS for an epilogue.
// ---------------------------------------------------------------------------
__device__ __forceinline__ void mfma_loop(
    const unsigned short* __restrict__ Ahg, const unsigned short* __restrict__ Alg,
    int lda,
    const unsigned short* __restrict__ Bhg, const unsigned short* __restrict__ Blg,
    int ldb, int K, int row0, int col0,
    f32x4 (&acc)[2][2],
    unsigned short (*buf)[64][40])   // buf[8]: stage*4 + {Ah,Al,Bh,Bl}
{
    const int tid = threadIdx.x;
    const int lane = tid & 63, wid = tid >> 6;
    const int wm0 = (wid >> 1) * 32, wn0 = (wid & 1) * 32;
    const int lm = lane & 15, q = lane >> 4;
    const int sr = tid >> 2, sc = (tid & 3) * 8;

    const unsigned short* pAh = Ahg + (size_t)(row0 + sr) * lda + sc;
    const unsigned short* pAl = Alg + (size_t)(row0 + sr) * lda + sc;
    const unsigned short* pBh = Bhg + (size_t)(col0 + sr) * ldb + sc;
    const unsigned short* pBl = Blg + (size_t)(col0 + sr) * ldb + sc;

    bs8 rAh = *(const bs8*)(pAh);
    bs8 rAl = *(const bs8*)(pAl);
    bs8 rBh = *(const bs8*)(pBh);
    bs8 rBl = *(const bs8*)(pBl);

    int st = 0;
    for (int k0 = 0; k0 < K; k0 += 32) {
        unsigned short (*Ah)[40] = buf[st * 4 + 0];
        unsigned short (*Al)[40] = buf[st * 4 + 1];
        unsigned short (*Bh)[40] = buf[st * 4 + 2];
        unsigned short (*Bl)[40] = buf[st * 4 + 3];
        *(bs8*)&Ah[sr][sc] = rAh;
        *(bs8*)&Al[sr][sc] = rAl;
        *(bs8*)&Bh[sr][sc] = rBh;
        *(bs8*)&Bl[sr][sc] = rBl;
        __syncthreads();
        if (k0 + 32 < K) {
            rAh = *(const bs8*)(pAh + k0 + 32);
            rAl = *(const bs8*)(pAl + k0 + 32);
            rBh = *(const bs8*)(pBh + k0 + 32);
            rBl = *(const bs8*)(pBl + k0 + 32);
        }
        bs8 a_h[2], a_l[2], b_h[2], b_l[2];
#pragma unroll
        for (int t = 0; t < 2; t++) {
            a_h[t] = *(bs8*)&Ah[wm0 + t * 16 + lm][q * 8];
            a_l[t] = *(bs8*)&Al[wm0 + t * 16 + lm][q * 8];
            b_h[t] = *(bs8*)&Bh[wn0 + t * 16 + lm][q * 8];
            b_l[t] = *(bs8*)&Bl[wn0 + t * 16 + lm][q * 8];
        }
#pragma unroll
        for (int mt = 0; mt < 2; mt++)
#pragma unroll
            for (int nt = 0; nt < 2; nt++) {
                acc[mt][nt] = __builtin_amdgcn_mfma_f32_16x16x32_bf16(a_h[mt], b_h[nt], acc[mt][nt], 0, 0, 0);
                acc[mt][nt] = __builtin_amdgcn_mfma_f32_16x16x32_bf16(a_h[mt], b_l[nt], acc[mt][nt], 0, 0, 0);
                acc[mt][nt] = __builtin_amdgcn_mfma_f32_16x16x32_bf16(a_l[mt], b_h[nt], acc[mt][nt], 0, 0, 0);
            }
        st ^= 1;
        // no second barrier: next iteration writes the OTHER stage.
    }
}

// 64x64 fp32 tile -> transposed bf16 hi/lo (dst[n][k] = src[k][n]).
__device__ __forceinline__ void transpose_split_tile(
    const float* __restrict__ src, int src_ld,
    unsigned short* __restrict__ dh, unsigned short* __restrict__ dl, int dst_ld,
    unsigned short (*Th)[72], unsigned short (*Tl)[72])
{
    int tid = threadIdx.x;
    int r = tid >> 2;
    int cb = (tid & 3) * 16;
#pragma unroll
    for (int cc = 0; cc < 16; cc += 4) {
        float4 v = *(const float4*)(src + (size_t)r * src_ld + cb + cc);
        unsigned short hh, ll;
        split2(v.x, hh, ll); Th[cb + cc + 0][r] = hh; Tl[cb + cc + 0][r] = ll;
        split2(v.y, hh, ll); Th[cb + cc + 1][r] = hh; Tl[cb + cc + 1][r] = ll;
        split2(v.z, hh, ll); Th[cb + cc + 2][r] = hh; Tl[cb + cc + 2][r] = ll;
        split2(v.w, hh, ll); Th[cb + cc + 3][r] = hh; Tl[cb + cc + 3][r] = ll;
    }
    __syncthreads();
    int n = tid >> 2, ch = (tid & 3) * 8;
    *(bs8*)(dh + (size_t)n * dst_ld + ch)      = *(bs8*)&Th[n][ch];
    *(bs8*)(dh + (size_t)n * dst_ld + ch + 32) = *(bs8*)&Th[n][ch + 32];
    *(bs8*)(dl + (size_t)n * dst_ld + ch)      = *(bs8*)&Tl[n][ch];
    *(bs8*)(dl + (size_t)n * dst_ld + ch + 32) = *(bs8*)&Tl[n][ch + 32];
}

// flat fp32 -> split bf16 hi/lo, 4096 elems/job, 16/thread.
__device__ __forceinline__ void flat_split_job(
    const float* __restrict__ src, unsigned short* __restrict__ dh,
    unsigned short* __restrict__ dl, size_t base)
{
    unsigned short hh, ll;
#pragma unroll
    for (int g = 0; g < 2; g++) {
        bs8 sh, sl;
#pragma unroll
        for (int cc = 0; cc < 8; cc += 4) {
            float4 v = *(const float4*)(src + base + g * 8 + cc);
            split2(v.x, hh, ll); sh[cc + 0] = (short)hh; sl[cc + 0] = (short)ll;
            split2(v.y, hh, ll); sh[cc + 1] = (short)hh; sl[cc + 1] = (short)ll;
            split2(v.z, hh, ll); sh[cc + 2] = (short)hh; sl[cc + 2] = (short)ll;
            split2(v.w, hh, ll); sh[cc + 3] = (short)hh; sl[cc + 3] = (short)ll;
        }
        *(bs8*)(dh + base + g * 8) = sh;
        *(bs8*)(dl + base + g * 8) = sl;
    }
}

struct MegaArgs {
    const float* feature; const int* adj;
    const float* W0; const float* b0; const float* W1; const float* b1;
    const float* A1; const float* ab1; const float* A2; const float* ab2;
    const float* gamma; const float* beta;
    float* s; float* psum; float* bA; float* g_ws;
    unsigned short* Wt0h; unsigned short* Wt0l;
    unsigned short* Wt1h; unsigned short* Wt1l;
    unsigned short* WAth; unsigned short* WAtl;
    unsigned short* fh;  unsigned short* fl;
    unsigned short* hth; unsigned short* htl;
    unsigned short* ndh; unsigned short* ndl;
    unsigned short* ph;  unsigned short* pl;
    float* out_graph; float* out_node;
};

__global__ __launch_bounds__(256) void mega_k(MegaArgs A) {
    __shared__ __align__(16) char SM[41216];
    const int bid = blockIdx.x;
    const int tid = threadIdx.x;
    unsigned lsense = 0;

    // ==================== phase 0: prep (530 jobs) ====================
    if (bid < 48) {
        // --- WA MFMA job, self-splitting operands (heavy -> dedicated block) ---
        int j = bid;
        int rt = j % 12, ct = (j / 12) & 1, lay = j / 24;
        const float* W = lay ? A.W1 : A.W0;
        const int r0 = rt * 64;
        unsigned short (*Ah)[40] = (unsigned short(*)[40])(SM);
        unsigned short (*Al)[40] = (unsigned short(*)[40])(SM + 5120);
        unsigned short (*Bh)[40] = (unsigned short(*)[40])(SM + 10240);
        unsigned short (*Bl)[40] = (unsigned short(*)[40])(SM + 15360);
        const int lane = tid & 63, wid = tid >> 6;
        const int wm0 = (wid >> 1) * 32, wn0 = (wid & 1) * 32;
        const int lm = lane & 15, q = lane >> 4;
        const int akk = tid & 31, acs = (tid >> 5) * 8;   // A: k-row, c-seg
        const int br = tid >> 2, bks = (tid & 3) * 8;     // B: r-row, k-seg
        f32x4 acc[2][2] = {};
        for (int k0 = 0; k0 < 768; k0 += 32) {
            {   // A-operand: Ah[c][k] = A1[(ct*768 + k0+kk)][c] (transpose-split)
                const float* ap = A.A1 + (size_t)(ct * 768 + k0 + akk) * 64 + acs;
                float4 v0 = *(const float4*)ap;
                float4 v1 = *(const float4*)(ap + 4);
                unsigned short hv, lv;
                split2(v0.x, hv, lv); Ah[acs + 0][akk] = hv; Al[acs + 0][akk] = lv;
                split2(v0.y, hv, lv); Ah[acs + 1][akk] = hv; Al[acs + 1][akk] = lv;
                split2(v0.z, hv, lv); Ah[acs + 2][akk] = hv; Al[acs + 2][akk] = lv;
                split2(v0.w, hv, lv); Ah[acs + 3][akk] = hv; Al[acs + 3][akk] = lv;
                split2(v1.x, hv, lv); Ah[acs + 4][akk] = hv; Al[acs + 4][akk] = lv;
                split2(v1.y, hv, lv); Ah[acs + 5][akk] = hv; Al[acs + 5][akk] = lv;
                split2(v1.z, hv, lv); Ah[acs + 6][akk] = hv; Al[acs + 6][akk] = lv;
                split2(v1.w, hv, lv); Ah[acs + 7][akk] = hv; Al[acs + 7][akk] = lv;
            }
            {   // B-operand: Bh[r][k] = W[r0+r][k0+k] (row-major split)
                const float* wp = W + (size_t)(r0 + br) * 768 + k0 + bks;
                float4 v0 = *(const float4*)wp;
                float4 v1 = *(const float4*)(wp + 4);
                bs8 sh, sl; unsigned short hv, lv;
                split2(v0.x, hv, lv); sh[0] = (short)hv; sl[0] = (short)lv;
                split2(v0.y, hv, lv); sh[1] = (short)hv; sl[1] = (short)lv;
                split2(v0.z, hv, lv); sh[2] = (short)hv; sl[2] = (short)lv;
                split2(v0.w, hv, lv); sh[3] = (short)hv; sl[3] = (short)lv;
                split2(v1.x, hv, lv); sh[4] = (short)hv; sl[4] = (short)lv;
                split2(v1.y, hv, lv); sh[5] = (short)hv; sl[5] = (short)lv;
                split2(v1.z, hv, lv); sh[6] = (short)hv; sl[6] = (short)lv;
                split2(v1.w, hv, lv); sh[7] = (short)hv; sl[7] = (short)lv;
                *(bs8*)&Bh[br][bks] = sh;
                *(bs8*)&Bl[br][bks] = sl;
            }
            __syncthreads();
            bs8 a_h[2], a_l[2], b_h[2], b_l[2];
#pragma unroll
            for (int t = 0; t < 2; t++) {
                a_h[t] = *(bs8*)&Ah[wm0 + t * 16 + lm][q * 8];
                a_l[t] = *(bs8*)&Al[wm0 + t * 16 + lm][q * 8];
                b_h[t] = *(bs8*)&Bh[wn0 + t * 16 + lm][q * 8];
                b_l[t] = *(bs8*)&Bl[wn0 + t * 16 + lm][q * 8];
            }
#pragma unroll
            for (int mt = 0; mt < 2; mt++)
#pragma unroll
                for (int nt = 0; nt < 2; nt++) {
                    acc[mt][nt] = __builtin_amdgcn_mfma_f32_16x16x32_bf16(a_h[mt], b_h[nt], acc[mt][nt], 0, 0, 0);
                    acc[mt][nt] = __builtin_amdgcn_mfma_f32_16x16x32_bf16(a_h[mt], b_l[nt], acc[mt][nt], 0, 0, 0);
                    acc[mt][nt] = __builtin_amdgcn_mfma_f32_16x16x32_bf16(a_l[mt], b_h[nt], acc[mt][nt], 0, 0, 0);
                }
            __syncthreads();
        }
        const int c0 = ct * 64;
        size_t base = (size_t)lay * 98304;
#pragma unroll
        for (int mt = 0; mt < 2; mt++)
#pragma unroll
            for (int nt = 0; nt < 2; nt++) {
                int n = r0 + wn0 + nt * 16 + lm;
#pragma unroll
                for (int i = 0; i < 4; i++) {
                    int m = c0 + wm0 + mt * 16 + q * 4 + i;
                    unsigned short hv, lv;
                    split2(acc[mt][nt][i], hv, lv);
                    A.WAth[base + (size_t)m * 768 + n] = hv;
                    A.WAtl[base + (size_t)m * 768 + n] = lv;
                }
            }
    } else if (bid < 50) {
        // --- bA[layer][c] = sum_k b[k] * A1x[k][c] ---
        float* redb = (float*)(SM);
        int lay = bid - 48;
        const float* bv = lay ? A.b1 : A.b0;
        int c = tid & 127, half = tid >> 7;
        float acc = 0.f;
        for (int kk = 0; kk < 384; kk++) {
            int k = half * 384 + kk;
            int row = (c < 64 ? k : 768 + k);
            acc += bv[k] * A.A1[(size_t)row * 64 + (c & 63)];
        }
        redb[tid] = acc;
        __syncthreads();
        if (tid < 128) A.bA[lay * 128 + tid] = redb[tid] + redb[tid + 128];
    } else {
        // --- light jobs 0..479: W transposes + feature split (2-3 per block) ---
        for (int id = bid - 50; id < 480; id += 206) {
            if (id < 288) {
                __syncthreads();   // protect previous job's LDS reads
                unsigned short (*Th)[72] = (unsigned short(*)[72])(SM);
                unsigned short (*Tl)[72] = (unsigned short(*)[72])(SM + 9216);
                if (id < 144) {
                    int kt = id / 12, nt = id % 12;
                    transpose_split_tile(A.W0 + (size_t)(kt * 64) * 768 + nt * 64, 768,
                                         A.Wt0h + (size_t)(nt * 64) * 768 + kt * 64,
                                         A.Wt0l + (size_t)(nt * 64) * 768 + kt * 64, 768, Th, Tl);
                } else {
                    int r = id - 144, kt = r / 12, nt = r % 12;
                    transpose_split_tile(A.W1 + (size_t)(kt * 64) * 768 + nt * 64, 768,
                                         A.Wt1h + (size_t)(nt * 64) * 768 + kt * 64,
                                         A.Wt1l + (size_t)(nt * 64) * 768 + kt * 64, 768, Th, Tl);
                }
            } else {
                flat_split_job(A.feature, A.fh, A.fl, (size_t)(id - 288) * 4096 + tid * 16);
            }
        }
    }
    gridbar(lsense);   // barrier 1

    for (int layer = 0; layer < 2; layer++) {
        const unsigned short* Wth = layer ? A.Wt1h : A.Wt0h;
        const unsigned short* Wtl = layer ? A.Wt1l : A.Wt0l;
        const float* bb = layer ? A.b1 : A.b0;
        const unsigned short* Ahg = layer ? A.ndh : A.fh;
        const unsigned short* Alg = layer ? A.ndl : A.fl;
        const unsigned short* WAthL = A.WAth + (size_t)layer * 98304;
        const unsigned short* WAtlL = A.WAtl + (size_t)layer * 98304;
        const float* bAl = A.bA + layer * 128;

        // ==================== gemm_fused (224 jobs) ====================
        if (bid < 224) {
            unsigned short (*buf)[64][40] = (unsigned short(*)[64][40])SM;
            int bx = bid % 14, row0 = (bid / 14) * 64;
            const unsigned short* Bh;
            const unsigned short* Bl;
            int col0;
            if (bx < 12) { Bh = Wth;   Bl = Wtl;   col0 = bx * 64; }
            else         { Bh = WAthL; Bl = WAtlL; col0 = (bx - 12) * 64; }
            f32x4 acc[2][2] = {};
            mfma_loop(Ahg, Alg, 768, Bh, Bl, 768, 768, row0, col0, acc, buf);
            int lane = tid & 63, wid = tid >> 6;
            int wm0 = (wid >> 1) * 32, wn0 = (wid & 1) * 32;
            int lm = lane & 15, q = lane >> 4;
            if (bx >= 12) {
#pragma unroll
                for (int mt = 0; mt < 2; mt++)
#pragma unroll
                    for (int nt = 0; nt < 2; nt++) {
                        int c = col0 + wn0 + nt * 16 + lm;
#pragma unroll
                        for (int i = 0; i < 4; i++) {
                            int r = row0 + wm0 + mt * 16 + q * 4 + i;
                            A.s[(size_t)r * 128 + c] = acc[mt][nt][i];
                        }
                    }
            } else {
                __syncthreads();   // drain last-stage LDS reads before reuse
                unsigned short* flat = (unsigned short*)SM;
                unsigned short (*Hi)[69] = (unsigned short(*)[69])flat;
                unsigned short (*Lo)[69] = (unsigned short(*)[69])(flat + 4416);
#pragma unroll
                for (int mt = 0; mt < 2; mt++)
#pragma unroll
                    for (int nt = 0; nt < 2; nt++) {
                        int c = wn0 + nt * 16 + lm;
                        float bv = bb[col0 + c];
#pragma unroll
                        for (int i = 0; i < 4; i++) {
                            int r = wm0 + mt * 16 + q * 4 + i;
                            unsigned short hv, lv;
                            split2(acc[mt][nt][i] + bv, hv, lv);
                            Hi[r][c] = hv; Lo[r][c] = lv;
                        }
                    }
                __syncthreads();
                int d = tid >> 2, kq = (tid & 3) * 16;
                int bN = row0 >> 7, kb = row0 & 127;
                bs8 th0, th1, tl0, tl1;
#pragma unroll
                for (int e = 0; e < 8; e++) {
                    th0[e] = Hi[kq + e][d];     th1[e] = Hi[kq + 8 + e][d];
                    tl0[e] = Lo[kq + e][d];     tl1[e] = Lo[kq + 8 + e][d];
                }
                size_t to = ((size_t)bN * 768 + col0 + d) * 128 + kb + kq;
                *(bs8*)(A.hth + to) = th0; *(bs8*)(A.hth + to + 8) = th1;
                *(bs8*)(A.htl + to) = tl0; *(bs8*)(A.htl + to + 8) = tl1;
            }
        }
        gridbar(lsense);   // barrier 2 / 5

        // ==================== score (256 jobs, all blocks) ====================
        {
            float (*st)[65] = (float(*)[65])SM;
            float (*ss)[65] = (float(*)[65])(SM + 33280);
            float* a2s = (float*)(SM + 34320);
            float* warr = (float*)(SM + 34576);
            int bx = bid & 31, b = bid >> 5;
            int i0 = bx * 4;
#pragma unroll
            for (int g = 0; g < 8; g++) {     // float4-vectorized st load
                int idx4 = tid + g * 256;
                int j = idx4 >> 4;
                int h2 = (idx4 & 15) * 4;
                float4 v = *(const float4*)&A.s[(size_t)(b * 128 + j) * 128 + 64 + h2];
                float4 bv = *(const float4*)&bAl[64 + h2];
                st[j][h2 + 0] = v.x + bv.x;
                st[j][h2 + 1] = v.y + bv.y;
                st[j][h2 + 2] = v.z + bv.z;
                st[j][h2 + 3] = v.w + bv.w;
            }
            {
                int i = tid >> 6, h2 = tid & 63;
                ss[i][h2] = A.s[(size_t)(b * 128 + i0 + i) * 128 + h2] + bAl[h2] + A.ab1[h2];
            }
            if (tid < 64) a2s[tid] = A.A2[tid];
            __syncthreads();
            const float ab2v = A.ab2[0];
            const int rr = tid >> 7;
            const int j = tid & 127;
            const int r0 = rr * 2, r1 = rr * 2 + 1;
            float acc0 = 0.f, acc1 = 0.f;
#pragma unroll 4
            for (int h2 = 0; h2 < 64; h2++) {
                float bbv = st[j][h2];
                float cv = a2s[h2];
                acc0 = fmaf(fmaxf(ss[r0][h2] + bbv, 0.f), cv, acc0);
                acc1 = fmaf(fmaxf(ss[r1][h2] + bbv, 0.f), cv, acc1);
            }
            float e0 = acc0 + ab2v; e0 = (e0 > 0.f) ? e0 : SLOPE_V * e0;
            float e1 = acc1 + ab2v; e1 = (e1 > 0.f) ? e1 : SLOPE_V * e1;
            size_t o0 = (size_t)b * 16384 + (size_t)(i0 + r0) * 128 + j;
            size_t o1 = (size_t)b * 16384 + (size_t)(i0 + r1) * 128 + j;
            float v0 = A.adj[o0] ? expf(e0) : 0.f;
            float v1 = A.adj[o1] ? expf(e1) : 0.f;
            unsigned short hv, lv;
            split2(v0, hv, lv); A.ph[o0] = hv; A.pl[o0] = lv;
            split2(v1, hv, lv); A.ph[o1] = hv; A.pl[o1] = lv;
            float vs = v0 + v1;
#pragma unroll
            for (int o = 32; o > 0; o >>= 1) vs += __shfl_down(vs, o);
            if ((tid & 63) == 0) warr[tid >> 6] = vs;
            __syncthreads();
            if (tid == 0) A.psum[b * 32 + bx] = warr[0] + warr[1] + warr[2] + warr[3];
        }
        gridbar(lsense);   // barrier 3 / 6

        // ==================== attn (192 jobs) ====================
        if (bid < 192) {
            unsigned short (*buf)[64][40] = (unsigned short(*)[64][40])SM;
            float* sred = (float*)(SM + 40960);
            int cx = bid % 12, ry = (bid / 12) & 1, b = bid / 24;
            int row0 = ry * 64, col0 = cx * 64;
            if (tid < 32) sred[tid] = A.psum[b * 32 + tid];
            __syncthreads();
            if (tid == 0) {
                float t = 0.f;
#pragma unroll
                for (int i = 0; i < 32; i++) t += sred[i];
                sred[32] = 1.0f / t;
            }
            __syncthreads();
            float alpha = sred[32];
            f32x4 acc[2][2] = {};
            mfma_loop(A.ph + (size_t)b * 16384, A.pl + (size_t)b * 16384, 128,
                      A.hth + (size_t)b * 98304, A.htl + (size_t)b * 98304, 128, 128,
                      row0, col0, acc, buf);
            __syncthreads();   // drain last-stage LDS reads before reuse
            float* C = A.out_node + (size_t)b * 98304;
            unsigned short* flat = (unsigned short*)SM;
            unsigned short (*Hi)[69] = (unsigned short(*)[69])flat;
            unsigned short (*Lo)[69] = (unsigned short(*)[69])(flat + 4416);
            int lane = tid & 63, wid = tid >> 6;
            int wm0 = (wid >> 1) * 32, wn0 = (wid & 1) * 32;
            int lm = lane & 15, q = lane >> 4;
#pragma unroll
            for (int mt = 0; mt < 2; mt++)
#pragma unroll
                for (int nt = 0; nt < 2; nt++) {
                    int c = wn0 + nt * 16 + lm;
#pragma unroll
                    for (int i = 0; i < 4; i++) {
                        int r = wm0 + mt * 16 + q * 4 + i;
                        float v = acc[mt][nt][i] * alpha;
                        C[(size_t)(row0 + r) * 768 + col0 + c] = v;
                        unsigned short hv, lv;
                        split2(v, hv, lv);
                        Hi[r][c] = hv; Lo[r][c] = lv;
                    }
                }
            __syncthreads();
            int r = tid >> 2, cq = (tid & 3) * 16;
            bs8 vh0, vh1, vl0, vl1;
#pragma unroll
            for (int e = 0; e < 8; e++) {
                vh0[e] = Hi[r][cq + e];     vh1[e] = Hi[r][cq + 8 + e];
                vl0[e] = Lo[r][cq + e];     vl1[e] = Lo[r][cq + 8 + e];
            }
            size_t ro = (size_t)(b * 128 + row0 + r) * 768 + col0 + cq;
            *(bs8*)(A.ndh + ro) = vh0; *(bs8*)(A.ndh + ro + 8) = vh1;
            *(bs8*)(A.ndl + ro) = vl0; *(bs8*)(A.ndl + ro + 8) = vl1;
        }
        gridbar(lsense);   // barrier 4 / 7
    }

    // ==================== gsum part 1: g[b][d] (96 jobs) ====================
    if (bid < 96) {
        float (*gbuf)[64] = (float(*)[64])SM;
        int b = bid / 12, dt = bid % 12;
        int dl = tid & 63, rg = tid >> 6;
        const float* np = A.out_node + (size_t)(b * 128 + rg * 32) * 768 + dt * 64 + dl;
        float v = 0.f;
        for (int i = 0; i < 32; i++) v += np[(size_t)i * 768];
        gbuf[rg][dl] = v;
        __syncthreads();
        if (tid < 64)
            A.g_ws[b * 768 + dt * 64 + tid] =
                gbuf[0][tid] + gbuf[1][tid] + gbuf[2][tid] + gbuf[3][tid];
    }
    gridbar(lsense);   // barrier 8

    // ==================== gsum part 2: batch-norm (12 jobs) ====================
    if (bid < 12 && tid < 64) {
        int d = bid * 64 + tid;
        float vals[8]; float m = 0.f;
#pragma unroll
        for (int b = 0; b < 8; b++) { vals[b] = A.g_ws[b * 768 + d]; m += vals[b]; }
        m *= 0.125f;
        float var = 0.f;
#pragma unroll
        for (int b = 0; b < 8; b++) { float t = vals[b] - m; var += t * t; }
        var *= 0.125f;
        float inv = 1.0f / sqrtf(var + EPS_V);
        float gm = A.gamma[d], bt = A.beta[d];
#pragma unroll
        for (int b = 0; b < 8; b++)
            A.out_graph[b * 768 + d] = gm * (vals[b] - m) * inv + bt;
    }
}

// ---------------------------------------------------------------------------
extern "C" void kernel_launch(void* const* d_in, const int* in_sizes, int n_in,
                              void* d_out, int out_size, void* d_ws, size_t ws_size,
                              hipStream_t stream)
{
    float* ws = (float*)d_ws;
    MegaArgs M;
    M.feature = (const float*)d_in[0];
    // d_in[1] = aspect: unused by the reference
    M.adj     = (const int*)d_in[2];
    M.W0      = (const float*)d_in[3];
    M.b0      = (const float*)d_in[4];
    M.W1      = (const float*)d_in[5];
    M.b1      = (const float*)d_in[6];
    M.A1      = (const float*)d_in[7];
    M.ab1     = (const float*)d_in[8];
    M.A2      = (const float*)d_in[9];
    M.ab2     = (const float*)d_in[10];
    M.gamma   = (const float*)d_in[11];
    M.beta    = (const float*)d_in[12];

    M.s    = ws;                 // 131072 f
    M.psum = ws + 131072;        // 256 f
    M.bA   = ws + 131328;        // 256 f
    M.g_ws = ws + 131584;        // 6144 f
    unsigned short* u = (unsigned short*)(ws + 137728);  // 16B-aligned
    M.Wt0h = u;                          // 589824 each
    M.Wt0l = M.Wt0h + 589824;
    M.Wt1h = M.Wt0l + 589824;
    M.Wt1l = M.Wt1h + 589824;
    M.WAth = M.Wt1l + 589824;            // 196608 each (2 layers)
    M.WAtl = M.WAth + 196608;
    M.fh   = M.WAtl + 196608;            // 786432 each from here
    M.fl   = M.fh + 786432;
    M.hth  = M.htl - 786432;  // placeholder overwritten below
    M.hth  = M.fl + 786432;
    M.htl  = M.hth + 786432;
    M.ndh  = M.htl + 786432;
    M.ndl  = M.ndh + 786432;
    M.ph   = M.ndl + 786432;             // 131072 each
    M.pl   = M.ph + 131072;

    float* out  = (float*)d_out;
    M.out_graph = out;           // (8,768)
    M.out_node  = out + 6144;    // (8,128,768)

    mega_k<<<256, 256, 0, stream>>>(M);
}

// Round 3
// 161.594 us; speedup vs baseline: 3.0848x; 1.8286x over previous
//
#include <hip/hip_runtime.h>
#include <math.h>

#define NEG_V (-1e30f)
#define SLOPE_V 0.01f
#define EPS_V 1e-5f

typedef __attribute__((ext_vector_type(8))) short bs8;    // 8 bf16 (4 VGPRs)
typedef __attribute__((ext_vector_type(4))) float f32x4;  // mfma acc

// ---------------------------------------------------------------------------
// Round 3: REVERT to the validated multi-kernel structure (round 0, 175.6us).
// Persistent-kernel post-mortem (rounds 1-2): SW grid barriers cost >= the
// CP-coordinated kernel boundary on multi-XCD (8 barriers, each needing
// agent-scope wb/inv; best case ~4us == HW boundary) -> structural dead end.
// This round attacks the measured stall profile instead (round-2 counters:
// occupancy at structural max, VALUBusy 2.4% -> latency-chain-bound phases):
//   1) mfma_loop: 2-deep register prefetch (X/Y sets, 2-step unroll) so the
//      global->reg load window spans ~2 k-steps (>~600cyc L3 latency).
//   2) prep WA job: same 2-deep prefetch of its 4 float4 operand loads.
//   3) score: float4-vectorized st tile load (validated in mega rounds).
//   4) gsum: 4-accumulator unrolled row sum (16 loads in flight).
// All phase MATH is identical to round 0 (gsum reassociation ~1e-6).
// ---------------------------------------------------------------------------

// Split fp32 x into bf16 hi + bf16 lo (RNE both). x ≈ hi + lo, rel err ~2^-17.
__device__ __forceinline__ void split2(float x, unsigned short& hi, unsigned short& lo) {
    unsigned u = __float_as_uint(x);
    unsigned h = (u + 0x7FFFu + ((u >> 16) & 1u)) >> 16;
    hi = (unsigned short)h;
    float hf = __uint_as_float(h << 16);
    float l = x - hf;
    unsigned ul = __float_as_uint(l);
    lo = (unsigned short)((ul + 0x7FFFu + ((ul >> 16) & 1u)) >> 16);
}

// ---------------------------------------------------------------------------
// Software-pipelined split-bf16 MFMA mainloop, 2-deep prefetch version.
//  - double-buffered LDS stages (buf[2][4][64][40], 40 KB): ONE barrier/step
//  - TWO register prefetch sets (X = even k-steps, Y = odd): each global load
//    is issued ~2 steps before its LDS write -> ~800+cyc window hides L3/HBM.
//  - W_{i+2} vs R_i safety: unchanged from validated round-0 argument (write
//    targets the OTHER stage; reads of stage i complete before the step
//    barrier because the MFMAs consuming them issue before barrier arrival).
// Requires K % 64 == 0 and K >= 64 (gemm K=768, attn K=128: both OK).
// Caller must __syncthreads() before reusing the LDS for an epilogue.
// ---------------------------------------------------------------------------
#define MFMA_COMPUTE(B0)                                                       \
    {                                                                          \
        bs8 a_h[2], a_l[2], b_h[2], b_l[2];                                    \
        _Pragma("unroll")                                                      \
        for (int t = 0; t < 2; t++) {                                          \
            a_h[t] = *(bs8*)&buf[(B0) + 0][wm0 + t * 16 + lm][q * 8];          \
            a_l[t] = *(bs8*)&buf[(B0) + 1][wm0 + t * 16 + lm][q * 8];          \
            b_h[t] = *(bs8*)&buf[(B0) + 2][wn0 + t * 16 + lm][q * 8];          \
            b_l[t] = *(bs8*)&buf[(B0) + 3][wn0 + t * 16 + lm][q * 8];          \
        }                                                                      \
        _Pragma("unroll")                                                      \
        for (int mt = 0; mt < 2; mt++)                                         \
            _Pragma("unroll")                                                  \
            for (int nt = 0; nt < 2; nt++) {                                   \
                acc[mt][nt] = __builtin_amdgcn_mfma_f32_16x16x32_bf16(a_h[mt], b_h[nt], acc[mt][nt], 0, 0, 0); \
                acc[mt][nt] = __builtin_amdgcn_mfma_f32_16x16x32_bf16(a_h[mt], b_l[nt], acc[mt][nt], 0, 0, 0); \
                acc[mt][nt] = __builtin_amdgcn_mfma_f32_16x16x32_bf16(a_l[mt], b_h[nt], acc[mt][nt], 0, 0, 0); \
            }                                                                  \
    }

__device__ __forceinline__ void mfma_loop(
    const unsigned short* __restrict__ Ahg, const unsigned short* __restrict__ Alg,
    int lda,
    const unsigned short* __restrict__ Bhg, const unsigned short* __restrict__ Blg,
    int ldb, int K, int row0, int col0,
    f32x4 (&acc)[2][2],
    unsigned short (*buf)[64][40])   // buf[8]: stage*4 + {Ah,Al,Bh,Bl}
{
    const int tid = threadIdx.x;
    const int lane = tid & 63, wid = tid >> 6;
    const int wm0 = (wid >> 1) * 32, wn0 = (wid & 1) * 32;
    const int lm = lane & 15, q = lane >> 4;
    const int sr = tid >> 2, sc = (tid & 3) * 8;

    const unsigned short* pAh = Ahg + (size_t)(row0 + sr) * lda + sc;
    const unsigned short* pAl = Alg + (size_t)(row0 + sr) * lda + sc;
    const unsigned short* pBh = Bhg + (size_t)(col0 + sr) * ldb + sc;
    const unsigned short* pBl = Blg + (size_t)(col0 + sr) * ldb + sc;

    // 2-deep prefetch: X = k-steps 0,2,4,..  Y = k-steps 1,3,5,..
    bs8 xAh = *(const bs8*)(pAh);
    bs8 xAl = *(const bs8*)(pAl);
    bs8 xBh = *(const bs8*)(pBh);
    bs8 xBl = *(const bs8*)(pBl);
    bs8 yAh = *(const bs8*)(pAh + 32);
    bs8 yAl = *(const bs8*)(pAl + 32);
    bs8 yBh = *(const bs8*)(pBh + 32);
    bs8 yBl = *(const bs8*)(pBl + 32);

    for (int k0 = 0; k0 < K; k0 += 64) {
        // ---- even step: stage 0, X regs ----
        *(bs8*)&buf[0][sr][sc] = xAh;
        *(bs8*)&buf[1][sr][sc] = xAl;
        *(bs8*)&buf[2][sr][sc] = xBh;
        *(bs8*)&buf[3][sr][sc] = xBl;
        __syncthreads();
        if (k0 + 64 < K) {
            xAh = *(const bs8*)(pAh + k0 + 64);
            xAl = *(const bs8*)(pAl + k0 + 64);
            xBh = *(const bs8*)(pBh + k0 + 64);
            xBl = *(const bs8*)(pBl + k0 + 64);
        }
        MFMA_COMPUTE(0);
        // ---- odd step: stage 1, Y regs ----
        *(bs8*)&buf[4][sr][sc] = yAh;
        *(bs8*)&buf[5][sr][sc] = yAl;
        *(bs8*)&buf[6][sr][sc] = yBh;
        *(bs8*)&buf[7][sr][sc] = yBl;
        __syncthreads();
        if (k0 + 96 < K) {
            yAh = *(const bs8*)(pAh + k0 + 96);
            yAl = *(const bs8*)(pAl + k0 + 96);
            yBh = *(const bs8*)(pBh + k0 + 96);
            yBl = *(const bs8*)(pBl + k0 + 96);
        }
        MFMA_COMPUTE(4);
    }
}

// 64x64 fp32 tile -> transposed bf16 hi/lo (dst[n][k] = src[k][n]).
__device__ __forceinline__ void transpose_split_tile(
    const float* __restrict__ src, int src_ld,
    unsigned short* __restrict__ dh, unsigned short* __restrict__ dl, int dst_ld,
    unsigned short (*Th)[72], unsigned short (*Tl)[72])
{
    int tid = threadIdx.x;
    int r = tid >> 2;
    int cb = (tid & 3) * 16;
#pragma unroll
    for (int cc = 0; cc < 16; cc += 4) {
        float4 v = *(const float4*)(src + (size_t)r * src_ld + cb + cc);
        unsigned short hh, ll;
        split2(v.x, hh, ll); Th[cb + cc + 0][r] = hh; Tl[cb + cc + 0][r] = ll;
        split2(v.y, hh, ll); Th[cb + cc + 1][r] = hh; Tl[cb + cc + 1][r] = ll;
        split2(v.z, hh, ll); Th[cb + cc + 2][r] = hh; Tl[cb + cc + 2][r] = ll;
        split2(v.w, hh, ll); Th[cb + cc + 3][r] = hh; Tl[cb + cc + 3][r] = ll;
    }
    __syncthreads();
    int n = tid >> 2, ch = (tid & 3) * 8;
    *(bs8*)(dh + (size_t)n * dst_ld + ch)      = *(bs8*)&Th[n][ch];
    *(bs8*)(dh + (size_t)n * dst_ld + ch + 32) = *(bs8*)&Th[n][ch + 32];
    *(bs8*)(dl + (size_t)n * dst_ld + ch)      = *(bs8*)&Tl[n][ch];
    *(bs8*)(dl + (size_t)n * dst_ld + ch + 32) = *(bs8*)&Tl[n][ch + 32];
}

// flat fp32 -> split bf16 hi/lo, 4096 elems/job, 16/thread.
__device__ __forceinline__ void flat_split_job(
    const float* __restrict__ src, unsigned short* __restrict__ dh,
    unsigned short* __restrict__ dl, size_t base)
{
    unsigned short hh, ll;
#pragma unroll
    for (int g = 0; g < 2; g++) {
        bs8 sh, sl;
#pragma unroll
        for (int cc = 0; cc < 8; cc += 4) {
            float4 v = *(const float4*)(src + base + g * 8 + cc);
            split2(v.x, hh, ll); sh[cc + 0] = (short)hh; sl[cc + 0] = (short)ll;
            split2(v.y, hh, ll); sh[cc + 1] = (short)hh; sl[cc + 1] = (short)ll;
            split2(v.z, hh, ll); sh[cc + 2] = (short)hh; sl[cc + 2] = (short)ll;
            split2(v.w, hh, ll); sh[cc + 3] = (short)hh; sl[cc + 3] = (short)ll;
        }
        *(bs8*)(dh + base + g * 8) = sh;
        *(bs8*)(dl + base + g * 8) = sl;
    }
}

// WA job: split one X/Y operand set into the (single-stage) LDS buffers.
#define WA_STORE(va0, va1, vw0, vw1) {                                       \
    unsigned short hv, lv;                                                   \
    split2((va0).x, hv, lv); Ah[acs + 0][akk] = hv; Al[acs + 0][akk] = lv;   \
    split2((va0).y, hv, lv); Ah[acs + 1][akk] = hv; Al[acs + 1][akk] = lv;   \
    split2((va0).z, hv, lv); Ah[acs + 2][akk] = hv; Al[acs + 2][akk] = lv;   \
    split2((va0).w, hv, lv); Ah[acs + 3][akk] = hv; Al[acs + 3][akk] = lv;   \
    split2((va1).x, hv, lv); Ah[acs + 4][akk] = hv; Al[acs + 4][akk] = lv;   \
    split2((va1).y, hv, lv); Ah[acs + 5][akk] = hv; Al[acs + 5][akk] = lv;   \
    split2((va1).z, hv, lv); Ah[acs + 6][akk] = hv; Al[acs + 6][akk] = lv;   \
    split2((va1).w, hv, lv); Ah[acs + 7][akk] = hv; Al[acs + 7][akk] = lv;   \
    bs8 sh, sl;                                                              \
    split2((vw0).x, hv, lv); sh[0] = (short)hv; sl[0] = (short)lv;           \
    split2((vw0).y, hv, lv); sh[1] = (short)hv; sl[1] = (short)lv;           \
    split2((vw0).z, hv, lv); sh[2] = (short)hv; sl[2] = (short)lv;           \
    split2((vw0).w, hv, lv); sh[3] = (short)hv; sl[3] = (short)lv;           \
    split2((vw1).x, hv, lv); sh[4] = (short)hv; sl[4] = (short)lv;           \
    split2((vw1).y, hv, lv); sh[5] = (short)hv; sl[5] = (short)lv;           \
    split2((vw1).z, hv, lv); sh[6] = (short)hv; sl[6] = (short)lv;           \
    split2((vw1).w, hv, lv); sh[7] = (short)hv; sl[7] = (short)lv;           \
    *(bs8*)&Bh[br][bks] = sh;                                                \
    *(bs8*)&Bl[br][bks] = sl;                                                \
}

#define WA_FRAG() {                                                          \
    bs8 a_h[2], a_l[2], b_h[2], b_l[2];                                      \
    _Pragma("unroll")                                                        \
    for (int t = 0; t < 2; t++) {                                            \
        a_h[t] = *(bs8*)&Ah[wm0 + t * 16 + lm][q * 8];                       \
        a_l[t] = *(bs8*)&Al[wm0 + t * 16 + lm][q * 8];                       \
        b_h[t] = *(bs8*)&Bh[wn0 + t * 16 + lm][q * 8];                       \
        b_l[t] = *(bs8*)&Bl[wn0 + t * 16 + lm][q * 8];                       \
    }                                                                        \
    _Pragma("unroll")                                                        \
    for (int mt = 0; mt < 2; mt++)                                           \
        _Pragma("unroll")                                                    \
        for (int nt = 0; nt < 2; nt++) {                                     \
            acc[mt][nt] = __builtin_amdgcn_mfma_f32_16x16x32_bf16(a_h[mt], b_h[nt], acc[mt][nt], 0, 0, 0); \
            acc[mt][nt] = __builtin_amdgcn_mfma_f32_16x16x32_bf16(a_h[mt], b_l[nt], acc[mt][nt], 0, 0, 0); \
            acc[mt][nt] = __builtin_amdgcn_mfma_f32_16x16x32_bf16(a_l[mt], b_h[nt], acc[mt][nt], 0, 0, 0); \
        }                                                                    \
}

// ---------------------------------------------------------------------------
// Prep, grid 530:
//   [0,144)   W0 -> Wt0 transposed split
//   [144,288) W1 -> Wt1 transposed split
//   [288,480) feature -> fh/fl row-major split
//   [480,528) WA via MFMA, operands split on the fly (2-deep prefetched)
//   [528,530) bA[layer][c] = sum_k b[k] * A1x[k][c]
// ---------------------------------------------------------------------------
__global__ __launch_bounds__(256) void prep_k(
    const float* __restrict__ W0, const float* __restrict__ W1,
    const float* __restrict__ A1, const float* __restrict__ feature,
    const float* __restrict__ b0, const float* __restrict__ b1,
    unsigned short* Wt0h, unsigned short* Wt0l,
    unsigned short* Wt1h, unsigned short* Wt1l,
    unsigned short* fh, unsigned short* fl,
    unsigned short* WAth, unsigned short* WAtl,
    float* bA)
{
    __shared__ __align__(16) char smem[20480];
    int id = blockIdx.x, tid = threadIdx.x;
    if (id < 288) {
        unsigned short (*Th)[72] = (unsigned short(*)[72])(smem);
        unsigned short (*Tl)[72] = (unsigned short(*)[72])(smem + 9216);
        if (id < 144) {
            int kt = id / 12, nt = id % 12;
            transpose_split_tile(W0 + (size_t)(kt * 64) * 768 + nt * 64, 768,
                                 Wt0h + (size_t)(nt * 64) * 768 + kt * 64,
                                 Wt0l + (size_t)(nt * 64) * 768 + kt * 64, 768, Th, Tl);
        } else {
            int r = id - 144, kt = r / 12, nt = r % 12;
            transpose_split_tile(W1 + (size_t)(kt * 64) * 768 + nt * 64, 768,
                                 Wt1h + (size_t)(nt * 64) * 768 + kt * 64,
                                 Wt1l + (size_t)(nt * 64) * 768 + kt * 64, 768, Th, Tl);
        }
    } else if (id < 480) {
        flat_split_job(feature, fh, fl, (size_t)(id - 288) * 4096 + tid * 16);
    } else if (id < 528) {
        // --- WA MFMA job, self-splitting operands, 2-deep prefetch ---
        int j = id - 480;
        int rt = j % 12, ct = (j / 12) & 1, layer = j / 24;
        const float* W = layer ? W1 : W0;
        const int r0 = rt * 64;
        unsigned short (*Ah)[40] = (unsigned short(*)[40])(smem);
        unsigned short (*Al)[40] = (unsigned short(*)[40])(smem + 5120);
        unsigned short (*Bh)[40] = (unsigned short(*)[40])(smem + 10240);
        unsigned short (*Bl)[40] = (unsigned short(*)[40])(smem + 15360);
        const int lane = tid & 63, wid = tid >> 6;
        const int wm0 = (wid >> 1) * 32, wn0 = (wid & 1) * 32;
        const int lm = lane & 15, q = lane >> 4;
        const int akk = tid & 31, acs = (tid >> 5) * 8;   // A: k-row, c-seg
        const int br = tid >> 2, bks = (tid & 3) * 8;     // B: r-row, k-seg
        const float* A1p = A1 + (size_t)(ct * 768 + akk) * 64 + acs;
        const float* Wp  = W + (size_t)(r0 + br) * 768 + bks;
        // prologue: X = steps 0,2,..  Y = steps 1,3,..  (k-step stride 32)
        float4 xa0 = *(const float4*)(A1p);
        float4 xa1 = *(const float4*)(A1p + 4);
        float4 xw0 = *(const float4*)(Wp);
        float4 xw1 = *(const float4*)(Wp + 4);
        float4 ya0 = *(const float4*)(A1p + 32 * 64);
        float4 ya1 = *(const float4*)(A1p + 32 * 64 + 4);
        float4 yw0 = *(const float4*)(Wp + 32);
        float4 yw1 = *(const float4*)(Wp + 36);
        f32x4 acc[2][2] = {};
        for (int k0 = 0; k0 < 768; k0 += 64) {
            // ---- even step ----
            WA_STORE(xa0, xa1, xw0, xw1);
            __syncthreads();
            if (k0 + 64 < 768) {
                xa0 = *(const float4*)(A1p + (size_t)(k0 + 64) * 64);
                xa1 = *(const float4*)(A1p + (size_t)(k0 + 64) * 64 + 4);
                xw0 = *(const float4*)(Wp + k0 + 64);
                xw1 = *(const float4*)(Wp + k0 + 68);
            }
            WA_FRAG();
            __syncthreads();
            // ---- odd step ----
            WA_STORE(ya0, ya1, yw0, yw1);
            __syncthreads();
            if (k0 + 96 < 768) {
                ya0 = *(const float4*)(A1p + (size_t)(k0 + 96) * 64);
                ya1 = *(const float4*)(A1p + (size_t)(k0 + 96) * 64 + 4);
                yw0 = *(const float4*)(Wp + k0 + 96);
                yw1 = *(const float4*)(Wp + k0 + 100);
            }
            WA_FRAG();
            __syncthreads();
        }
        // epilogue: D[m=c_local][n=r_local] -> WAt[layer][c0+m][r0+n]
        const int c0 = ct * 64;
        size_t base = (size_t)layer * 98304;
#pragma unroll
        for (int mt = 0; mt < 2; mt++)
#pragma unroll
            for (int nt = 0; nt < 2; nt++) {
                int n = r0 + wn0 + nt * 16 + lm;
#pragma unroll
                for (int i = 0; i < 4; i++) {
                    int m = c0 + wm0 + mt * 16 + q * 4 + i;
                    unsigned short hv, lv;
                    split2(acc[mt][nt][i], hv, lv);
                    WAth[base + (size_t)m * 768 + n] = hv;
                    WAtl[base + (size_t)m * 768 + n] = lv;
                }
            }
    } else {
        float* redb = (float*)(smem);    // 256 f
        int layer = id - 528;
        const float* bv = layer ? b1 : b0;
        int c = tid & 127, half = tid >> 7;
        float acc = 0.f;
        for (int kk = 0; kk < 384; kk++) {
            int k = half * 384 + kk;
            int row = (c < 64 ? k : 768 + k);
            acc += bv[k] * A1[(size_t)row * 64 + (c & 63)];
        }
        redb[tid] = acc;
        __syncthreads();
        if (tid < 128) bA[layer * 128 + tid] = redb[tid] + redb[tid + 128];
    }
}

// ---------------------------------------------------------------------------
// Fused gemm: grid (14, 16). col-tiles 0-11: h = A@W + bias -> transposed
// split hth/htl (attn B). col-tiles 12-13: s = A@WA -> fp32 (bias in score).
// 2-deep-prefetch mainloop (this round). Epilogues unchanged.
// ---------------------------------------------------------------------------
__global__ __launch_bounds__(256) void gemm_fused_k(
    const unsigned short* __restrict__ Ahg, const unsigned short* __restrict__ Alg,
    const unsigned short* __restrict__ Wth, const unsigned short* __restrict__ Wtl,
    const unsigned short* __restrict__ WAth, const unsigned short* __restrict__ WAtl,
    const float* __restrict__ bias,
    unsigned short* __restrict__ hth, unsigned short* __restrict__ htl,
    float* __restrict__ s)
{
    __shared__ unsigned short smem[8][64][40];   // 40 KB: 2-stage x 4 bufs
    int bx = blockIdx.x, row0 = blockIdx.y * 64;
    const unsigned short* Bh;
    const unsigned short* Bl;
    int col0;
    if (bx < 12) { Bh = Wth;  Bl = Wtl;  col0 = bx * 64; }
    else         { Bh = WAth; Bl = WAtl; col0 = (bx - 12) * 64; }
    f32x4 acc[2][2] = {};
    mfma_loop(Ahg, Alg, 768, Bh, Bl, 768, 768, row0, col0, acc, smem);
    int tid = threadIdx.x, lane = tid & 63, wid = tid >> 6;
    int wm0 = (wid >> 1) * 32, wn0 = (wid & 1) * 32;
    int lm = lane & 15, q = lane >> 4;
    if (bx >= 12) {
#pragma unroll
        for (int mt = 0; mt < 2; mt++)
#pragma unroll
            for (int nt = 0; nt < 2; nt++) {
                int c = col0 + wn0 + nt * 16 + lm;
#pragma unroll
                for (int i = 0; i < 4; i++) {
                    int r = row0 + wm0 + mt * 16 + q * 4 + i;
                    s[(size_t)r * 128 + c] = acc[mt][nt][i];
                }
            }
        return;
    }
    __syncthreads();   // drain last-stage LDS reads before epilogue reuse
    unsigned short* flat = &smem[0][0][0];
    unsigned short (*Hi)[69] = (unsigned short(*)[69])flat;
    unsigned short (*Lo)[69] = (unsigned short(*)[69])(flat + 4416);
#pragma unroll
    for (int mt = 0; mt < 2; mt++)
#pragma unroll
        for (int nt = 0; nt < 2; nt++) {
            int c = wn0 + nt * 16 + lm;
            float bv = bias[col0 + c];
#pragma unroll
            for (int i = 0; i < 4; i++) {
                int r = wm0 + mt * 16 + q * 4 + i;
                unsigned short hv, lv;
                split2(acc[mt][nt][i] + bv, hv, lv);
                Hi[r][c] = hv; Lo[r][c] = lv;
            }
        }
    __syncthreads();
    int d = tid >> 2, kq = (tid & 3) * 16;
    int b = row0 >> 7, kb = row0 & 127;
    bs8 th0, th1, tl0, tl1;
#pragma unroll
    for (int e = 0; e < 8; e++) {
        th0[e] = Hi[kq + e][d];     th1[e] = Hi[kq + 8 + e][d];
        tl0[e] = Lo[kq + e][d];     tl1[e] = Lo[kq + 8 + e][d];
    }
    size_t to = ((size_t)b * 768 + col0 + d) * 128 + kb + kq;
    *(bs8*)(hth + to) = th0; *(bs8*)(hth + to + 8) = th1;
    *(bs8*)(htl + to) = tl0; *(bs8*)(htl + to + 8) = tl1;
}

// ---------------------------------------------------------------------------
// score_k: masked score + exp (no max-shift; |e|<<80 by construction, masked
// entries = 0 exactly). Writes split exp to ph/pl + per-block sum psum[b][32].
// grid (32 i-tiles, 8 b), block 256. float4 st load (validated in mega round).
// ---------------------------------------------------------------------------
__global__ __launch_bounds__(256) void score_k(
    const float* __restrict__ s, const int* __restrict__ adj,
    const float* __restrict__ ab1, const float* __restrict__ A2,
    const float* __restrict__ ab2, const float* __restrict__ bA,
    unsigned short* __restrict__ ph, unsigned short* __restrict__ pl,
    float* __restrict__ psum)
{
    __shared__ float st[128][65];
    __shared__ float ss[4][65];
    __shared__ float a2s[64];
    __shared__ float warr[4];
    const int bx = blockIdx.x, b = blockIdx.y, tid = threadIdx.x;
    const int i0 = bx * 4;
#pragma unroll
    for (int g = 0; g < 8; g++) {     // float4-vectorized st load
        int idx4 = tid + g * 256;
        int j = idx4 >> 4;
        int h2 = (idx4 & 15) * 4;
        float4 v = *(const float4*)&s[(size_t)(b * 128 + j) * 128 + 64 + h2];
        float4 bv = *(const float4*)&bA[64 + h2];
        st[j][h2 + 0] = v.x + bv.x;
        st[j][h2 + 1] = v.y + bv.y;
        st[j][h2 + 2] = v.z + bv.z;
        st[j][h2 + 3] = v.w + bv.w;
    }
    {
        int i = tid >> 6, h2 = tid & 63;
        ss[i][h2] = s[(size_t)(b * 128 + i0 + i) * 128 + h2] + bA[h2] + ab1[h2];
    }
    if (tid < 64) a2s[tid] = A2[tid];
    __syncthreads();
    const float ab2v = ab2[0];
    const int rr = tid >> 7;
    const int j = tid & 127;
    const int r0 = rr * 2, r1 = rr * 2 + 1;
    float acc0 = 0.f, acc1 = 0.f;
#pragma unroll 4
    for (int h2 = 0; h2 < 64; h2++) {
        float bb = st[j][h2];
        float cv = a2s[h2];
        acc0 = fmaf(fmaxf(ss[r0][h2] + bb, 0.f), cv, acc0);
        acc1 = fmaf(fmaxf(ss[r1][h2] + bb, 0.f), cv, acc1);
    }
    float e0 = acc0 + ab2v; e0 = (e0 > 0.f) ? e0 : SLOPE_V * e0;
    float e1 = acc1 + ab2v; e1 = (e1 > 0.f) ? e1 : SLOPE_V * e1;
    size_t o0 = (size_t)b * 16384 + (size_t)(i0 + r0) * 128 + j;
    size_t o1 = (size_t)b * 16384 + (size_t)(i0 + r1) * 128 + j;
    float v0 = adj[o0] ? expf(e0) : 0.f;
    float v1 = adj[o1] ? expf(e1) : 0.f;
    unsigned short hv, lv;
    split2(v0, hv, lv); ph[o0] = hv; pl[o0] = lv;
    split2(v1, hv, lv); ph[o1] = hv; pl[o1] = lv;
    float vs = v0 + v1;
#pragma unroll
    for (int o = 32; o > 0; o >>= 1) vs += __shfl_down(vs, o);
    if ((tid & 63) == 0) warr[tid >> 6] = vs;
    __syncthreads();
    if (tid == 0) psum[b * 32 + bx] = warr[0] + warr[1] + warr[2] + warr[3];
}

// ---------------------------------------------------------------------------
// attn: node[b] = (1/sum_b) * P[b] @ h[b]; alpha from psum partials.
// 2-deep-prefetch mainloop. Outputs fp32 node AND split ndh/ndl. grid (12,2,8).
// ---------------------------------------------------------------------------
__global__ __launch_bounds__(256) void attn_mfma_k(
    const unsigned short* __restrict__ ph, const unsigned short* __restrict__ pl,
    const unsigned short* __restrict__ hth, const unsigned short* __restrict__ htl,
    const float* __restrict__ psum, float* __restrict__ node,
    unsigned short* __restrict__ nodeh, unsigned short* __restrict__ nodel)
{
    __shared__ unsigned short smem[8][64][40];   // 40 KB
    __shared__ float sred[33];
    int b = blockIdx.z;
    int row0 = blockIdx.y * 64, col0 = blockIdx.x * 64;
    int tid = threadIdx.x;
    if (tid < 32) sred[tid] = psum[b * 32 + tid];
    __syncthreads();
    if (tid == 0) {
        float t = 0.f;
#pragma unroll
        for (int i = 0; i < 32; i++) t += sred[i];
        sred[32] = 1.0f / t;
    }
    __syncthreads();
    float alpha = sred[32];
    f32x4 acc[2][2] = {};
    mfma_loop(ph + (size_t)b * 16384, pl + (size_t)b * 16384, 128,
              hth + (size_t)b * 98304, htl + (size_t)b * 98304, 128, 128,
              row0, col0, acc, smem);
    __syncthreads();   // drain last-stage LDS reads before epilogue reuse
    float* C = node + (size_t)b * 98304;
    unsigned short* flat = &smem[0][0][0];
    unsigned short (*Hi)[69] = (unsigned short(*)[69])flat;
    unsigned short (*Lo)[69] = (unsigned short(*)[69])(flat + 4416);
    int lane = tid & 63, wid = tid >> 6;
    int wm0 = (wid >> 1) * 32, wn0 = (wid & 1) * 32;
    int lm = lane & 15, q = lane >> 4;
#pragma unroll
    for (int mt = 0; mt < 2; mt++)
#pragma unroll
        for (int nt = 0; nt < 2; nt++) {
            int c = wn0 + nt * 16 + lm;
#pragma unroll
            for (int i = 0; i < 4; i++) {
                int r = wm0 + mt * 16 + q * 4 + i;
                float v = acc[mt][nt][i] * alpha;
                C[(size_t)(row0 + r) * 768 + col0 + c] = v;
                unsigned short hv, lv;
                split2(v, hv, lv);
                Hi[r][c] = hv; Lo[r][c] = lv;
            }
        }
    __syncthreads();
    int r = tid >> 2, cq = (tid & 3) * 16;
    bs8 vh0, vh1, vl0, vl1;
#pragma unroll
    for (int e = 0; e < 8; e++) {
        vh0[e] = Hi[r][cq + e];     vh1[e] = Hi[r][cq + 8 + e];
        vl0[e] = Lo[r][cq + e];     vl1[e] = Lo[r][cq + 8 + e];
    }
    size_t ro = (size_t)(b * 128 + row0 + r) * 768 + col0 + cq;
    *(bs8*)(nodeh + ro) = vh0; *(bs8*)(nodeh + ro + 8) = vh1;
    *(bs8*)(nodel + ro) = vl0; *(bs8*)(nodel + ro + 8) = vl1;
}

// ---------------------------------------------------------------------------
// Fused graph-sum + batch-norm. grid 12, block 512.
// 4-accumulator unrolled row sum (16 loads in flight; reassoc ~1e-6).
// ---------------------------------------------------------------------------
__global__ __launch_bounds__(512) void gsum_bnorm_k(
    const float* __restrict__ node, const float* __restrict__ gamma,
    const float* __restrict__ beta, float* __restrict__ out)
{
    __shared__ float gbuf[8][64];
    __shared__ float mean_s[64], inv_s[64];
    int tid = threadIdx.x;
    int bg = tid >> 6, dl = tid & 63;
    int d = blockIdx.x * 64 + dl;
    const float* np = node + (size_t)(bg * 128) * 768 + d;
    float a0 = 0.f, a1 = 0.f, a2 = 0.f, a3 = 0.f;
#pragma unroll 4
    for (int i = 0; i < 128; i += 4) {
        a0 += np[(size_t)(i + 0) * 768];
        a1 += np[(size_t)(i + 1) * 768];
        a2 += np[(size_t)(i + 2) * 768];
        a3 += np[(size_t)(i + 3) * 768];
    }
    float v = (a0 + a1) + (a2 + a3);
    gbuf[bg][dl] = v;
    __syncthreads();
    if (tid < 64) {
        float m = 0.f;
#pragma unroll
        for (int b = 0; b < 8; b++) m += gbuf[b][tid];
        m *= 0.125f;
        float var = 0.f;
#pragma unroll
        for (int b = 0; b < 8; b++) { float t = gbuf[b][tid] - m; var += t * t; }
        var *= 0.125f;
        mean_s[tid] = m;
        inv_s[tid] = 1.0f / sqrtf(var + EPS_V);
    }
    __syncthreads();
    out[bg * 768 + d] = gamma[d] * (v - mean_s[dl]) * inv_s[dl] + beta[d];
}

// ---------------------------------------------------------------------------
extern "C" void kernel_launch(void* const* d_in, const int* in_sizes, int n_in,
                              void* d_out, int out_size, void* d_ws, size_t ws_size,
                              hipStream_t stream)
{
    const float* feature = (const float*)d_in[0];
    // d_in[1] = aspect: unused by the reference
    const int*   adj     = (const int*)d_in[2];
    const float* W0      = (const float*)d_in[3];
    const float* b0      = (const float*)d_in[4];
    const float* W1      = (const float*)d_in[5];
    const float* b1      = (const float*)d_in[6];
    const float* A1      = (const float*)d_in[7];
    const float* ab1     = (const float*)d_in[8];
    const float* A2      = (const float*)d_in[9];
    const float* ab2     = (const float*)d_in[10];
    const float* gamma   = (const float*)d_in[11];
    const float* beta    = (const float*)d_in[12];

    float* ws    = (float*)d_ws;
    float* s     = ws;               // 131072
    float* psum  = ws + 131072;      // 256
    float* bA    = ws + 131328;      // 256
    unsigned short* u = (unsigned short*)(ws + 131584);  // 16B-aligned
    unsigned short* Wt0h = u;                    // 589824 each
    unsigned short* Wt0l = Wt0h + 589824;
    unsigned short* Wt1h = Wt0l + 589824;
    unsigned short* Wt1l = Wt1h + 589824;
    unsigned short* WAth = Wt1l + 589824;        // 196608 each (2 layers)
    unsigned short* WAtl = WAth + 196608;
    unsigned short* fh   = WAtl + 196608;        // 786432 each from here
    unsigned short* fl   = fh + 786432;
    unsigned short* hth  = fl + 786432;
    unsigned short* htl  = hth + 786432;
    unsigned short* ndh  = htl + 786432;
    unsigned short* ndl  = ndh + 786432;
    unsigned short* ph   = ndl + 786432;         // 131072 each
    unsigned short* pl   = ph + 131072;

    float* out       = (float*)d_out;
    float* graph_out = out;          // (8,768)
    float* node_out  = out + 6144;   // (8,128,768)

    prep_k<<<530, 256, 0, stream>>>(W0, W1, A1, feature, b0, b1,
                                    Wt0h, Wt0l, Wt1h, Wt1l,
                                    fh, fl, WAth, WAtl, bA);

    for (int layer = 0; layer < 2; layer++) {
        const unsigned short* Wth = layer ? Wt1h : Wt0h;
        const unsigned short* Wtl = layer ? Wt1l : Wt0l;
        const float* bb = layer ? b1 : b0;
        const unsigned short* Ahg = layer ? ndh : fh;
        const unsigned short* Alg = layer ? ndl : fl;
        gemm_fused_k<<<dim3(14, 16), 256, 0, stream>>>(
            Ahg, Alg, Wth, Wtl, WAth + (size_t)layer * 98304,
            WAtl + (size_t)layer * 98304, bb, hth, htl, s);
        score_k<<<dim3(32, 8), 256, 0, stream>>>(s, adj, ab1, A2, ab2,
                                                 bA + layer * 128, ph, pl, psum);
        attn_mfma_k<<<dim3(12, 2, 8), 256, 0, stream>>>(ph, pl, hth, htl, psum,
                                                        node_out, ndh, ndl);
    }
    gsum_bnorm_k<<<12, 512, 0, stream>>>(node_out, gamma, beta, graph_out);
}

// Round 4
// 157.240 us; speedup vs baseline: 3.1702x; 1.0277x over previous
//
#include <hip/hip_runtime.h>
#include <math.h>

#define NEG_V (-1e30f)
#define SLOPE_V 0.01f
#define EPS_V 1e-5f

typedef __attribute__((ext_vector_type(8))) short bs8;    // 8 bf16 (4 VGPRs)
typedef __attribute__((ext_vector_type(4))) float f32x4;  // mfma acc

// ---------------------------------------------------------------------------
// Round 4: XCD-locality swizzle (T1) on top of the validated round-3 code.
// Theory: phases are L2/L3-traffic-bound by cross-block operand re-reads
// (GEMM: A-panels x14, B-panels x16 = 88MB/layer; score: st x32/batch;
// prep WA: A1 x12/group). CP maps workgroup i -> XCD i%8, so remap 1-D
// block ids so panel-sharing blocks land on one XCD and share its 4MB L2:
//   gemm:  ids == by (mod 8)  -> A-panel fetched once; B L2-resident/XCD
//   score: b = id%8           -> st tile fetched once per XCD
//   attn:  b = id%8           -> per-batch hth/htl fetched once
//   prep WA: (layer,ct) groups folded onto id residues
// Phase MATH and memory layouts byte-identical to round 3.
// ---------------------------------------------------------------------------

// Split fp32 x into bf16 hi + bf16 lo (RNE both). x ≈ hi + lo, rel err ~2^-17.
__device__ __forceinline__ void split2(float x, unsigned short& hi, unsigned short& lo) {
    unsigned u = __float_as_uint(x);
    unsigned h = (u + 0x7FFFu + ((u >> 16) & 1u)) >> 16;
    hi = (unsigned short)h;
    float hf = __uint_as_float(h << 16);
    float l = x - hf;
    unsigned ul = __float_as_uint(l);
    lo = (unsigned short)((ul + 0x7FFFu + ((ul >> 16) & 1u)) >> 16);
}

// ---------------------------------------------------------------------------
// Software-pipelined split-bf16 MFMA mainloop, 2-deep prefetch (validated r3).
// ---------------------------------------------------------------------------
#define MFMA_COMPUTE(B0)                                                       \
    {                                                                          \
        bs8 a_h[2], a_l[2], b_h[2], b_l[2];                                    \
        _Pragma("unroll")                                                      \
        for (int t = 0; t < 2; t++) {                                          \
            a_h[t] = *(bs8*)&buf[(B0) + 0][wm0 + t * 16 + lm][q * 8];          \
            a_l[t] = *(bs8*)&buf[(B0) + 1][wm0 + t * 16 + lm][q * 8];          \
            b_h[t] = *(bs8*)&buf[(B0) + 2][wn0 + t * 16 + lm][q * 8];          \
            b_l[t] = *(bs8*)&buf[(B0) + 3][wn0 + t * 16 + lm][q * 8];          \
        }                                                                      \
        _Pragma("unroll")                                                      \
        for (int mt = 0; mt < 2; mt++)                                         \
            _Pragma("unroll")                                                  \
            for (int nt = 0; nt < 2; nt++) {                                   \
                acc[mt][nt] = __builtin_amdgcn_mfma_f32_16x16x32_bf16(a_h[mt], b_h[nt], acc[mt][nt], 0, 0, 0); \
                acc[mt][nt] = __builtin_amdgcn_mfma_f32_16x16x32_bf16(a_h[mt], b_l[nt], acc[mt][nt], 0, 0, 0); \
                acc[mt][nt] = __builtin_amdgcn_mfma_f32_16x16x32_bf16(a_l[mt], b_h[nt], acc[mt][nt], 0, 0, 0); \
            }                                                                  \
    }

__device__ __forceinline__ void mfma_loop(
    const unsigned short* __restrict__ Ahg, const unsigned short* __restrict__ Alg,
    int lda,
    const unsigned short* __restrict__ Bhg, const unsigned short* __restrict__ Blg,
    int ldb, int K, int row0, int col0,
    f32x4 (&acc)[2][2],
    unsigned short (*buf)[64][40])   // buf[8]: stage*4 + {Ah,Al,Bh,Bl}
{
    const int tid = threadIdx.x;
    const int lane = tid & 63, wid = tid >> 6;
    const int wm0 = (wid >> 1) * 32, wn0 = (wid & 1) * 32;
    const int lm = lane & 15, q = lane >> 4;
    const int sr = tid >> 2, sc = (tid & 3) * 8;

    const unsigned short* pAh = Ahg + (size_t)(row0 + sr) * lda + sc;
    const unsigned short* pAl = Alg + (size_t)(row0 + sr) * lda + sc;
    const unsigned short* pBh = Bhg + (size_t)(col0 + sr) * ldb + sc;
    const unsigned short* pBl = Blg + (size_t)(col0 + sr) * ldb + sc;

    // 2-deep prefetch: X = k-steps 0,2,4,..  Y = k-steps 1,3,5,..
    bs8 xAh = *(const bs8*)(pAh);
    bs8 xAl = *(const bs8*)(pAl);
    bs8 xBh = *(const bs8*)(pBh);
    bs8 xBl = *(const bs8*)(pBl);
    bs8 yAh = *(const bs8*)(pAh + 32);
    bs8 yAl = *(const bs8*)(pAl + 32);
    bs8 yBh = *(const bs8*)(pBh + 32);
    bs8 yBl = *(const bs8*)(pBl + 32);

    for (int k0 = 0; k0 < K; k0 += 64) {
        // ---- even step: stage 0, X regs ----
        *(bs8*)&buf[0][sr][sc] = xAh;
        *(bs8*)&buf[1][sr][sc] = xAl;
        *(bs8*)&buf[2][sr][sc] = xBh;
        *(bs8*)&buf[3][sr][sc] = xBl;
        __syncthreads();
        if (k0 + 64 < K) {
            xAh = *(const bs8*)(pAh + k0 + 64);
            xAl = *(const bs8*)(pAl + k0 + 64);
            xBh = *(const bs8*)(pBh + k0 + 64);
            xBl = *(const bs8*)(pBl + k0 + 64);
        }
        MFMA_COMPUTE(0);
        // ---- odd step: stage 1, Y regs ----
        *(bs8*)&buf[4][sr][sc] = yAh;
        *(bs8*)&buf[5][sr][sc] = yAl;
        *(bs8*)&buf[6][sr][sc] = yBh;
        *(bs8*)&buf[7][sr][sc] = yBl;
        __syncthreads();
        if (k0 + 96 < K) {
            yAh = *(const bs8*)(pAh + k0 + 96);
            yAl = *(const bs8*)(pAl + k0 + 96);
            yBh = *(const bs8*)(pBh + k0 + 96);
            yBl = *(const bs8*)(pBl + k0 + 96);
        }
        MFMA_COMPUTE(4);
    }
}

// 64x64 fp32 tile -> transposed bf16 hi/lo (dst[n][k] = src[k][n]).
__device__ __forceinline__ void transpose_split_tile(
    const float* __restrict__ src, int src_ld,
    unsigned short* __restrict__ dh, unsigned short* __restrict__ dl, int dst_ld,
    unsigned short (*Th)[72], unsigned short (*Tl)[72])
{
    int tid = threadIdx.x;
    int r = tid >> 2;
    int cb = (tid & 3) * 16;
#pragma unroll
    for (int cc = 0; cc < 16; cc += 4) {
        float4 v = *(const float4*)(src + (size_t)r * src_ld + cb + cc);
        unsigned short hh, ll;
        split2(v.x, hh, ll); Th[cb + cc + 0][r] = hh; Tl[cb + cc + 0][r] = ll;
        split2(v.y, hh, ll); Th[cb + cc + 1][r] = hh; Tl[cb + cc + 1][r] = ll;
        split2(v.z, hh, ll); Th[cb + cc + 2][r] = hh; Tl[cb + cc + 2][r] = ll;
        split2(v.w, hh, ll); Th[cb + cc + 3][r] = hh; Tl[cb + cc + 3][r] = ll;
    }
    __syncthreads();
    int n = tid >> 2, ch = (tid & 3) * 8;
    *(bs8*)(dh + (size_t)n * dst_ld + ch)      = *(bs8*)&Th[n][ch];
    *(bs8*)(dh + (size_t)n * dst_ld + ch + 32) = *(bs8*)&Th[n][ch + 32];
    *(bs8*)(dl + (size_t)n * dst_ld + ch)      = *(bs8*)&Tl[n][ch];
    *(bs8*)(dl + (size_t)n * dst_ld + ch + 32) = *(bs8*)&Tl[n][ch + 32];
}

// flat fp32 -> split bf16 hi/lo, 4096 elems/job, 16/thread.
__device__ __forceinline__ void flat_split_job(
    const float* __restrict__ src, unsigned short* __restrict__ dh,
    unsigned short* __restrict__ dl, size_t base)
{
    unsigned short hh, ll;
#pragma unroll
    for (int g = 0; g < 2; g++) {
        bs8 sh, sl;
#pragma unroll
        for (int cc = 0; cc < 8; cc += 4) {
            float4 v = *(const float4*)(src + base + g * 8 + cc);
            split2(v.x, hh, ll); sh[cc + 0] = (short)hh; sl[cc + 0] = (short)ll;
            split2(v.y, hh, ll); sh[cc + 1] = (short)hh; sl[cc + 1] = (short)ll;
            split2(v.z, hh, ll); sh[cc + 2] = (short)hh; sl[cc + 2] = (short)ll;
            split2(v.w, hh, ll); sh[cc + 3] = (short)hh; sl[cc + 3] = (short)ll;
        }
        *(bs8*)(dh + base + g * 8) = sh;
        *(bs8*)(dl + base + g * 8) = sl;
    }
}

// WA job: split one X/Y operand set into the (single-stage) LDS buffers.
#define WA_STORE(va0, va1, vw0, vw1) {                                       \
    unsigned short hv, lv;                                                   \
    split2((va0).x, hv, lv); Ah[acs + 0][akk] = hv; Al[acs + 0][akk] = lv;   \
    split2((va0).y, hv, lv); Ah[acs + 1][akk] = hv; Al[acs + 1][akk] = lv;   \
    split2((va0).z, hv, lv); Ah[acs + 2][akk] = hv; Al[acs + 2][akk] = lv;   \
    split2((va0).w, hv, lv); Ah[acs + 3][akk] = hv; Al[acs + 3][akk] = lv;   \
    split2((va1).x, hv, lv); Ah[acs + 4][akk] = hv; Al[acs + 4][akk] = lv;   \
    split2((va1).y, hv, lv); Ah[acs + 5][akk] = hv; Al[acs + 5][akk] = lv;   \
    split2((va1).z, hv, lv); Ah[acs + 6][akk] = hv; Al[acs + 6][akk] = lv;   \
    split2((va1).w, hv, lv); Ah[acs + 7][akk] = hv; Al[acs + 7][akk] = lv;   \
    bs8 sh, sl;                                                              \
    split2((vw0).x, hv, lv); sh[0] = (short)hv; sl[0] = (short)lv;           \
    split2((vw0).y, hv, lv); sh[1] = (short)hv; sl[1] = (short)lv;           \
    split2((vw0).z, hv, lv); sh[2] = (short)hv; sl[2] = (short)lv;           \
    split2((vw0).w, hv, lv); sh[3] = (short)hv; sl[3] = (short)lv;           \
    split2((vw1).x, hv, lv); sh[4] = (short)hv; sl[4] = (short)lv;           \
    split2((vw1).y, hv, lv); sh[5] = (short)hv; sl[5] = (short)lv;           \
    split2((vw1).z, hv, lv); sh[6] = (short)hv; sl[6] = (short)lv;           \
    split2((vw1).w, hv, lv); sh[7] = (short)hv; sl[7] = (short)lv;           \
    *(bs8*)&Bh[br][bks] = sh;                                                \
    *(bs8*)&Bl[br][bks] = sl;                                                \
}

#define WA_FRAG() {                                                          \
    bs8 a_h[2], a_l[2], b_h[2], b_l[2];                                      \
    _Pragma("unroll")                                                        \
    for (int t = 0; t < 2; t++) {                                            \
        a_h[t] = *(bs8*)&Ah[wm0 + t * 16 + lm][q * 8];                       \
        a_l[t] = *(bs8*)&Al[wm0 + t * 16 + lm][q * 8];                       \
        b_h[t] = *(bs8*)&Bh[wn0 + t * 16 + lm][q * 8];                       \
        b_l[t] = *(bs8*)&Bl[wn0 + t * 16 + lm][q * 8];                       \
    }                                                                        \
    _Pragma("unroll")                                                        \
    for (int mt = 0; mt < 2; mt++)                                           \
        _Pragma("unroll")                                                    \
        for (int nt = 0; nt < 2; nt++) {                                     \
            acc[mt][nt] = __builtin_amdgcn_mfma_f32_16x16x32_bf16(a_h[mt], b_h[nt], acc[mt][nt], 0, 0, 0); \
            acc[mt][nt] = __builtin_amdgcn_mfma_f32_16x16x32_bf16(a_h[mt], b_l[nt], acc[mt][nt], 0, 0, 0); \
            acc[mt][nt] = __builtin_amdgcn_mfma_f32_16x16x32_bf16(a_l[mt], b_h[nt], acc[mt][nt], 0, 0, 0); \
        }                                                                    \
}

// ---------------------------------------------------------------------------
// Prep, grid 530:
//   [0,144)   W0 -> Wt0 transposed split
//   [144,288) W1 -> Wt1 transposed split
//   [288,480) feature -> fh/fl row-major split
//   [480,528) WA via MFMA (XCD-swizzled job decode: each id residue class
//             handles one (layer,ct) pair -> A1-half fetched ~2x not 12x)
//   [528,530) bA[layer][c] = sum_k b[k] * A1x[k][c]
// ---------------------------------------------------------------------------
__global__ __launch_bounds__(256) void prep_k(
    const float* __restrict__ W0, const float* __restrict__ W1,
    const float* __restrict__ A1, const float* __restrict__ feature,
    const float* __restrict__ b0, const float* __restrict__ b1,
    unsigned short* Wt0h, unsigned short* Wt0l,
    unsigned short* Wt1h, unsigned short* Wt1l,
    unsigned short* fh, unsigned short* fl,
    unsigned short* WAth, unsigned short* WAtl,
    float* bA)
{
    __shared__ __align__(16) char smem[20480];
    int id = blockIdx.x, tid = threadIdx.x;
    if (id < 288) {
        unsigned short (*Th)[72] = (unsigned short(*)[72])(smem);
        unsigned short (*Tl)[72] = (unsigned short(*)[72])(smem + 9216);
        if (id < 144) {
            int kt = id / 12, nt = id % 12;
            transpose_split_tile(W0 + (size_t)(kt * 64) * 768 + nt * 64, 768,
                                 Wt0h + (size_t)(nt * 64) * 768 + kt * 64,
                                 Wt0l + (size_t)(nt * 64) * 768 + kt * 64, 768, Th, Tl);
        } else {
            int r = id - 144, kt = r / 12, nt = r % 12;
            transpose_split_tile(W1 + (size_t)(kt * 64) * 768 + nt * 64, 768,
                                 Wt1h + (size_t)(nt * 64) * 768 + kt * 64,
                                 Wt1l + (size_t)(nt * 64) * 768 + kt * 64, 768, Th, Tl);
        }
    } else if (id < 480) {
        flat_split_job(feature, fh, fl, (size_t)(id - 288) * 4096 + tid * 16);
    } else if (id < 528) {
        // --- WA MFMA job; XCD-friendly decode (bijective over j in [0,48)):
        //     c8 = j&7 selects (layer,ct); rt = j/8 + 6*(c8>=4).
        //     480%8==0, so jobs with equal c8 land on one XCD -> A1-half and
        //     its L2 lines shared by 6 blocks instead of spread over 8 XCDs.
        int j = id - 480;
        int c8 = j & 7, kq8 = j >> 3;           // kq8 0..5
        int layer = (c8 >> 1) & 1;
        int ct = c8 & 1;
        int rt = kq8 + 6 * (c8 >> 2);
        const float* W = layer ? W1 : W0;
        const int r0 = rt * 64;
        unsigned short (*Ah)[40] = (unsigned short(*)[40])(smem);
        unsigned short (*Al)[40] = (unsigned short(*)[40])(smem + 5120);
        unsigned short (*Bh)[40] = (unsigned short(*)[40])(smem + 10240);
        unsigned short (*Bl)[40] = (unsigned short(*)[40])(smem + 15360);
        const int lane = tid & 63, wid = tid >> 6;
        const int wm0 = (wid >> 1) * 32, wn0 = (wid & 1) * 32;
        const int lm = lane & 15, q = lane >> 4;
        const int akk = tid & 31, acs = (tid >> 5) * 8;   // A: k-row, c-seg
        const int br = tid >> 2, bks = (tid & 3) * 8;     // B: r-row, k-seg
        const float* A1p = A1 + (size_t)(ct * 768 + akk) * 64 + acs;
        const float* Wp  = W + (size_t)(r0 + br) * 768 + bks;
        // prologue: X = steps 0,2,..  Y = steps 1,3,..  (k-step stride 32)
        float4 xa0 = *(const float4*)(A1p);
        float4 xa1 = *(const float4*)(A1p + 4);
        float4 xw0 = *(const float4*)(Wp);
        float4 xw1 = *(const float4*)(Wp + 4);
        float4 ya0 = *(const float4*)(A1p + 32 * 64);
        float4 ya1 = *(const float4*)(A1p + 32 * 64 + 4);
        float4 yw0 = *(const float4*)(Wp + 32);
        float4 yw1 = *(const float4*)(Wp + 36);
        f32x4 acc[2][2] = {};
        for (int k0 = 0; k0 < 768; k0 += 64) {
            // ---- even step ----
            WA_STORE(xa0, xa1, xw0, xw1);
            __syncthreads();
            if (k0 + 64 < 768) {
                xa0 = *(const float4*)(A1p + (size_t)(k0 + 64) * 64);
                xa1 = *(const float4*)(A1p + (size_t)(k0 + 64) * 64 + 4);
                xw0 = *(const float4*)(Wp + k0 + 64);
                xw1 = *(const float4*)(Wp + k0 + 68);
            }
            WA_FRAG();
            __syncthreads();
            // ---- odd step ----
            WA_STORE(ya0, ya1, yw0, yw1);
            __syncthreads();
            if (k0 + 96 < 768) {
                ya0 = *(const float4*)(A1p + (size_t)(k0 + 96) * 64);
                ya1 = *(const float4*)(A1p + (size_t)(k0 + 96) * 64 + 4);
                yw0 = *(const float4*)(Wp + k0 + 96);
                yw1 = *(const float4*)(Wp + k0 + 100);
            }
            WA_FRAG();
            __syncthreads();
        }
        // epilogue: D[m=c_local][n=r_local] -> WAt[layer][c0+m][r0+n]
        const int c0 = ct * 64;
        size_t base = (size_t)layer * 98304;
#pragma unroll
        for (int mt = 0; mt < 2; mt++)
#pragma unroll
            for (int nt = 0; nt < 2; nt++) {
                int n = r0 + wn0 + nt * 16 + lm;
#pragma unroll
                for (int i = 0; i < 4; i++) {
                    int m = c0 + wm0 + mt * 16 + q * 4 + i;
                    unsigned short hv, lv;
                    split2(acc[mt][nt][i], hv, lv);
                    WAth[base + (size_t)m * 768 + n] = hv;
                    WAtl[base + (size_t)m * 768 + n] = lv;
                }
            }
    } else {
        float* redb = (float*)(smem);    // 256 f
        int layer = id - 528;
        const float* bv = layer ? b1 : b0;
        int c = tid & 127, half = tid >> 7;
        float acc = 0.f;
        for (int kk = 0; kk < 384; kk++) {
            int k = half * 384 + kk;
            int row = (c < 64 ? k : 768 + k);
            acc += bv[k] * A1[(size_t)row * 64 + (c & 63)];
        }
        redb[tid] = acc;
        __syncthreads();
        if (tid < 128) bA[layer * 128 + tid] = redb[tid] + redb[tid + 128];
    }
}

// ---------------------------------------------------------------------------
// Fused gemm, 1-D grid 224 with XCD swizzle. Decode (bijective):
//   g = id>>3, r = id&7;  by = r + 8*(g>=14);  bx = g - 14*(g>=14)
// => all 14 blocks of row-panel `by` have id == by (mod 8) -> same XCD:
//    A-panel (0.25MB) fetched from L3 once, then L2-hits; full B (3.5MB)
//    becomes L2-resident per XCD across its 28 blocks.
// col-tiles 0-11: h = A@W + bias -> transposed split hth/htl (attn B).
// col-tiles 12-13: s = A@WA -> fp32 (bias added in score).
// ---------------------------------------------------------------------------
__global__ __launch_bounds__(256) void gemm_fused_k(
    const unsigned short* __restrict__ Ahg, const unsigned short* __restrict__ Alg,
    const unsigned short* __restrict__ Wth, const unsigned short* __restrict__ Wtl,
    const unsigned short* __restrict__ WAth, const unsigned short* __restrict__ WAtl,
    const float* __restrict__ bias,
    unsigned short* __restrict__ hth, unsigned short* __restrict__ htl,
    float* __restrict__ s)
{
    __shared__ unsigned short smem[8][64][40];   // 40 KB: 2-stage x 4 bufs
    int id = blockIdx.x;
    int g = id >> 3, r8 = id & 7;
    int hi2 = (g >= 14) ? 1 : 0;
    int by = r8 + 8 * hi2;
    int bx = g - 14 * hi2;
    int row0 = by * 64;
    const unsigned short* Bh;
    const unsigned short* Bl;
    int col0;
    if (bx < 12) { Bh = Wth;  Bl = Wtl;  col0 = bx * 64; }
    else         { Bh = WAth; Bl = WAtl; col0 = (bx - 12) * 64; }
    f32x4 acc[2][2] = {};
    mfma_loop(Ahg, Alg, 768, Bh, Bl, 768, 768, row0, col0, acc, smem);
    int tid = threadIdx.x, lane = tid & 63, wid = tid >> 6;
    int wm0 = (wid >> 1) * 32, wn0 = (wid & 1) * 32;
    int lm = lane & 15, q = lane >> 4;
    if (bx >= 12) {
#pragma unroll
        for (int mt = 0; mt < 2; mt++)
#pragma unroll
            for (int nt = 0; nt < 2; nt++) {
                int c = col0 + wn0 + nt * 16 + lm;
#pragma unroll
                for (int i = 0; i < 4; i++) {
                    int r = row0 + wm0 + mt * 16 + q * 4 + i;
                    s[(size_t)r * 128 + c] = acc[mt][nt][i];
                }
            }
        return;
    }
    __syncthreads();   // drain last-stage LDS reads before epilogue reuse
    unsigned short* flat = &smem[0][0][0];
    unsigned short (*Hi)[69] = (unsigned short(*)[69])flat;
    unsigned short (*Lo)[69] = (unsigned short(*)[69])(flat + 4416);
#pragma unroll
    for (int mt = 0; mt < 2; mt++)
#pragma unroll
        for (int nt = 0; nt < 2; nt++) {
            int c = wn0 + nt * 16 + lm;
            float bv = bias[col0 + c];
#pragma unroll
            for (int i = 0; i < 4; i++) {
                int r = wm0 + mt * 16 + q * 4 + i;
                unsigned short hv, lv;
                split2(acc[mt][nt][i] + bv, hv, lv);
                Hi[r][c] = hv; Lo[r][c] = lv;
            }
        }
    __syncthreads();
    int d = tid >> 2, kq = (tid & 3) * 16;
    int b = row0 >> 7, kb = row0 & 127;
    bs8 th0, th1, tl0, tl1;
#pragma unroll
    for (int e = 0; e < 8; e++) {
        th0[e] = Hi[kq + e][d];     th1[e] = Hi[kq + 8 + e][d];
        tl0[e] = Lo[kq + e][d];     tl1[e] = Lo[kq + 8 + e][d];
    }
    size_t to = ((size_t)b * 768 + col0 + d) * 128 + kb + kq;
    *(bs8*)(hth + to) = th0; *(bs8*)(hth + to + 8) = th1;
    *(bs8*)(htl + to) = tl0; *(bs8*)(htl + to + 8) = tl1;
}

// ---------------------------------------------------------------------------
// score_k: masked score + exp. 1-D grid 256: b = id&7 (batch pinned to XCD,
// st tile of s[b] fetched once per XCD instead of 32x), bx = id>>3.
// ---------------------------------------------------------------------------
__global__ __launch_bounds__(256) void score_k(
    const float* __restrict__ s, const int* __restrict__ adj,
    const float* __restrict__ ab1, const float* __restrict__ A2,
    const float* __restrict__ ab2, const float* __restrict__ bA,
    unsigned short* __restrict__ ph, unsigned short* __restrict__ pl,
    float* __restrict__ psum)
{
    __shared__ float st[128][65];
    __shared__ float ss[4][65];
    __shared__ float a2s[64];
    __shared__ float warr[4];
    const int id = blockIdx.x, tid = threadIdx.x;
    const int b = id & 7, bx = id >> 3;
    const int i0 = bx * 4;
#pragma unroll
    for (int g = 0; g < 8; g++) {     // float4-vectorized st load
        int idx4 = tid + g * 256;
        int j = idx4 >> 4;
        int h2 = (idx4 & 15) * 4;
        float4 v = *(const float4*)&s[(size_t)(b * 128 + j) * 128 + 64 + h2];
        float4 bv = *(const float4*)&bA[64 + h2];
        st[j][h2 + 0] = v.x + bv.x;
        st[j][h2 + 1] = v.y + bv.y;
        st[j][h2 + 2] = v.z + bv.z;
        st[j][h2 + 3] = v.w + bv.w;
    }
    {
        int i = tid >> 6, h2 = tid & 63;
        ss[i][h2] = s[(size_t)(b * 128 + i0 + i) * 128 + h2] + bA[h2] + ab1[h2];
    }
    if (tid < 64) a2s[tid] = A2[tid];
    __syncthreads();
    const float ab2v = ab2[0];
    const int rr = tid >> 7;
    const int j = tid & 127;
    const int r0 = rr * 2, r1 = rr * 2 + 1;
    float acc0 = 0.f, acc1 = 0.f;
#pragma unroll 4
    for (int h2 = 0; h2 < 64; h2++) {
        float bb = st[j][h2];
        float cv = a2s[h2];
        acc0 = fmaf(fmaxf(ss[r0][h2] + bb, 0.f), cv, acc0);
        acc1 = fmaf(fmaxf(ss[r1][h2] + bb, 0.f), cv, acc1);
    }
    float e0 = acc0 + ab2v; e0 = (e0 > 0.f) ? e0 : SLOPE_V * e0;
    float e1 = acc1 + ab2v; e1 = (e1 > 0.f) ? e1 : SLOPE_V * e1;
    size_t o0 = (size_t)b * 16384 + (size_t)(i0 + r0) * 128 + j;
    size_t o1 = (size_t)b * 16384 + (size_t)(i0 + r1) * 128 + j;
    float v0 = adj[o0] ? expf(e0) : 0.f;
    float v1 = adj[o1] ? expf(e1) : 0.f;
    unsigned short hv, lv;
    split2(v0, hv, lv); ph[o0] = hv; pl[o0] = lv;
    split2(v1, hv, lv); ph[o1] = hv; pl[o1] = lv;
    float vs = v0 + v1;
#pragma unroll
    for (int o = 32; o > 0; o >>= 1) vs += __shfl_down(vs, o);
    if ((tid & 63) == 0) warr[tid >> 6] = vs;
    __syncthreads();
    if (tid == 0) psum[b * 32 + bx] = warr[0] + warr[1] + warr[2] + warr[3];
}

// ---------------------------------------------------------------------------
// attn: node[b] = (1/sum_b) * P[b] @ h[b]. 1-D grid 192: b = id&7 (batch
// pinned to XCD -> per-batch ph/pl + hth/htl fetched once per XCD),
// t = id>>3: cx = t%12, ry = t/12.
// ---------------------------------------------------------------------------
__global__ __launch_bounds__(256) void attn_mfma_k(
    const unsigned short* __restrict__ ph, const unsigned short* __restrict__ pl,
    const unsigned short* __restrict__ hth, const unsigned short* __restrict__ htl,
    const float* __restrict__ psum, float* __restrict__ node,
    unsigned short* __restrict__ nodeh, unsigned short* __restrict__ nodel)
{
    __shared__ unsigned short smem[8][64][40];   // 40 KB
    __shared__ float sred[33];
    int id = blockIdx.x;
    int b = id & 7, t = id >> 3;
    int cx = t % 12, ry = t / 12;
    int row0 = ry * 64, col0 = cx * 64;
    int tid = threadIdx.x;
    if (tid < 32) sred[tid] = psum[b * 32 + tid];
    __syncthreads();
    if (tid == 0) {
        float tt = 0.f;
#pragma unroll
        for (int i = 0; i < 32; i++) tt += sred[i];
        sred[32] = 1.0f / tt;
    }
    __syncthreads();
    float alpha = sred[32];
    f32x4 acc[2][2] = {};
    mfma_loop(ph + (size_t)b * 16384, pl + (size_t)b * 16384, 128,
              hth + (size_t)b * 98304, htl + (size_t)b * 98304, 128, 128,
              row0, col0, acc, smem);
    __syncthreads();   // drain last-stage LDS reads before epilogue reuse
    float* C = node + (size_t)b * 98304;
    unsigned short* flat = &smem[0][0][0];
    unsigned short (*Hi)[69] = (unsigned short(*)[69])flat;
    unsigned short (*Lo)[69] = (unsigned short(*)[69])(flat + 4416);
    int lane = tid & 63, wid = tid >> 6;
    int wm0 = (wid >> 1) * 32, wn0 = (wid & 1) * 32;
    int lm = lane & 15, q = lane >> 4;
#pragma unroll
    for (int mt = 0; mt < 2; mt++)
#pragma unroll
        for (int nt = 0; nt < 2; nt++) {
            int c = wn0 + nt * 16 + lm;
#pragma unroll
            for (int i = 0; i < 4; i++) {
                int r = wm0 + mt * 16 + q * 4 + i;
                float v = acc[mt][nt][i] * alpha;
                C[(size_t)(row0 + r) * 768 + col0 + c] = v;
                unsigned short hv, lv;
                split2(v, hv, lv);
                Hi[r][c] = hv; Lo[r][c] = lv;
            }
        }
    __syncthreads();
    int r = tid >> 2, cq = (tid & 3) * 16;
    bs8 vh0, vh1, vl0, vl1;
#pragma unroll
    for (int e = 0; e < 8; e++) {
        vh0[e] = Hi[r][cq + e];     vh1[e] = Hi[r][cq + 8 + e];
        vl0[e] = Lo[r][cq + e];     vl1[e] = Lo[r][cq + 8 + e];
    }
    size_t ro = (size_t)(b * 128 + row0 + r) * 768 + col0 + cq;
    *(bs8*)(nodeh + ro) = vh0; *(bs8*)(nodeh + ro + 8) = vh1;
    *(bs8*)(nodel + ro) = vl0; *(bs8*)(nodel + ro + 8) = vl1;
}

// ---------------------------------------------------------------------------
// Fused graph-sum + batch-norm. grid 12, block 512.
// 4-accumulator unrolled row sum (16 loads in flight).
// ---------------------------------------------------------------------------
__global__ __launch_bounds__(512) void gsum_bnorm_k(
    const float* __restrict__ node, const float* __restrict__ gamma,
    const float* __restrict__ beta, float* __restrict__ out)
{
    __shared__ float gbuf[8][64];
    __shared__ float mean_s[64], inv_s[64];
    int tid = threadIdx.x;
    int bg = tid >> 6, dl = tid & 63;
    int d = blockIdx.x * 64 + dl;
    const float* np = node + (size_t)(bg * 128) * 768 + d;
    float a0 = 0.f, a1 = 0.f, a2 = 0.f, a3 = 0.f;
#pragma unroll 4
    for (int i = 0; i < 128; i += 4) {
        a0 += np[(size_t)(i + 0) * 768];
        a1 += np[(size_t)(i + 1) * 768];
        a2 += np[(size_t)(i + 2) * 768];
        a3 += np[(size_t)(i + 3) * 768];
    }
    float v = (a0 + a1) + (a2 + a3);
    gbuf[bg][dl] = v;
    __syncthreads();
    if (tid < 64) {
        float m = 0.f;
#pragma unroll
        for (int b = 0; b < 8; b++) m += gbuf[b][tid];
        m *= 0.125f;
        float var = 0.f;
#pragma unroll
        for (int b = 0; b < 8; b++) { float t = gbuf[b][tid] - m; var += t * t; }
        var *= 0.125f;
        mean_s[tid] = m;
        inv_s[tid] = 1.0f / sqrtf(var + EPS_V);
    }
    __syncthreads();
    out[bg * 768 + d] = gamma[d] * (v - mean_s[dl]) * inv_s[dl] + beta[d];
}

// ---------------------------------------------------------------------------
extern "C" void kernel_launch(void* const* d_in, const int* in_sizes, int n_in,
                              void* d_out, int out_size, void* d_ws, size_t ws_size,
                              hipStream_t stream)
{
    const float* feature = (const float*)d_in[0];
    // d_in[1] = aspect: unused by the reference
    const int*   adj     = (const int*)d_in[2];
    const float* W0      = (const float*)d_in[3];
    const float* b0      = (const float*)d_in[4];
    const float* W1      = (const float*)d_in[5];
    const float* b1      = (const float*)d_in[6];
    const float* A1      = (const float*)d_in[7];
    const float* ab1     = (const float*)d_in[8];
    const float* A2      = (const float*)d_in[9];
    const float* ab2     = (const float*)d_in[10];
    const float* gamma   = (const float*)d_in[11];
    const float* beta    = (const float*)d_in[12];

    float* ws    = (float*)d_ws;
    float* s     = ws;               // 131072
    float* psum  = ws + 131072;      // 256
    float* bA    = ws + 131328;      // 256
    unsigned short* u = (unsigned short*)(ws + 131584);  // 16B-aligned
    unsigned short* Wt0h = u;                    // 589824 each
    unsigned short* Wt0l = Wt0h + 589824;
    unsigned short* Wt1h = Wt0l + 589824;
    unsigned short* Wt1l = Wt1h + 589824;
    unsigned short* WAth = Wt1l + 589824;        // 196608 each (2 layers)
    unsigned short* WAtl = WAth + 196608;
    unsigned short* fh   = WAtl + 196608;        // 786432 each from here
    unsigned short* fl   = fh + 786432;
    unsigned short* hth  = fl + 786432;
    unsigned short* htl  = hth + 786432;
    unsigned short* ndh  = htl + 786432;
    unsigned short* ndl  = ndh + 786432;
    unsigned short* ph   = ndl + 786432;         // 131072 each
    unsigned short* pl   = ph + 131072;

    float* out       = (float*)d_out;
    float* graph_out = out;          // (8,768)
    float* node_out  = out + 6144;   // (8,128,768)

    prep_k<<<530, 256, 0, stream>>>(W0, W1, A1, feature, b0, b1,
                                    Wt0h, Wt0l, Wt1h, Wt1l,
                                    fh, fl, WAth, WAtl, bA);

    for (int layer = 0; layer < 2; layer++) {
        const unsigned short* Wth = layer ? Wt1h : Wt0h;
        const unsigned short* Wtl = layer ? Wt1l : Wt0l;
        const float* bb = layer ? b1 : b0;
        const unsigned short* Ahg = layer ? ndh : fh;
        const unsigned short* Alg = layer ? ndl : fl;
        gemm_fused_k<<<224, 256, 0, stream>>>(
            Ahg, Alg, Wth, Wtl, WAth + (size_t)layer * 98304,
            WAtl + (size_t)layer * 98304, bb, hth, htl, s);
        score_k<<<256, 256, 0, stream>>>(s, adj, ab1, A2, ab2,
                                         bA + layer * 128, ph, pl, psum);
        attn_mfma_k<<<192, 256, 0, stream>>>(ph, pl, hth, htl, psum,
                                             node_out, ndh, ndl);
    }
    gsum_bnorm_k<<<12, 512, 0, stream>>>(node_out, gamma, beta, graph_out);
}

// Round 5
// 149.876 us; speedup vs baseline: 3.3260x; 1.0491x over previous
//
#include <hip/hip_runtime.h>
#include <math.h>

#define NEG_V (-1e30f)
#define SLOPE_V 0.01f
#define EPS_V 1e-5f

typedef __attribute__((ext_vector_type(8))) short bs8;    // 8 bf16 (4 VGPRs)
typedef __attribute__((ext_vector_type(4))) float f32x4;  // mfma acc

// ---------------------------------------------------------------------------
// Round 5: serialization cuts on top of validated round-4 (157.2us).
// Revised model: ~70-76us of dur_us is harness poison/reset (mega rounds:
// dur_us - kernel_dur = 69/76); controllable chain ~85us is latency- and
// barrier-bound at 1 wave/SIMD (grid-limited occupancy).
// Changes (all local, validated patterns):
//  1) prep WA jobs: single-stage 2-barrier/step -> mfma_loop-style double
//     buffer, 1 barrier/step (8 LDS stages, 40KB).
//  2) attn layer-1 epilogue: register-resident column sums + atomicAdd to
//     g_ws (zeroed by score layer-1) -> kills gsum's 3MB/12-block tail;
//     gsum_bnorm becomes a 12x64 bnorm-only kernel.
//  3) attn prologue: per-wave shfl_xor psum reduction (no barriers).
// Phase math otherwise byte-identical to round 4.
// ---------------------------------------------------------------------------

// Split fp32 x into bf16 hi + bf16 lo (RNE both). x ≈ hi + lo, rel err ~2^-17.
__device__ __forceinline__ void split2(float x, unsigned short& hi, unsigned short& lo) {
    unsigned u = __float_as_uint(x);
    unsigned h = (u + 0x7FFFu + ((u >> 16) & 1u)) >> 16;
    hi = (unsigned short)h;
    float hf = __uint_as_float(h << 16);
    float l = x - hf;
    unsigned ul = __float_as_uint(l);
    lo = (unsigned short)((ul + 0x7FFFu + ((ul >> 16) & 1u)) >> 16);
}

// ---------------------------------------------------------------------------
// Software-pipelined split-bf16 MFMA mainloop, 2-deep prefetch (validated r3).
// buf[8][64][40]: stage*4 + {Ah,Al,Bh,Bl}; ONE barrier per 32-k-step.
// W_{i+2} vs R_i safety: reads of stage s complete before the next barrier
// (consuming MFMAs issue pre-barrier, compiler inserts waitcnt); the write of
// stage s at step i+2 sits after that barrier in every wave's program order.
// ---------------------------------------------------------------------------
#define MFMA_COMPUTE(B0)                                                       \
    {                                                                          \
        bs8 a_h[2], a_l[2], b_h[2], b_l[2];                                    \
        _Pragma("unroll")                                                      \
        for (int t = 0; t < 2; t++) {                                          \
            a_h[t] = *(bs8*)&buf[(B0) + 0][wm0 + t * 16 + lm][q * 8];          \
            a_l[t] = *(bs8*)&buf[(B0) + 1][wm0 + t * 16 + lm][q * 8];          \
            b_h[t] = *(bs8*)&buf[(B0) + 2][wn0 + t * 16 + lm][q * 8];          \
            b_l[t] = *(bs8*)&buf[(B0) + 3][wn0 + t * 16 + lm][q * 8];          \
        }                                                                      \
        _Pragma("unroll")                                                      \
        for (int mt = 0; mt < 2; mt++)                                         \
            _Pragma("unroll")                                                  \
            for (int nt = 0; nt < 2; nt++) {                                   \
                acc[mt][nt] = __builtin_amdgcn_mfma_f32_16x16x32_bf16(a_h[mt], b_h[nt], acc[mt][nt], 0, 0, 0); \
                acc[mt][nt] = __builtin_amdgcn_mfma_f32_16x16x32_bf16(a_h[mt], b_l[nt], acc[mt][nt], 0, 0, 0); \
                acc[mt][nt] = __builtin_amdgcn_mfma_f32_16x16x32_bf16(a_l[mt], b_h[nt], acc[mt][nt], 0, 0, 0); \
            }                                                                  \
    }

__device__ __forceinline__ void mfma_loop(
    const unsigned short* __restrict__ Ahg, const unsigned short* __restrict__ Alg,
    int lda,
    const unsigned short* __restrict__ Bhg, const unsigned short* __restrict__ Blg,
    int ldb, int K, int row0, int col0,
    f32x4 (&acc)[2][2],
    unsigned short (*buf)[64][40])   // buf[8]: stage*4 + {Ah,Al,Bh,Bl}
{
    const int tid = threadIdx.x;
    const int lane = tid & 63, wid = tid >> 6;
    const int wm0 = (wid >> 1) * 32, wn0 = (wid & 1) * 32;
    const int lm = lane & 15, q = lane >> 4;
    const int sr = tid >> 2, sc = (tid & 3) * 8;

    const unsigned short* pAh = Ahg + (size_t)(row0 + sr) * lda + sc;
    const unsigned short* pAl = Alg + (size_t)(row0 + sr) * lda + sc;
    const unsigned short* pBh = Bhg + (size_t)(col0 + sr) * ldb + sc;
    const unsigned short* pBl = Blg + (size_t)(col0 + sr) * ldb + sc;

    // 2-deep prefetch: X = k-steps 0,2,4,..  Y = k-steps 1,3,5,..
    bs8 xAh = *(const bs8*)(pAh);
    bs8 xAl = *(const bs8*)(pAl);
    bs8 xBh = *(const bs8*)(pBh);
    bs8 xBl = *(const bs8*)(pBl);
    bs8 yAh = *(const bs8*)(pAh + 32);
    bs8 yAl = *(const bs8*)(pAl + 32);
    bs8 yBh = *(const bs8*)(pBh + 32);
    bs8 yBl = *(const bs8*)(pBl + 32);

    for (int k0 = 0; k0 < K; k0 += 64) {
        // ---- even step: stage 0, X regs ----
        *(bs8*)&buf[0][sr][sc] = xAh;
        *(bs8*)&buf[1][sr][sc] = xAl;
        *(bs8*)&buf[2][sr][sc] = xBh;
        *(bs8*)&buf[3][sr][sc] = xBl;
        __syncthreads();
        if (k0 + 64 < K) {
            xAh = *(const bs8*)(pAh + k0 + 64);
            xAl = *(const bs8*)(pAl + k0 + 64);
            xBh = *(const bs8*)(pBh + k0 + 64);
            xBl = *(const bs8*)(pBl + k0 + 64);
        }
        MFMA_COMPUTE(0);
        // ---- odd step: stage 1, Y regs ----
        *(bs8*)&buf[4][sr][sc] = yAh;
        *(bs8*)&buf[5][sr][sc] = yAl;
        *(bs8*)&buf[6][sr][sc] = yBh;
        *(bs8*)&buf[7][sr][sc] = yBl;
        __syncthreads();
        if (k0 + 96 < K) {
            yAh = *(const bs8*)(pAh + k0 + 96);
            yAl = *(const bs8*)(pAl + k0 + 96);
            yBh = *(const bs8*)(pBh + k0 + 96);
            yBl = *(const bs8*)(pBl + k0 + 96);
        }
        MFMA_COMPUTE(4);
    }
}

// 64x64 fp32 tile -> transposed bf16 hi/lo (dst[n][k] = src[k][n]).
__device__ __forceinline__ void transpose_split_tile(
    const float* __restrict__ src, int src_ld,
    unsigned short* __restrict__ dh, unsigned short* __restrict__ dl, int dst_ld,
    unsigned short (*Th)[72], unsigned short (*Tl)[72])
{
    int tid = threadIdx.x;
    int r = tid >> 2;
    int cb = (tid & 3) * 16;
#pragma unroll
    for (int cc = 0; cc < 16; cc += 4) {
        float4 v = *(const float4*)(src + (size_t)r * src_ld + cb + cc);
        unsigned short hh, ll;
        split2(v.x, hh, ll); Th[cb + cc + 0][r] = hh; Tl[cb + cc + 0][r] = ll;
        split2(v.y, hh, ll); Th[cb + cc + 1][r] = hh; Tl[cb + cc + 1][r] = ll;
        split2(v.z, hh, ll); Th[cb + cc + 2][r] = hh; Tl[cb + cc + 2][r] = ll;
        split2(v.w, hh, ll); Th[cb + cc + 3][r] = hh; Tl[cb + cc + 3][r] = ll;
    }
    __syncthreads();
    int n = tid >> 2, ch = (tid & 3) * 8;
    *(bs8*)(dh + (size_t)n * dst_ld + ch)      = *(bs8*)&Th[n][ch];
    *(bs8*)(dh + (size_t)n * dst_ld + ch + 32) = *(bs8*)&Th[n][ch + 32];
    *(bs8*)(dl + (size_t)n * dst_ld + ch)      = *(bs8*)&Tl[n][ch];
    *(bs8*)(dl + (size_t)n * dst_ld + ch + 32) = *(bs8*)&Tl[n][ch + 32];
}

// flat fp32 -> split bf16 hi/lo, 4096 elems/job, 16/thread.
__device__ __forceinline__ void flat_split_job(
    const float* __restrict__ src, unsigned short* __restrict__ dh,
    unsigned short* __restrict__ dl, size_t base)
{
    unsigned short hh, ll;
#pragma unroll
    for (int g = 0; g < 2; g++) {
        bs8 sh, sl;
#pragma unroll
        for (int cc = 0; cc < 8; cc += 4) {
            float4 v = *(const float4*)(src + base + g * 8 + cc);
            split2(v.x, hh, ll); sh[cc + 0] = (short)hh; sl[cc + 0] = (short)ll;
            split2(v.y, hh, ll); sh[cc + 1] = (short)hh; sl[cc + 1] = (short)ll;
            split2(v.z, hh, ll); sh[cc + 2] = (short)hh; sl[cc + 2] = (short)ll;
            split2(v.w, hh, ll); sh[cc + 3] = (short)hh; sl[cc + 3] = (short)ll;
        }
        *(bs8*)(dh + base + g * 8) = sh;
        *(bs8*)(dl + base + g * 8) = sl;
    }
}

// WA job: split one X/Y operand set into LDS stage B0 (buf[B0+0..3]).
#define WA_STORE(B0, va0, va1, vw0, vw1) {                                   \
    unsigned short hv, lv;                                                   \
    split2((va0).x, hv, lv); buf[(B0)+0][acs + 0][akk] = hv; buf[(B0)+1][acs + 0][akk] = lv; \
    split2((va0).y, hv, lv); buf[(B0)+0][acs + 1][akk] = hv; buf[(B0)+1][acs + 1][akk] = lv; \
    split2((va0).z, hv, lv); buf[(B0)+0][acs + 2][akk] = hv; buf[(B0)+1][acs + 2][akk] = lv; \
    split2((va0).w, hv, lv); buf[(B0)+0][acs + 3][akk] = hv; buf[(B0)+1][acs + 3][akk] = lv; \
    split2((va1).x, hv, lv); buf[(B0)+0][acs + 4][akk] = hv; buf[(B0)+1][acs + 4][akk] = lv; \
    split2((va1).y, hv, lv); buf[(B0)+0][acs + 5][akk] = hv; buf[(B0)+1][acs + 5][akk] = lv; \
    split2((va1).z, hv, lv); buf[(B0)+0][acs + 6][akk] = hv; buf[(B0)+1][acs + 6][akk] = lv; \
    split2((va1).w, hv, lv); buf[(B0)+0][acs + 7][akk] = hv; buf[(B0)+1][acs + 7][akk] = lv; \
    bs8 sh, sl;                                                              \
    split2((vw0).x, hv, lv); sh[0] = (short)hv; sl[0] = (short)lv;           \
    split2((vw0).y, hv, lv); sh[1] = (short)hv; sl[1] = (short)lv;           \
    split2((vw0).z, hv, lv); sh[2] = (short)hv; sl[2] = (short)lv;           \
    split2((vw0).w, hv, lv); sh[3] = (short)hv; sl[3] = (short)lv;           \
    split2((vw1).x, hv, lv); sh[4] = (short)hv; sl[4] = (short)lv;           \
    split2((vw1).y, hv, lv); sh[5] = (short)hv; sl[5] = (short)lv;           \
    split2((vw1).z, hv, lv); sh[6] = (short)hv; sl[6] = (short)lv;           \
    split2((vw1).w, hv, lv); sh[7] = (short)hv; sl[7] = (short)lv;           \
    *(bs8*)&buf[(B0)+2][br][bks] = sh;                                       \
    *(bs8*)&buf[(B0)+3][br][bks] = sl;                                       \
}

// ---------------------------------------------------------------------------
// Prep, grid 530:
//   [0,144)   W0 -> Wt0 transposed split
//   [144,288) W1 -> Wt1 transposed split
//   [288,480) feature -> fh/fl row-major split
//   [480,528) WA via MFMA (double-buffered, 1 barrier/step; XCD job decode)
//   [528,530) bA[layer][c] = sum_k b[k] * A1x[k][c]
// ---------------------------------------------------------------------------
__global__ __launch_bounds__(256) void prep_k(
    const float* __restrict__ W0, const float* __restrict__ W1,
    const float* __restrict__ A1, const float* __restrict__ feature,
    const float* __restrict__ b0, const float* __restrict__ b1,
    unsigned short* Wt0h, unsigned short* Wt0l,
    unsigned short* Wt1h, unsigned short* Wt1l,
    unsigned short* fh, unsigned short* fl,
    unsigned short* WAth, unsigned short* WAtl,
    float* bA)
{
    __shared__ __align__(16) char smem[40960];
    int id = blockIdx.x, tid = threadIdx.x;
    if (id < 288) {
        unsigned short (*Th)[72] = (unsigned short(*)[72])(smem);
        unsigned short (*Tl)[72] = (unsigned short(*)[72])(smem + 9216);
        if (id < 144) {
            int kt = id / 12, nt = id % 12;
            transpose_split_tile(W0 + (size_t)(kt * 64) * 768 + nt * 64, 768,
                                 Wt0h + (size_t)(nt * 64) * 768 + kt * 64,
                                 Wt0l + (size_t)(nt * 64) * 768 + kt * 64, 768, Th, Tl);
        } else {
            int r = id - 144, kt = r / 12, nt = r % 12;
            transpose_split_tile(W1 + (size_t)(kt * 64) * 768 + nt * 64, 768,
                                 Wt1h + (size_t)(nt * 64) * 768 + kt * 64,
                                 Wt1l + (size_t)(nt * 64) * 768 + kt * 64, 768, Th, Tl);
        }
    } else if (id < 480) {
        flat_split_job(feature, fh, fl, (size_t)(id - 288) * 4096 + tid * 16);
    } else if (id < 528) {
        // --- WA MFMA job; XCD-friendly decode (bijective over j in [0,48)):
        //     c8 = j&7 selects (layer,ct); rt = j/8 + 6*(c8>=4).
        int j = id - 480;
        int c8 = j & 7, kq8 = j >> 3;           // kq8 0..5
        int layer = (c8 >> 1) & 1;
        int ct = c8 & 1;
        int rt = kq8 + 6 * (c8 >> 2);
        const float* W = layer ? W1 : W0;
        const int r0 = rt * 64;
        unsigned short (*buf)[64][40] = (unsigned short(*)[64][40])smem;  // 8 stages
        const int lane = tid & 63, wid = tid >> 6;
        const int wm0 = (wid >> 1) * 32, wn0 = (wid & 1) * 32;
        const int lm = lane & 15, q = lane >> 4;
        const int akk = tid & 31, acs = (tid >> 5) * 8;   // A: k-row, c-seg
        const int br = tid >> 2, bks = (tid & 3) * 8;     // B: r-row, k-seg
        const float* A1p = A1 + (size_t)(ct * 768 + akk) * 64 + acs;
        const float* Wp  = W + (size_t)(r0 + br) * 768 + bks;
        // prologue: X = steps 0,2,..  Y = steps 1,3,..  (k-step stride 32)
        float4 xa0 = *(const float4*)(A1p);
        float4 xa1 = *(const float4*)(A1p + 4);
        float4 xw0 = *(const float4*)(Wp);
        float4 xw1 = *(const float4*)(Wp + 4);
        float4 ya0 = *(const float4*)(A1p + 32 * 64);
        float4 ya1 = *(const float4*)(A1p + 32 * 64 + 4);
        float4 yw0 = *(const float4*)(Wp + 32);
        float4 yw1 = *(const float4*)(Wp + 36);
        f32x4 acc[2][2] = {};
        for (int k0 = 0; k0 < 768; k0 += 64) {
            // ---- even step: stage 0 ----
            WA_STORE(0, xa0, xa1, xw0, xw1);
            __syncthreads();
            if (k0 + 64 < 768) {
                xa0 = *(const float4*)(A1p + (size_t)(k0 + 64) * 64);
                xa1 = *(const float4*)(A1p + (size_t)(k0 + 64) * 64 + 4);
                xw0 = *(const float4*)(Wp + k0 + 64);
                xw1 = *(const float4*)(Wp + k0 + 68);
            }
            MFMA_COMPUTE(0);
            // ---- odd step: stage 1 ----
            WA_STORE(4, ya0, ya1, yw0, yw1);
            __syncthreads();
            if (k0 + 96 < 768) {
                ya0 = *(const float4*)(A1p + (size_t)(k0 + 96) * 64);
                ya1 = *(const float4*)(A1p + (size_t)(k0 + 96) * 64 + 4);
                yw0 = *(const float4*)(Wp + k0 + 96);
                yw1 = *(const float4*)(Wp + k0 + 100);
            }
            MFMA_COMPUTE(4);
        }
        // epilogue: D[m=c_local][n=r_local] -> WAt[layer][c0+m][r0+n]
        const int c0 = ct * 64;
        size_t base = (size_t)layer * 98304;
#pragma unroll
        for (int mt = 0; mt < 2; mt++)
#pragma unroll
            for (int nt = 0; nt < 2; nt++) {
                int n = r0 + wn0 + nt * 16 + lm;
#pragma unroll
                for (int i = 0; i < 4; i++) {
                    int m = c0 + wm0 + mt * 16 + q * 4 + i;
                    unsigned short hv, lv;
                    split2(acc[mt][nt][i], hv, lv);
                    WAth[base + (size_t)m * 768 + n] = hv;
                    WAtl[base + (size_t)m * 768 + n] = lv;
                }
            }
    } else {
        float* redb = (float*)(smem);    // 256 f
        int layer = id - 528;
        const float* bv = layer ? b1 : b0;
        int c = tid & 127, half = tid >> 7;
        float acc = 0.f;
        for (int kk = 0; kk < 384; kk++) {
            int k = half * 384 + kk;
            int row = (c < 64 ? k : 768 + k);
            acc += bv[k] * A1[(size_t)row * 64 + (c & 63)];
        }
        redb[tid] = acc;
        __syncthreads();
        if (tid < 128) bA[layer * 128 + tid] = redb[tid] + redb[tid + 128];
    }
}

// ---------------------------------------------------------------------------
// Fused gemm, 1-D grid 224 with XCD swizzle (validated r4 decode).
// col-tiles 0-11: h = A@W + bias -> transposed split hth/htl (attn B).
// col-tiles 12-13: s = A@WA -> fp32 (bias added in score).
// ---------------------------------------------------------------------------
__global__ __launch_bounds__(256) void gemm_fused_k(
    const unsigned short* __restrict__ Ahg, const unsigned short* __restrict__ Alg,
    const unsigned short* __restrict__ Wth, const unsigned short* __restrict__ Wtl,
    const unsigned short* __restrict__ WAth, const unsigned short* __restrict__ WAtl,
    const float* __restrict__ bias,
    unsigned short* __restrict__ hth, unsigned short* __restrict__ htl,
    float* __restrict__ s)
{
    __shared__ unsigned short smem[8][64][40];   // 40 KB: 2-stage x 4 bufs
    int id = blockIdx.x;
    int g = id >> 3, r8 = id & 7;
    int hi2 = (g >= 14) ? 1 : 0;
    int by = r8 + 8 * hi2;
    int bx = g - 14 * hi2;
    int row0 = by * 64;
    const unsigned short* Bh;
    const unsigned short* Bl;
    int col0;
    if (bx < 12) { Bh = Wth;  Bl = Wtl;  col0 = bx * 64; }
    else         { Bh = WAth; Bl = WAtl; col0 = (bx - 12) * 64; }
    f32x4 acc[2][2] = {};
    mfma_loop(Ahg, Alg, 768, Bh, Bl, 768, 768, row0, col0, acc, smem);
    int tid = threadIdx.x, lane = tid & 63, wid = tid >> 6;
    int wm0 = (wid >> 1) * 32, wn0 = (wid & 1) * 32;
    int lm = lane & 15, q = lane >> 4;
    if (bx >= 12) {
#pragma unroll
        for (int mt = 0; mt < 2; mt++)
#pragma unroll
            for (int nt = 0; nt < 2; nt++) {
                int c = col0 + wn0 + nt * 16 + lm;
#pragma unroll
                for (int i = 0; i < 4; i++) {
                    int r = row0 + wm0 + mt * 16 + q * 4 + i;
                    s[(size_t)r * 128 + c] = acc[mt][nt][i];
                }
            }
        return;
    }
    __syncthreads();   // drain last-stage LDS reads before epilogue reuse
    unsigned short* flat = &smem[0][0][0];
    unsigned short (*Hi)[69] = (unsigned short(*)[69])flat;
    unsigned short (*Lo)[69] = (unsigned short(*)[69])(flat + 4416);
#pragma unroll
    for (int mt = 0; mt < 2; mt++)
#pragma unroll
        for (int nt = 0; nt < 2; nt++) {
            int c = wn0 + nt * 16 + lm;
            float bv = bias[col0 + c];
#pragma unroll
            for (int i = 0; i < 4; i++) {
                int r = wm0 + mt * 16 + q * 4 + i;
                unsigned short hv, lv;
                split2(acc[mt][nt][i] + bv, hv, lv);
                Hi[r][c] = hv; Lo[r][c] = lv;
            }
        }
    __syncthreads();
    int d = tid >> 2, kq = (tid & 3) * 16;
    int b = row0 >> 7, kb = row0 & 127;
    bs8 th0, th1, tl0, tl1;
#pragma unroll
    for (int e = 0; e < 8; e++) {
        th0[e] = Hi[kq + e][d];     th1[e] = Hi[kq + 8 + e][d];
        tl0[e] = Lo[kq + e][d];     tl1[e] = Lo[kq + 8 + e][d];
    }
    size_t to = ((size_t)b * 768 + col0 + d) * 128 + kb + kq;
    *(bs8*)(hth + to) = th0; *(bs8*)(hth + to + 8) = th1;
    *(bs8*)(htl + to) = tl0; *(bs8*)(htl + to + 8) = tl1;
}

// ---------------------------------------------------------------------------
// score_k: masked score + exp. 1-D grid 256: b = id&7 (batch pinned to XCD),
// bx = id>>3. Also zeroes g_ws (blocks 0..23) for the attn layer-1 atomics.
// ---------------------------------------------------------------------------
__global__ __launch_bounds__(256) void score_k(
    const float* __restrict__ s, const int* __restrict__ adj,
    const float* __restrict__ ab1, const float* __restrict__ A2,
    const float* __restrict__ ab2, const float* __restrict__ bA,
    unsigned short* __restrict__ ph, unsigned short* __restrict__ pl,
    float* __restrict__ psum, float* __restrict__ g_ws)
{
    __shared__ float st[128][65];
    __shared__ float ss[4][65];
    __shared__ float a2s[64];
    __shared__ float warr[4];
    const int id = blockIdx.x, tid = threadIdx.x;
    const int b = id & 7, bx = id >> 3;
    const int i0 = bx * 4;
    if (id < 24) g_ws[id * 256 + tid] = 0.f;   // 24*256 = 6144 floats
#pragma unroll
    for (int g = 0; g < 8; g++) {     // float4-vectorized st load
        int idx4 = tid + g * 256;
        int j = idx4 >> 4;
        int h2 = (idx4 & 15) * 4;
        float4 v = *(const float4*)&s[(size_t)(b * 128 + j) * 128 + 64 + h2];
        float4 bv = *(const float4*)&bA[64 + h2];
        st[j][h2 + 0] = v.x + bv.x;
        st[j][h2 + 1] = v.y + bv.y;
        st[j][h2 + 2] = v.z + bv.z;
        st[j][h2 + 3] = v.w + bv.w;
    }
    {
        int i = tid >> 6, h2 = tid & 63;
        ss[i][h2] = s[(size_t)(b * 128 + i0 + i) * 128 + h2] + bA[h2] + ab1[h2];
    }
    if (tid < 64) a2s[tid] = A2[tid];
    __syncthreads();
    const float ab2v = ab2[0];
    const int rr = tid >> 7;
    const int j = tid & 127;
    const int r0 = rr * 2, r1 = rr * 2 + 1;
    float acc0 = 0.f, acc1 = 0.f;
#pragma unroll 4
    for (int h2 = 0; h2 < 64; h2++) {
        float bb = st[j][h2];
        float cv = a2s[h2];
        acc0 = fmaf(fmaxf(ss[r0][h2] + bb, 0.f), cv, acc0);
        acc1 = fmaf(fmaxf(ss[r1][h2] + bb, 0.f), cv, acc1);
    }
    float e0 = acc0 + ab2v; e0 = (e0 > 0.f) ? e0 : SLOPE_V * e0;
    float e1 = acc1 + ab2v; e1 = (e1 > 0.f) ? e1 : SLOPE_V * e1;
    size_t o0 = (size_t)b * 16384 + (size_t)(i0 + r0) * 128 + j;
    size_t o1 = (size_t)b * 16384 + (size_t)(i0 + r1) * 128 + j;
    float v0 = adj[o0] ? expf(e0) : 0.f;
    float v1 = adj[o1] ? expf(e1) : 0.f;
    unsigned short hv, lv;
    split2(v0, hv, lv); ph[o0] = hv; pl[o0] = lv;
    split2(v1, hv, lv); ph[o1] = hv; pl[o1] = lv;
    float vs = v0 + v1;
#pragma unroll
    for (int o = 32; o > 0; o >>= 1) vs += __shfl_down(vs, o);
    if ((tid & 63) == 0) warr[tid >> 6] = vs;
    __syncthreads();
    if (tid == 0) psum[b * 32 + bx] = warr[0] + warr[1] + warr[2] + warr[3];
}

// ---------------------------------------------------------------------------
// attn: node[b] = (1/sum_b) * P[b] @ h[b]. 1-D grid 192: b = id&7 (XCD pin),
// t = id>>3: cx = t%12, ry = t/12. alpha via per-wave shfl_xor (no barriers).
// If g_ws != nullptr (layer 1): register-resident column sums atomically
// accumulated into g_ws[b*768+d] (the graph-sum, consumed by bnorm_k).
// ---------------------------------------------------------------------------
__global__ __launch_bounds__(256) void attn_mfma_k(
    const unsigned short* __restrict__ ph, const unsigned short* __restrict__ pl,
    const unsigned short* __restrict__ hth, const unsigned short* __restrict__ htl,
    const float* __restrict__ psum, float* __restrict__ node,
    unsigned short* __restrict__ nodeh, unsigned short* __restrict__ nodel,
    float* __restrict__ g_ws)
{
    __shared__ unsigned short smem[8][64][40];   // 40 KB
    int id = blockIdx.x;
    int b = id & 7, t = id >> 3;
    int cx = t % 12, ry = t / 12;
    int row0 = ry * 64, col0 = cx * 64;
    int tid = threadIdx.x;
    // alpha: per-wave butterfly over psum[b][0..31] (both 32-halves identical)
    float pv = psum[b * 32 + (tid & 31)];
#pragma unroll
    for (int o = 1; o < 32; o <<= 1) pv += __shfl_xor(pv, o);
    float alpha = 1.0f / pv;
    f32x4 acc[2][2] = {};
    mfma_loop(ph + (size_t)b * 16384, pl + (size_t)b * 16384, 128,
              hth + (size_t)b * 98304, htl + (size_t)b * 98304, 128, 128,
              row0, col0, acc, smem);
    __syncthreads();   // drain last-stage LDS reads before epilogue reuse
    float* C = node + (size_t)b * 98304;
    unsigned short* flat = &smem[0][0][0];
    unsigned short (*Hi)[69] = (unsigned short(*)[69])flat;
    unsigned short (*Lo)[69] = (unsigned short(*)[69])(flat + 4416);
    int lane = tid & 63, wid = tid >> 6;
    int wm0 = (wid >> 1) * 32, wn0 = (wid & 1) * 32;
    int lm = lane & 15, q = lane >> 4;
    float csum[2] = {0.f, 0.f};
#pragma unroll
    for (int mt = 0; mt < 2; mt++)
#pragma unroll
        for (int nt = 0; nt < 2; nt++) {
            int c = wn0 + nt * 16 + lm;
#pragma unroll
            for (int i = 0; i < 4; i++) {
                int r = wm0 + mt * 16 + q * 4 + i;
                float v = acc[mt][nt][i] * alpha;
                C[(size_t)(row0 + r) * 768 + col0 + c] = v;
                csum[nt] += v;
                unsigned short hv, lv;
                split2(v, hv, lv);
                Hi[r][c] = hv; Lo[r][c] = lv;
            }
        }
    if (g_ws) {   // layer 1: fold graph-sum here (16 adds/address total)
#pragma unroll
        for (int nt = 0; nt < 2; nt++)
            atomicAdd(&g_ws[b * 768 + col0 + wn0 + nt * 16 + lm], csum[nt]);
    }
    __syncthreads();
    int r = tid >> 2, cq = (tid & 3) * 16;
    bs8 vh0, vh1, vl0, vl1;
#pragma unroll
    for (int e = 0; e < 8; e++) {
        vh0[e] = Hi[r][cq + e];     vh1[e] = Hi[r][cq + 8 + e];
        vl0[e] = Lo[r][cq + e];     vl1[e] = Lo[r][cq + 8 + e];
    }
    size_t ro = (size_t)(b * 128 + row0 + r) * 768 + col0 + cq;
    *(bs8*)(nodeh + ro) = vh0; *(bs8*)(nodeh + ro + 8) = vh1;
    *(bs8*)(nodel + ro) = vl0; *(bs8*)(nodel + ro + 8) = vl1;
}

// ---------------------------------------------------------------------------
// bnorm only (graph-sum now accumulated by attn layer-1 atomics).
// grid 12, block 64: d = bid*64 + tid.
// ---------------------------------------------------------------------------
__global__ __launch_bounds__(64) void bnorm_k(
    const float* __restrict__ g_ws, const float* __restrict__ gamma,
    const float* __restrict__ beta, float* __restrict__ out)
{
    int d = blockIdx.x * 64 + threadIdx.x;
    float vals[8]; float m = 0.f;
#pragma unroll
    for (int b = 0; b < 8; b++) { vals[b] = g_ws[b * 768 + d]; m += vals[b]; }
    m *= 0.125f;
    float var = 0.f;
#pragma unroll
    for (int b = 0; b < 8; b++) { float t = vals[b] - m; var += t * t; }
    var *= 0.125f;
    float inv = 1.0f / sqrtf(var + EPS_V);
    float gm = gamma[d], bt = beta[d];
#pragma unroll
    for (int b = 0; b < 8; b++)
        out[b * 768 + d] = gm * (vals[b] - m) * inv + bt;
}

// ---------------------------------------------------------------------------
extern "C" void kernel_launch(void* const* d_in, const int* in_sizes, int n_in,
                              void* d_out, int out_size, void* d_ws, size_t ws_size,
                              hipStream_t stream)
{
    const float* feature = (const float*)d_in[0];
    // d_in[1] = aspect: unused by the reference
    const int*   adj     = (const int*)d_in[2];
    const float* W0      = (const float*)d_in[3];
    const float* b0      = (const float*)d_in[4];
    const float* W1      = (const float*)d_in[5];
    const float* b1      = (const float*)d_in[6];
    const float* A1      = (const float*)d_in[7];
    const float* ab1     = (const float*)d_in[8];
    const float* A2      = (const float*)d_in[9];
    const float* ab2     = (const float*)d_in[10];
    const float* gamma   = (const float*)d_in[11];
    const float* beta    = (const float*)d_in[12];

    float* ws    = (float*)d_ws;
    float* s     = ws;               // 131072
    float* psum  = ws + 131072;      // 256
    float* bA    = ws + 131328;      // 256
    float* g_ws  = ws + 131584;      // 6144
    unsigned short* u = (unsigned short*)(ws + 137728);  // 16B-aligned
    unsigned short* Wt0h = u;                    // 589824 each
    unsigned short* Wt0l = Wt0h + 589824;
    unsigned short* Wt1h = Wt0l + 589824;
    unsigned short* Wt1l = Wt1h + 589824;
    unsigned short* WAth = Wt1l + 589824;        // 196608 each (2 layers)
    unsigned short* WAtl = WAth + 196608;
    unsigned short* fh   = WAtl + 196608;        // 786432 each from here
    unsigned short* fl   = fh + 786432;
    unsigned short* hth  = fl + 786432;
    unsigned short* htl  = hth + 786432;
    unsigned short* ndh  = htl + 786432;
    unsigned short* ndl  = ndh + 786432;
    unsigned short* ph   = ndl + 786432;         // 131072 each
    unsigned short* pl   = ph + 131072;

    float* out       = (float*)d_out;
    float* graph_out = out;          // (8,768)
    float* node_out  = out + 6144;   // (8,128,768)

    prep_k<<<530, 256, 0, stream>>>(W0, W1, A1, feature, b0, b1,
                                    Wt0h, Wt0l, Wt1h, Wt1l,
                                    fh, fl, WAth, WAtl, bA);

    for (int layer = 0; layer < 2; layer++) {
        const unsigned short* Wth = layer ? Wt1h : Wt0h;
        const unsigned short* Wtl = layer ? Wt1l : Wt0l;
        const float* bb = layer ? b1 : b0;
        const unsigned short* Ahg = layer ? ndh : fh;
        const unsigned short* Alg = layer ? ndl : fl;
        gemm_fused_k<<<224, 256, 0, stream>>>(
            Ahg, Alg, Wth, Wtl, WAth + (size_t)layer * 98304,
            WAtl + (size_t)layer * 98304, bb, hth, htl, s);
        score_k<<<256, 256, 0, stream>>>(s, adj, ab1, A2, ab2,
                                         bA + layer * 128, ph, pl, psum, g_ws);
        attn_mfma_k<<<192, 256, 0, stream>>>(ph, pl, hth, htl, psum,
                                             node_out, ndh, ndl,
                                             layer ? g_ws : (float*)nullptr);
    }
    bnorm_k<<<12, 64, 0, stream>>>(g_ws, gamma, beta, graph_out);
}

// Round 7
// 149.214 us; speedup vs baseline: 3.3407x; 1.0044x over previous
//
#include <hip/hip_runtime.h>
#include <math.h>

#define NEG_V (-1e30f)
#define SLOPE_V 0.01f
#define EPS_V 1e-5f

typedef __attribute__((ext_vector_type(8))) short bs8;    // 8 bf16 (4 VGPRs)
typedef __attribute__((ext_vector_type(4))) float f32x4;  // mfma acc

// ---------------------------------------------------------------------------
// Round 7: bisect round-6's container failure. Round 6 = round 5 + {BK=64
// mainloop, bnorm folded into attn via cross-kernel device counter, dead
// node-store elim}. The cross-kernel last-block-done protocol is the only
// hang-capable change (multi-XCD coherence + graph replay) -> REVERTED here:
// standalone bnorm_k restored (validated r5). BK=64 loop and dead-store elim
// KEPT (straight-line, bounds-verified, no cross-block state).
// If this fails too, next round reverts to exact round-5 source.
// ---------------------------------------------------------------------------

// Split fp32 x into bf16 hi + bf16 lo (RNE both). x ≈ hi + lo, rel err ~2^-17.
__device__ __forceinline__ void split2(float x, unsigned short& hi, unsigned short& lo) {
    unsigned u = __float_as_uint(x);
    unsigned h = (u + 0x7FFFu + ((u >> 16) & 1u)) >> 16;
    hi = (unsigned short)h;
    float hf = __uint_as_float(h << 16);
    float l = x - hf;
    unsigned ul = __float_as_uint(l);
    lo = (unsigned short)((ul + 0x7FFFu + ((ul >> 16) & 1u)) >> 16);
}

// ---- BK=32 compute (prep WA job, buf rows of 40 shorts) --------------------
#define MFMA_COMPUTE(B0)                                                       \
    {                                                                          \
        bs8 a_h[2], a_l[2], b_h[2], b_l[2];                                    \
        _Pragma("unroll")                                                      \
        for (int t = 0; t < 2; t++) {                                          \
            a_h[t] = *(bs8*)&buf[(B0) + 0][wm0 + t * 16 + lm][q * 8];          \
            a_l[t] = *(bs8*)&buf[(B0) + 1][wm0 + t * 16 + lm][q * 8];          \
            b_h[t] = *(bs8*)&buf[(B0) + 2][wn0 + t * 16 + lm][q * 8];          \
            b_l[t] = *(bs8*)&buf[(B0) + 3][wn0 + t * 16 + lm][q * 8];          \
        }                                                                      \
        _Pragma("unroll")                                                      \
        for (int mt = 0; mt < 2; mt++)                                         \
            _Pragma("unroll")                                                  \
            for (int nt = 0; nt < 2; nt++) {                                   \
                acc[mt][nt] = __builtin_amdgcn_mfma_f32_16x16x32_bf16(a_h[mt], b_h[nt], acc[mt][nt], 0, 0, 0); \
                acc[mt][nt] = __builtin_amdgcn_mfma_f32_16x16x32_bf16(a_h[mt], b_l[nt], acc[mt][nt], 0, 0, 0); \
                acc[mt][nt] = __builtin_amdgcn_mfma_f32_16x16x32_bf16(a_l[mt], b_h[nt], acc[mt][nt], 0, 0, 0); \
            }                                                                  \
    }

// ---- BK=64 compute (gemm/attn, buf rows of 72 shorts) ----------------------
#define MFMA_COMPUTE64(B0)                                                     \
    _Pragma("unroll")                                                          \
    for (int ks = 0; ks < 64; ks += 32) {                                      \
        bs8 a_h[2], a_l[2], b_h[2], b_l[2];                                    \
        _Pragma("unroll")                                                      \
        for (int t = 0; t < 2; t++) {                                          \
            a_h[t] = *(bs8*)&buf[(B0) + 0][wm0 + t * 16 + lm][ks + q * 8];     \
            a_l[t] = *(bs8*)&buf[(B0) + 1][wm0 + t * 16 + lm][ks + q * 8];     \
            b_h[t] = *(bs8*)&buf[(B0) + 2][wn0 + t * 16 + lm][ks + q * 8];     \
            b_l[t] = *(bs8*)&buf[(B0) + 3][wn0 + t * 16 + lm][ks + q * 8];     \
        }                                                                      \
        _Pragma("unroll")                                                      \
        for (int mt = 0; mt < 2; mt++)                                         \
            _Pragma("unroll")                                                  \
            for (int nt = 0; nt < 2; nt++) {                                   \
                acc[mt][nt] = __builtin_amdgcn_mfma_f32_16x16x32_bf16(a_h[mt], b_h[nt], acc[mt][nt], 0, 0, 0); \
                acc[mt][nt] = __builtin_amdgcn_mfma_f32_16x16x32_bf16(a_h[mt], b_l[nt], acc[mt][nt], 0, 0, 0); \
                acc[mt][nt] = __builtin_amdgcn_mfma_f32_16x16x32_bf16(a_l[mt], b_h[nt], acc[mt][nt], 0, 0, 0); \
            }                                                                  \
    }

// ---------------------------------------------------------------------------
// BK=64 software-pipelined split-bf16 MFMA mainloop. X stage = k [k0,k0+64),
// Y stage = [k0+64,k0+128); ONE barrier per stage. W_{next} vs R_cur safety:
// reads of a stage retire before the barrier that follows them (consuming
// MFMAs issue pre-barrier; syncthreads drains lgkm), and the overwrite of
// that stage sits after that barrier in program order. Requires K%128==0
// (gemm 768, attn 128). Caller syncthreads before LDS reuse.
// ---------------------------------------------------------------------------
__device__ __forceinline__ void mfma_loop(
    const unsigned short* __restrict__ Ahg, const unsigned short* __restrict__ Alg,
    int lda,
    const unsigned short* __restrict__ Bhg, const unsigned short* __restrict__ Blg,
    int ldb, int K, int row0, int col0,
    f32x4 (&acc)[2][2],
    unsigned short (*buf)[64][72])   // buf[8]: stage*4 + {Ah,Al,Bh,Bl}
{
    const int tid = threadIdx.x;
    const int lane = tid & 63, wid = tid >> 6;
    const int wm0 = (wid >> 1) * 32, wn0 = (wid & 1) * 32;
    const int lm = lane & 15, q = lane >> 4;
    const int sr = tid >> 2, sc = (tid & 3) * 8;

    const unsigned short* pAh = Ahg + (size_t)(row0 + sr) * lda + sc;
    const unsigned short* pAl = Alg + (size_t)(row0 + sr) * lda + sc;
    const unsigned short* pBh = Bhg + (size_t)(col0 + sr) * ldb + sc;
    const unsigned short* pBl = Blg + (size_t)(col0 + sr) * ldb + sc;

    // X = k [0,64): cols sc, sc+32.  Y = k [64,128).
    bs8 xAh0 = *(const bs8*)(pAh);      bs8 xAh1 = *(const bs8*)(pAh + 32);
    bs8 xAl0 = *(const bs8*)(pAl);      bs8 xAl1 = *(const bs8*)(pAl + 32);
    bs8 xBh0 = *(const bs8*)(pBh);      bs8 xBh1 = *(const bs8*)(pBh + 32);
    bs8 xBl0 = *(const bs8*)(pBl);      bs8 xBl1 = *(const bs8*)(pBl + 32);
    bs8 yAh0 = *(const bs8*)(pAh + 64); bs8 yAh1 = *(const bs8*)(pAh + 96);
    bs8 yAl0 = *(const bs8*)(pAl + 64); bs8 yAl1 = *(const bs8*)(pAl + 96);
    bs8 yBh0 = *(const bs8*)(pBh + 64); bs8 yBh1 = *(const bs8*)(pBh + 96);
    bs8 yBl0 = *(const bs8*)(pBl + 64); bs8 yBl1 = *(const bs8*)(pBl + 96);

    for (int k0 = 0; k0 < K; k0 += 128) {
        // ---- stage 0 <- X ----
        *(bs8*)&buf[0][sr][sc]      = xAh0;  *(bs8*)&buf[0][sr][sc + 32] = xAh1;
        *(bs8*)&buf[1][sr][sc]      = xAl0;  *(bs8*)&buf[1][sr][sc + 32] = xAl1;
        *(bs8*)&buf[2][sr][sc]      = xBh0;  *(bs8*)&buf[2][sr][sc + 32] = xBh1;
        *(bs8*)&buf[3][sr][sc]      = xBl0;  *(bs8*)&buf[3][sr][sc + 32] = xBl1;
        __syncthreads();
        if (k0 + 128 < K) {
            xAh0 = *(const bs8*)(pAh + k0 + 128); xAh1 = *(const bs8*)(pAh + k0 + 160);
            xAl0 = *(const bs8*)(pAl + k0 + 128); xAl1 = *(const bs8*)(pAl + k0 + 160);
            xBh0 = *(const bs8*)(pBh + k0 + 128); xBh1 = *(const bs8*)(pBh + k0 + 160);
            xBl0 = *(const bs8*)(pBl + k0 + 128); xBl1 = *(const bs8*)(pBl + k0 + 160);
        }
        MFMA_COMPUTE64(0);
        // ---- stage 1 <- Y ----
        *(bs8*)&buf[4][sr][sc]      = yAh0;  *(bs8*)&buf[4][sr][sc + 32] = yAh1;
        *(bs8*)&buf[5][sr][sc]      = yAl0;  *(bs8*)&buf[5][sr][sc + 32] = yAl1;
        *(bs8*)&buf[6][sr][sc]      = yBh0;  *(bs8*)&buf[6][sr][sc + 32] = yBh1;
        *(bs8*)&buf[7][sr][sc]      = yBl0;  *(bs8*)&buf[7][sr][sc + 32] = yBl1;
        __syncthreads();
        if (k0 + 192 < K) {
            yAh0 = *(const bs8*)(pAh + k0 + 192); yAh1 = *(const bs8*)(pAh + k0 + 224);
            yAl0 = *(const bs8*)(pAl + k0 + 192); yAl1 = *(const bs8*)(pAl + k0 + 224);
            yBh0 = *(const bs8*)(pBh + k0 + 192); yBh1 = *(const bs8*)(pBh + k0 + 224);
            yBl0 = *(const bs8*)(pBl + k0 + 192); yBl1 = *(const bs8*)(pBl + k0 + 224);
        }
        MFMA_COMPUTE64(4);
    }
}

// 64x64 fp32 tile -> transposed bf16 hi/lo (dst[n][k] = src[k][n]).
__device__ __forceinline__ void transpose_split_tile(
    const float* __restrict__ src, int src_ld,
    unsigned short* __restrict__ dh, unsigned short* __restrict__ dl, int dst_ld,
    unsigned short (*Th)[72], unsigned short (*Tl)[72])
{
    int tid = threadIdx.x;
    int r = tid >> 2;
    int cb = (tid & 3) * 16;
#pragma unroll
    for (int cc = 0; cc < 16; cc += 4) {
        float4 v = *(const float4*)(src + (size_t)r * src_ld + cb + cc);
        unsigned short hh, ll;
        split2(v.x, hh, ll); Th[cb + cc + 0][r] = hh; Tl[cb + cc + 0][r] = ll;
        split2(v.y, hh, ll); Th[cb + cc + 1][r] = hh; Tl[cb + cc + 1][r] = ll;
        split2(v.z, hh, ll); Th[cb + cc + 2][r] = hh; Tl[cb + cc + 2][r] = ll;
        split2(v.w, hh, ll); Th[cb + cc + 3][r] = hh; Tl[cb + cc + 3][r] = ll;
    }
    __syncthreads();
    int n = tid >> 2, ch = (tid & 3) * 8;
    *(bs8*)(dh + (size_t)n * dst_ld + ch)      = *(bs8*)&Th[n][ch];
    *(bs8*)(dh + (size_t)n * dst_ld + ch + 32) = *(bs8*)&Th[n][ch + 32];
    *(bs8*)(dl + (size_t)n * dst_ld + ch)      = *(bs8*)&Tl[n][ch];
    *(bs8*)(dl + (size_t)n * dst_ld + ch + 32) = *(bs8*)&Tl[n][ch + 32];
}

// flat fp32 -> split bf16 hi/lo, 4096 elems/job, 16/thread.
__device__ __forceinline__ void flat_split_job(
    const float* __restrict__ src, unsigned short* __restrict__ dh,
    unsigned short* __restrict__ dl, size_t base)
{
    unsigned short hh, ll;
#pragma unroll
    for (int g = 0; g < 2; g++) {
        bs8 sh, sl;
#pragma unroll
        for (int cc = 0; cc < 8; cc += 4) {
            float4 v = *(const float4*)(src + base + g * 8 + cc);
            split2(v.x, hh, ll); sh[cc + 0] = (short)hh; sl[cc + 0] = (short)ll;
            split2(v.y, hh, ll); sh[cc + 1] = (short)hh; sl[cc + 1] = (short)ll;
            split2(v.z, hh, ll); sh[cc + 2] = (short)hh; sl[cc + 2] = (short)ll;
            split2(v.w, hh, ll); sh[cc + 3] = (short)hh; sl[cc + 3] = (short)ll;
        }
        *(bs8*)(dh + base + g * 8) = sh;
        *(bs8*)(dl + base + g * 8) = sl;
    }
}

// WA job: split one X/Y operand set into LDS stage B0 (buf[B0+0..3]).
#define WA_STORE(B0, va0, va1, vw0, vw1) {                                   \
    unsigned short hv, lv;                                                   \
    split2((va0).x, hv, lv); buf[(B0)+0][acs + 0][akk] = hv; buf[(B0)+1][acs + 0][akk] = lv; \
    split2((va0).y, hv, lv); buf[(B0)+0][acs + 1][akk] = hv; buf[(B0)+1][acs + 1][akk] = lv; \
    split2((va0).z, hv, lv); buf[(B0)+0][acs + 2][akk] = hv; buf[(B0)+1][acs + 2][akk] = lv; \
    split2((va0).w, hv, lv); buf[(B0)+0][acs + 3][akk] = hv; buf[(B0)+1][acs + 3][akk] = lv; \
    split2((va1).x, hv, lv); buf[(B0)+0][acs + 4][akk] = hv; buf[(B0)+1][acs + 4][akk] = lv; \
    split2((va1).y, hv, lv); buf[(B0)+0][acs + 5][akk] = hv; buf[(B0)+1][acs + 5][akk] = lv; \
    split2((va1).z, hv, lv); buf[(B0)+0][acs + 6][akk] = hv; buf[(B0)+1][acs + 6][akk] = lv; \
    split2((va1).w, hv, lv); buf[(B0)+0][acs + 7][akk] = hv; buf[(B0)+1][acs + 7][akk] = lv; \
    bs8 sh, sl;                                                              \
    split2((vw0).x, hv, lv); sh[0] = (short)hv; sl[0] = (short)lv;           \
    split2((vw0).y, hv, lv); sh[1] = (short)hv; sl[1] = (short)lv;           \
    split2((vw0).z, hv, lv); sh[2] = (short)hv; sl[2] = (short)lv;           \
    split2((vw0).w, hv, lv); sh[3] = (short)hv; sl[3] = (short)lv;           \
    split2((vw1).x, hv, lv); sh[4] = (short)hv; sl[4] = (short)lv;           \
    split2((vw1).y, hv, lv); sh[5] = (short)hv; sl[5] = (short)lv;           \
    split2((vw1).z, hv, lv); sh[6] = (short)hv; sl[6] = (short)lv;           \
    split2((vw1).w, hv, lv); sh[7] = (short)hv; sl[7] = (short)lv;           \
    *(bs8*)&buf[(B0)+2][br][bks] = sh;                                       \
    *(bs8*)&buf[(B0)+3][br][bks] = sl;                                       \
}

// ---------------------------------------------------------------------------
// Prep, grid 530 (unchanged from round 5).
// ---------------------------------------------------------------------------
__global__ __launch_bounds__(256) void prep_k(
    const float* __restrict__ W0, const float* __restrict__ W1,
    const float* __restrict__ A1, const float* __restrict__ feature,
    const float* __restrict__ b0, const float* __restrict__ b1,
    unsigned short* Wt0h, unsigned short* Wt0l,
    unsigned short* Wt1h, unsigned short* Wt1l,
    unsigned short* fh, unsigned short* fl,
    unsigned short* WAth, unsigned short* WAtl,
    float* bA)
{
    __shared__ __align__(16) char smem[40960];
    int id = blockIdx.x, tid = threadIdx.x;
    if (id < 288) {
        unsigned short (*Th)[72] = (unsigned short(*)[72])(smem);
        unsigned short (*Tl)[72] = (unsigned short(*)[72])(smem + 9216);
        if (id < 144) {
            int kt = id / 12, nt = id % 12;
            transpose_split_tile(W0 + (size_t)(kt * 64) * 768 + nt * 64, 768,
                                 Wt0h + (size_t)(nt * 64) * 768 + kt * 64,
                                 Wt0l + (size_t)(nt * 64) * 768 + kt * 64, 768, Th, Tl);
        } else {
            int r = id - 144, kt = r / 12, nt = r % 12;
            transpose_split_tile(W1 + (size_t)(kt * 64) * 768 + nt * 64, 768,
                                 Wt1h + (size_t)(nt * 64) * 768 + kt * 64,
                                 Wt1l + (size_t)(nt * 64) * 768 + kt * 64, 768, Th, Tl);
        }
    } else if (id < 480) {
        flat_split_job(feature, fh, fl, (size_t)(id - 288) * 4096 + tid * 16);
    } else if (id < 528) {
        // WA MFMA job; XCD-friendly decode (bijective over j in [0,48)).
        int j = id - 480;
        int c8 = j & 7, kq8 = j >> 3;           // kq8 0..5
        int layer = (c8 >> 1) & 1;
        int ct = c8 & 1;
        int rt = kq8 + 6 * (c8 >> 2);
        const float* W = layer ? W1 : W0;
        const int r0 = rt * 64;
        unsigned short (*buf)[64][40] = (unsigned short(*)[64][40])smem;  // 8 stages
        const int lane = tid & 63, wid = tid >> 6;
        const int wm0 = (wid >> 1) * 32, wn0 = (wid & 1) * 32;
        const int lm = lane & 15, q = lane >> 4;
        const int akk = tid & 31, acs = (tid >> 5) * 8;   // A: k-row, c-seg
        const int br = tid >> 2, bks = (tid & 3) * 8;     // B: r-row, k-seg
        const float* A1p = A1 + (size_t)(ct * 768 + akk) * 64 + acs;
        const float* Wp  = W + (size_t)(r0 + br) * 768 + bks;
        float4 xa0 = *(const float4*)(A1p);
        float4 xa1 = *(const float4*)(A1p + 4);
        float4 xw0 = *(const float4*)(Wp);
        float4 xw1 = *(const float4*)(Wp + 4);
        float4 ya0 = *(const float4*)(A1p + 32 * 64);
        float4 ya1 = *(const float4*)(A1p + 32 * 64 + 4);
        float4 yw0 = *(const float4*)(Wp + 32);
        float4 yw1 = *(const float4*)(Wp + 36);
        f32x4 acc[2][2] = {};
        for (int k0 = 0; k0 < 768; k0 += 64) {
            WA_STORE(0, xa0, xa1, xw0, xw1);
            __syncthreads();
            if (k0 + 64 < 768) {
                xa0 = *(const float4*)(A1p + (size_t)(k0 + 64) * 64);
                xa1 = *(const float4*)(A1p + (size_t)(k0 + 64) * 64 + 4);
                xw0 = *(const float4*)(Wp + k0 + 64);
                xw1 = *(const float4*)(Wp + k0 + 68);
            }
            MFMA_COMPUTE(0);
            WA_STORE(4, ya0, ya1, yw0, yw1);
            __syncthreads();
            if (k0 + 96 < 768) {
                ya0 = *(const float4*)(A1p + (size_t)(k0 + 96) * 64);
                ya1 = *(const float4*)(A1p + (size_t)(k0 + 96) * 64 + 4);
                yw0 = *(const float4*)(Wp + k0 + 96);
                yw1 = *(const float4*)(Wp + k0 + 100);
            }
            MFMA_COMPUTE(4);
        }
        const int c0 = ct * 64;
        size_t base = (size_t)layer * 98304;
#pragma unroll
        for (int mt = 0; mt < 2; mt++)
#pragma unroll
            for (int nt = 0; nt < 2; nt++) {
                int n = r0 + wn0 + nt * 16 + lm;
#pragma unroll
                for (int i = 0; i < 4; i++) {
                    int m = c0 + wm0 + mt * 16 + q * 4 + i;
                    unsigned short hv, lv;
                    split2(acc[mt][nt][i], hv, lv);
                    WAth[base + (size_t)m * 768 + n] = hv;
                    WAtl[base + (size_t)m * 768 + n] = lv;
                }
            }
    } else {
        float* redb = (float*)(smem);    // 256 f
        int layer = id - 528;
        const float* bv = layer ? b1 : b0;
        int c = tid & 127, half = tid >> 7;
        float acc = 0.f;
        for (int kk = 0; kk < 384; kk++) {
            int k = half * 384 + kk;
            int row = (c < 64 ? k : 768 + k);
            acc += bv[k] * A1[(size_t)row * 64 + (c & 63)];
        }
        redb[tid] = acc;
        __syncthreads();
        if (tid < 128) bA[layer * 128 + tid] = redb[tid] + redb[tid + 128];
    }
}

// ---------------------------------------------------------------------------
// Fused gemm, 1-D grid 224 with XCD swizzle (validated r4 decode); BK=64 loop.
// ---------------------------------------------------------------------------
__global__ __launch_bounds__(256) void gemm_fused_k(
    const unsigned short* __restrict__ Ahg, const unsigned short* __restrict__ Alg,
    const unsigned short* __restrict__ Wth, const unsigned short* __restrict__ Wtl,
    const unsigned short* __restrict__ WAth, const unsigned short* __restrict__ WAtl,
    const float* __restrict__ bias,
    unsigned short* __restrict__ hth, unsigned short* __restrict__ htl,
    float* __restrict__ s)
{
    __shared__ unsigned short smem[8][64][72];   // 72 KB: 2-stage x 4 bufs
    int id = blockIdx.x;
    int g = id >> 3, r8 = id & 7;
    int hi2 = (g >= 14) ? 1 : 0;
    int by = r8 + 8 * hi2;
    int bx = g - 14 * hi2;
    int row0 = by * 64;
    const unsigned short* Bh;
    const unsigned short* Bl;
    int col0;
    if (bx < 12) { Bh = Wth;  Bl = Wtl;  col0 = bx * 64; }
    else         { Bh = WAth; Bl = WAtl; col0 = (bx - 12) * 64; }
    f32x4 acc[2][2] = {};
    mfma_loop(Ahg, Alg, 768, Bh, Bl, 768, 768, row0, col0, acc, smem);
    int tid = threadIdx.x, lane = tid & 63, wid = tid >> 6;
    int wm0 = (wid >> 1) * 32, wn0 = (wid & 1) * 32;
    int lm = lane & 15, q = lane >> 4;
    if (bx >= 12) {
#pragma unroll
        for (int mt = 0; mt < 2; mt++)
#pragma unroll
            for (int nt = 0; nt < 2; nt++) {
                int c = col0 + wn0 + nt * 16 + lm;
#pragma unroll
                for (int i = 0; i < 4; i++) {
                    int r = row0 + wm0 + mt * 16 + q * 4 + i;
                    s[(size_t)r * 128 + c] = acc[mt][nt][i];
                }
            }
        return;
    }
    __syncthreads();   // drain last-stage LDS reads before epilogue reuse
    unsigned short* flat = &smem[0][0][0];
    unsigned short (*Hi)[69] = (unsigned short(*)[69])flat;
    unsigned short (*Lo)[69] = (unsigned short(*)[69])(flat + 4416);
#pragma unroll
    for (int mt = 0; mt < 2; mt++)
#pragma unroll
        for (int nt = 0; nt < 2; nt++) {
            int c = wn0 + nt * 16 + lm;
            float bv = bias[col0 + c];
#pragma unroll
            for (int i = 0; i < 4; i++) {
                int r = wm0 + mt * 16 + q * 4 + i;
                unsigned short hv, lv;
                split2(acc[mt][nt][i] + bv, hv, lv);
                Hi[r][c] = hv; Lo[r][c] = lv;
            }
        }
    __syncthreads();
    int d = tid >> 2, kq = (tid & 3) * 16;
    int b = row0 >> 7, kb = row0 & 127;
    bs8 th0, th1, tl0, tl1;
#pragma unroll
    for (int e = 0; e < 8; e++) {
        th0[e] = Hi[kq + e][d];     th1[e] = Hi[kq + 8 + e][d];
        tl0[e] = Lo[kq + e][d];     tl1[e] = Lo[kq + 8 + e][d];
    }
    size_t to = ((size_t)b * 768 + col0 + d) * 128 + kb + kq;
    *(bs8*)(hth + to) = th0; *(bs8*)(hth + to + 8) = th1;
    *(bs8*)(htl + to) = tl0; *(bs8*)(htl + to + 8) = tl1;
}

// ---------------------------------------------------------------------------
// score_k: masked score + exp. 1-D grid 256: b = id&7 (XCD pin), bx = id>>3.
// Zeroes g_ws (blocks 0..23) for the attn layer-1 atomics.
// ---------------------------------------------------------------------------
__global__ __launch_bounds__(256) void score_k(
    const float* __restrict__ s, const int* __restrict__ adj,
    const float* __restrict__ ab1, const float* __restrict__ A2,
    const float* __restrict__ ab2, const float* __restrict__ bA,
    unsigned short* __restrict__ ph, unsigned short* __restrict__ pl,
    float* __restrict__ psum, float* __restrict__ g_ws)
{
    __shared__ float st[128][65];
    __shared__ float ss[4][65];
    __shared__ float a2s[64];
    __shared__ float warr[4];
    const int id = blockIdx.x, tid = threadIdx.x;
    const int b = id & 7, bx = id >> 3;
    const int i0 = bx * 4;
    if (id < 24) g_ws[id * 256 + tid] = 0.f;   // 24*256 = 6144 floats
#pragma unroll
    for (int g = 0; g < 8; g++) {     // float4-vectorized st load
        int idx4 = tid + g * 256;
        int j = idx4 >> 4;
        int h2 = (idx4 & 15) * 4;
        float4 v = *(const float4*)&s[(size_t)(b * 128 + j) * 128 + 64 + h2];
        float4 bv = *(const float4*)&bA[64 + h2];
        st[j][h2 + 0] = v.x + bv.x;
        st[j][h2 + 1] = v.y + bv.y;
        st[j][h2 + 2] = v.z + bv.z;
        st[j][h2 + 3] = v.w + bv.w;
    }
    {
        int i = tid >> 6, h2 = tid & 63;
        ss[i][h2] = s[(size_t)(b * 128 + i0 + i) * 128 + h2] + bA[h2] + ab1[h2];
    }
    if (tid < 64) a2s[tid] = A2[tid];
    __syncthreads();
    const float ab2v = ab2[0];
    const int rr = tid >> 7;
    const int j = tid & 127;
    const int r0 = rr * 2, r1 = rr * 2 + 1;
    float acc0 = 0.f, acc1 = 0.f;
#pragma unroll 4
    for (int h2 = 0; h2 < 64; h2++) {
        float bb = st[j][h2];
        float cv = a2s[h2];
        acc0 = fmaf(fmaxf(ss[r0][h2] + bb, 0.f), cv, acc0);
        acc1 = fmaf(fmaxf(ss[r1][h2] + bb, 0.f), cv, acc1);
    }
    float e0 = acc0 + ab2v; e0 = (e0 > 0.f) ? e0 : SLOPE_V * e0;
    float e1 = acc1 + ab2v; e1 = (e1 > 0.f) ? e1 : SLOPE_V * e1;
    size_t o0 = (size_t)b * 16384 + (size_t)(i0 + r0) * 128 + j;
    size_t o1 = (size_t)b * 16384 + (size_t)(i0 + r1) * 128 + j;
    float v0 = adj[o0] ? expf(e0) : 0.f;
    float v1 = adj[o1] ? expf(e1) : 0.f;
    unsigned short hv, lv;
    split2(v0, hv, lv); ph[o0] = hv; pl[o0] = lv;
    split2(v1, hv, lv); ph[o1] = hv; pl[o1] = lv;
    float vs = v0 + v1;
#pragma unroll
    for (int o = 32; o > 0; o >>= 1) vs += __shfl_down(vs, o);
    if ((tid & 63) == 0) warr[tid >> 6] = vs;
    __syncthreads();
    if (tid == 0) psum[b * 32 + bx] = warr[0] + warr[1] + warr[2] + warr[3];
}

// ---------------------------------------------------------------------------
// attn: node[b] = (1/sum_b) * P[b] @ h[b]. 1-D grid 192: b = id&7 (XCD pin).
// BK=64 loop (K=128: 1 iteration). node==nullptr on layer 0 (fp32 write is
// dead there). Layer 1 (g_ws != nullptr): column-sum atomics into g_ws.
// ---------------------------------------------------------------------------
__global__ __launch_bounds__(256) void attn_mfma_k(
    const unsigned short* __restrict__ ph, const unsigned short* __restrict__ pl,
    const unsigned short* __restrict__ hth, const unsigned short* __restrict__ htl,
    const float* __restrict__ psum, float* __restrict__ node,
    unsigned short* __restrict__ nodeh, unsigned short* __restrict__ nodel,
    float* __restrict__ g_ws)
{
    __shared__ unsigned short smem[8][64][72];   // 72 KB
    int id = blockIdx.x;
    int b = id & 7, t = id >> 3;
    int cx = t % 12, ry = t / 12;
    int row0 = ry * 64, col0 = cx * 64;
    int tid = threadIdx.x;
    // alpha: per-wave butterfly over psum[b][0..31] (both 32-halves identical)
    float pv = psum[b * 32 + (tid & 31)];
#pragma unroll
    for (int o = 1; o < 32; o <<= 1) pv += __shfl_xor(pv, o);
    float alpha = 1.0f / pv;
    f32x4 acc[2][2] = {};
    mfma_loop(ph + (size_t)b * 16384, pl + (size_t)b * 16384, 128,
              hth + (size_t)b * 98304, htl + (size_t)b * 98304, 128, 128,
              row0, col0, acc, smem);
    __syncthreads();   // drain last-stage LDS reads before epilogue reuse
    float* C = node ? node + (size_t)b * 98304 : nullptr;
    unsigned short* flat = &smem[0][0][0];
    unsigned short (*Hi)[69] = (unsigned short(*)[69])flat;
    unsigned short (*Lo)[69] = (unsigned short(*)[69])(flat + 4416);
    int lane = tid & 63, wid = tid >> 6;
    int wm0 = (wid >> 1) * 32, wn0 = (wid & 1) * 32;
    int lm = lane & 15, q = lane >> 4;
    float csum[2] = {0.f, 0.f};
#pragma unroll
    for (int mt = 0; mt < 2; mt++)
#pragma unroll
        for (int nt = 0; nt < 2; nt++) {
            int c = wn0 + nt * 16 + lm;
#pragma unroll
            for (int i = 0; i < 4; i++) {
                int r = wm0 + mt * 16 + q * 4 + i;
                float v = acc[mt][nt][i] * alpha;
                if (C) C[(size_t)(row0 + r) * 768 + col0 + c] = v;
                csum[nt] += v;
                unsigned short hv, lv;
                split2(v, hv, lv);
                Hi[r][c] = hv; Lo[r][c] = lv;
            }
        }
    if (g_ws) {   // layer 1: fold graph-sum here (16 adds/address total)
#pragma unroll
        for (int nt = 0; nt < 2; nt++)
            atomicAdd(&g_ws[b * 768 + col0 + wn0 + nt * 16 + lm], csum[nt]);
    }
    __syncthreads();
    int r = tid >> 2, cq = (tid & 3) * 16;
    bs8 vh0, vh1, vl0, vl1;
#pragma unroll
    for (int e = 0; e < 8; e++) {
        vh0[e] = Hi[r][cq + e];     vh1[e] = Hi[r][cq + 8 + e];
        vl0[e] = Lo[r][cq + e];     vl1[e] = Lo[r][cq + 8 + e];
    }
    size_t ro = (size_t)(b * 128 + row0 + r) * 768 + col0 + cq;
    *(bs8*)(nodeh + ro) = vh0; *(bs8*)(nodeh + ro + 8) = vh1;
    *(bs8*)(nodel + ro) = vl0; *(bs8*)(nodel + ro + 8) = vl1;
}

// ---------------------------------------------------------------------------
// bnorm only (graph-sum accumulated by attn layer-1 atomics).
// grid 12, block 64: d = bid*64 + tid.  (validated round 5)
// ---------------------------------------------------------------------------
__global__ __launch_bounds__(64) void bnorm_k(
    const float* __restrict__ g_ws, const float* __restrict__ gamma,
    const float* __restrict__ beta, float* __restrict__ out)
{
    int d = blockIdx.x * 64 + threadIdx.x;
    float vals[8]; float m = 0.f;
#pragma unroll
    for (int b = 0; b < 8; b++) { vals[b] = g_ws[b * 768 + d]; m += vals[b]; }
    m *= 0.125f;
    float var = 0.f;
#pragma unroll
    for (int b = 0; b < 8; b++) { float t = vals[b] - m; var += t * t; }
    var *= 0.125f;
    float inv = 1.0f / sqrtf(var + EPS_V);
    float gm = gamma[d], bt = beta[d];
#pragma unroll
    for (int b = 0; b < 8; b++)
        out[b * 768 + d] = gm * (vals[b] - m) * inv + bt;
}

// ---------------------------------------------------------------------------
extern "C" void kernel_launch(void* const* d_in, const int* in_sizes, int n_in,
                              void* d_out, int out_size, void* d_ws, size_t ws_size,
                              hipStream_t stream)
{
    const float* feature = (const float*)d_in[0];
    // d_in[1] = aspect: unused by the reference
    const int*   adj     = (const int*)d_in[2];
    const float* W0      = (const float*)d_in[3];
    const float* b0      = (const float*)d_in[4];
    const float* W1      = (const float*)d_in[5];
    const float* b1      = (const float*)d_in[6];
    const float* A1      = (const float*)d_in[7];
    const float* ab1     = (const float*)d_in[8];
    const float* A2      = (const float*)d_in[9];
    const float* ab2     = (const float*)d_in[10];
    const float* gamma   = (const float*)d_in[11];
    const float* beta    = (const float*)d_in[12];

    float* ws    = (float*)d_ws;
    float* s     = ws;               // 131072
    float* psum  = ws + 131072;      // 256
    float* bA    = ws + 131328;      // 256
    float* g_ws  = ws + 131584;      // 6144
    unsigned short* u = (unsigned short*)(ws + 137728);  // 16B-aligned
    unsigned short* Wt0h = u;                    // 589824 each
    unsigned short* Wt0l = Wt0h + 589824;
    unsigned short* Wt1h = Wt0l + 589824;
    unsigned short* Wt1l = Wt1h + 589824;
    unsigned short* WAth = Wt1l + 589824;        // 196608 each (2 layers)
    unsigned short* WAtl = WAth + 196608;
    unsigned short* fh   = WAtl + 196608;        // 786432 each from here
    unsigned short* fl   = fh + 786432;
    unsigned short* hth  = fl + 786432;
    unsigned short* htl  = hth + 786432;
    unsigned short* ndh  = htl + 786432;
    unsigned short* ndl  = ndh + 786432;
    unsigned short* ph   = ndl + 786432;         // 131072 each
    unsigned short* pl   = ph + 131072;

    float* out       = (float*)d_out;
    float* graph_out = out;          // (8,768)
    float* node_out  = out + 6144;   // (8,128,768)

    prep_k<<<530, 256, 0, stream>>>(W0, W1, A1, feature, b0, b1,
                                    Wt0h, Wt0l, Wt1h, Wt1l,
                                    fh, fl, WAth, WAtl, bA);

    for (int layer = 0; layer < 2; layer++) {
        const unsigned short* Wth = layer ? Wt1h : Wt0h;
        const unsigned short* Wtl = layer ? Wt1l : Wt0l;
        const float* bb = layer ? b1 : b0;
        const unsigned short* Ahg = layer ? ndh : fh;
        const unsigned short* Alg = layer ? ndl : fl;
        gemm_fused_k<<<224, 256, 0, stream>>>(
            Ahg, Alg, Wth, Wtl, WAth + (size_t)layer * 98304,
            WAtl + (size_t)layer * 98304, bb, hth, htl, s);
        score_k<<<256, 256, 0, stream>>>(s, adj, ab1, A2, ab2,
                                         bA + layer * 128, ph, pl, psum, g_ws);
        attn_mfma_k<<<192, 256, 0, stream>>>(ph, pl, hth, htl, psum,
                                             layer ? node_out : (float*)nullptr,
                                             ndh, ndl,
                                             layer ? g_ws : (float*)nullptr);
    }
    bnorm_k<<<12, 64, 0, stream>>>(g_ws, gamma, beta, graph_out);
}